// Round 8
// baseline (8330.923 us; speedup 1.0000x reference)
//
#include <hip/hip_runtime.h>
#include <hip/hip_bf16.h>
#include <stdint.h>

typedef __hip_bfloat16 bf16;
typedef __attribute__((ext_vector_type(8))) short short8;
typedef __attribute__((ext_vector_type(4))) float f32x4;

__device__ __forceinline__ bf16 f2b(float v){ return __float2bfloat16(v); }
__device__ __forceinline__ short8 s8zero()
{
    short8 z;
    for (int i = 0; i < 8; ++i) z[i] = 0;
    return z;
}

struct Taps  { int n; int oh[9]; int ow[9]; int ti[9]; };
struct Taps4 { Taps t[4]; };

// ===================== fp32 implicit-GEMM conv (encoder) =====================
template<int CIN, int COUT, int HIN, int WIN, int HOUT, int WOUT,
         int A, int OST, int MH, int MW, int KC, bool IN_NCHW>
__global__ __launch_bounds__(256)
void conv_gemm(const float* __restrict__ x, const float* __restrict__ wt,
               const float* __restrict__ bias, float* __restrict__ y, Taps4 ts)
{
    constexpr int M   = MH * MW;
    constexpr int N   = COUT;
    constexpr int NT4 = N / 4;
    constexpr int HQ  = HOUT / OST, WQ = WOUT / OST;
    constexpr int TH  = HQ / MH,   TW = WQ / MW;
    constexpr int XSTR = M + 4;
    static_assert(M * N == 4096, "block tile must be 4096");

    __shared__ float Xs[KC * XSTR];
    __shared__ float Ws[KC * N];

    const int tid = threadIdx.x;
    const int mt = tid / NT4, nt = tid % NT4;

    int bx = blockIdx.x;
    const int tw = bx % TW; bx /= TW;
    const int th = bx % TH;
    const int n  = bx / TH;
    const int hq0 = th * MH, wq0 = tw * MW;

    float bv[4];
    #pragma unroll
    for (int j = 0; j < 4; ++j) bv[j] = bias[nt * 4 + j];

    float acc[4][4];
    #pragma unroll
    for (int i = 0; i < 4; ++i)
        #pragma unroll
        for (int j = 0; j < 4; ++j) acc[i][j] = 0.f;

    const int ntaps = ts.t[0].n;
    for (int t = 0; t < ntaps; ++t) {
        const int oh = ts.t[0].oh[t];
        const int ow = ts.t[0].ow[t];
        const int ti = ts.t[0].ti[t];
        const float* wtp = wt + (size_t)(ti * CIN) * N;
        for (int c0 = 0; c0 < CIN; c0 += KC) {
            __syncthreads();
            for (int e = tid; e < KC * N; e += 256)
                Ws[e] = wtp[(size_t)c0 * N + e];
            for (int e = tid; e < M * KC; e += 256) {
                int k, m;
                if (IN_NCHW) { k = e / M;  m = e % M; }
                else         { k = e % KC; m = e / KC; }
                const int hq = hq0 + m / MW;
                const int wq = wq0 + m % MW;
                const int hi = hq * A + oh;
                const int wi = wq * A + ow;
                float v = 0.f;
                if ((unsigned)hi < (unsigned)HIN && (unsigned)wi < (unsigned)WIN) {
                    if (IN_NCHW)
                        v = x[(((size_t)n * CIN + c0 + k) * HIN + hi) * WIN + wi];
                    else
                        v = x[(((size_t)n * HIN + hi) * WIN + wi) * CIN + c0 + k];
                }
                Xs[k * XSTR + m] = v;
            }
            __syncthreads();
            #pragma unroll
            for (int k = 0; k < KC; ++k) {
                float4 av = *reinterpret_cast<const float4*>(&Xs[k * XSTR + mt * 4]);
                float4 bw = *reinterpret_cast<const float4*>(&Ws[k * N + nt * 4]);
                acc[0][0] += av.x * bw.x; acc[0][1] += av.x * bw.y;
                acc[0][2] += av.x * bw.z; acc[0][3] += av.x * bw.w;
                acc[1][0] += av.y * bw.x; acc[1][1] += av.y * bw.y;
                acc[1][2] += av.y * bw.z; acc[1][3] += av.y * bw.w;
                acc[2][0] += av.z * bw.x; acc[2][1] += av.z * bw.y;
                acc[2][2] += av.z * bw.z; acc[2][3] += av.z * bw.w;
                acc[3][0] += av.w * bw.x; acc[3][1] += av.w * bw.y;
                acc[3][2] += av.w * bw.z; acc[3][3] += av.w * bw.w;
            }
        }
    }
    #pragma unroll
    for (int i = 0; i < 4; ++i) {
        const int m  = mt * 4 + i;
        const int ho = (hq0 + m / MW);
        const int wo = (wq0 + m % MW);
        float4 o;
        o.x = fmaxf(acc[i][0] + bv[0], 0.f);
        o.y = fmaxf(acc[i][1] + bv[1], 0.f);
        o.z = fmaxf(acc[i][2] + bv[2], 0.f);
        o.w = fmaxf(acc[i][3] + bv[3], 0.f);
        *reinterpret_cast<float4*>(&y[(((size_t)n * HOUT + ho) * WOUT + wo) * N + nt * 4]) = o;
    }
}

__global__ void wtr_conv(const float* __restrict__ w, float* __restrict__ wt,
                         int COUT, int CIN)   // w[co][ci][9] -> wt[t][ci][co]
{
    int idx = blockIdx.x * blockDim.x + threadIdx.x;
    if (idx >= COUT * CIN * 9) return;
    int co = idx / (CIN * 9);
    int r  = idx - co * CIN * 9;
    int ci = r / 9, t = r - ci * 9;
    wt[((size_t)t * CIN + ci) * COUT + co] = w[idx];
}

// ============ decoder weight transform: w[ci][co][9] -> wtb[t][co][ci] bf16 ============
__global__ void wtrb_convt(const float* __restrict__ w, bf16* __restrict__ wt,
                           int CIN, int COUT)
{
    int idx = blockIdx.x * blockDim.x + threadIdx.x;
    if (idx >= CIN * COUT * 9) return;
    int ci = idx / (COUT * 9);
    int r  = idx - ci * COUT * 9;
    int co = r / 9, t = r - co * 9;
    wt[((size_t)t * COUT + co) * CIN + ci] = f2b(w[idx]);
}

// ============ MFMA transpose-conv stride 2 (parity classes via blockIdx.y) ============
// in [img][HIN][WIN][64] bf16, out [img][2H][2W][COUT] bf16; wtb [9][COUT][64]
template<int COUT, int HIN, int WIN>
__global__ __launch_bounds__(256)
void convt2_mfma(const bf16* __restrict__ xg, const bf16* __restrict__ wtb,
                 const float* __restrict__ bias, bf16* __restrict__ yg)
{
    constexpr int CIN = 64, C8 = 8;
    constexpr int HP = HIN + 1, WP = WIN + 1, NPOS = HP * WP;
    constexpr int HOUT = HIN * 2, WOUT = WIN * 2;
    constexpr int NT = COUT / 16;
    constexpr int MT = (HIN * WIN) / 16;
    __shared__ short8 Xs[NPOS * C8];

    const int img = blockIdx.x;
    const int cls = blockIdx.y;
    const int pa = cls >> 1, pb = cls & 1;
    const bf16* xi = xg + (size_t)img * HIN * WIN * CIN;

    for (int e = threadIdx.x; e < NPOS * C8; e += 256) {
        int c8 = e & 7, pos = e >> 3;
        int hi = pos / WP, wi = pos % WP;
        short8 v = s8zero();
        if (hi < HIN && wi < WIN)
            v = *reinterpret_cast<const short8*>(xi + ((size_t)(hi * WIN + wi)) * CIN + c8 * 8);
        Xs[pos * C8 + (c8 ^ (pos & 7))] = v;
    }
    __syncthreads();

    const int wv = threadIdx.x >> 6, lane = threadIdx.x & 63;
    const int lp = lane & 15, lq = lane >> 4;
    const int nt    = (NT == 4) ? wv : (wv & 1);
    const int mt0   = (NT == 4) ? 0  : (wv >> 1);
    const int mstep = (NT == 4) ? 1  : 2;

    int toh[4], tow[4], tti[4], ntap = 0;
    for (int kh = 0; kh < 3; ++kh) {
        if ((pa + 1 - kh) & 1) continue;
        for (int kw = 0; kw < 3; ++kw) {
            if ((pb + 1 - kw) & 1) continue;
            toh[ntap] = (pa + 1 - kh) >> 1;
            tow[ntap] = (pb + 1 - kw) >> 1;
            tti[ntap] = kh * 3 + kw;
            ++ntap;
        }
    }
    short8 wf[4][2];
    for (int t = 0; t < ntap; ++t) {
        const bf16* wp = wtb + ((size_t)tti[t] * COUT + nt * 16 + lp) * CIN + lq * 8;
        wf[t][0] = *reinterpret_cast<const short8*>(wp);
        wf[t][1] = *reinterpret_cast<const short8*>(wp + 32);
    }
    float bv[4];
    #pragma unroll
    for (int r = 0; r < 4; ++r) bv[r] = bias[nt * 16 + lq * 4 + r];

    bf16* yi = yg + (size_t)img * HOUT * WOUT * COUT;
    for (int mt = mt0; mt < MT; mt += mstep) {
        int m = mt * 16 + lp;
        int hq = m / WIN, wq = m % WIN;
        f32x4 acc = {0.f, 0.f, 0.f, 0.f};
        for (int t = 0; t < ntap; ++t) {
            int pos = (hq + toh[t]) * WP + (wq + tow[t]);
            int sw = pos & 7;
            short8 b0 = Xs[pos * C8 + (lq ^ sw)];
            acc = __builtin_amdgcn_mfma_f32_16x16x32_bf16(wf[t][0], b0, acc, 0, 0, 0);
            short8 b1 = Xs[pos * C8 + ((4 + lq) ^ sw)];
            acc = __builtin_amdgcn_mfma_f32_16x16x32_bf16(wf[t][1], b1, acc, 0, 0, 0);
        }
        int ho = hq * 2 + pa, wo = wq * 2 + pb;
        __align__(8) bf16 ov[4];
        #pragma unroll
        for (int r = 0; r < 4; ++r) ov[r] = f2b(fmaxf(acc[r] + bv[r], 0.f));
        *reinterpret_cast<uint2*>(yi + ((size_t)(ho * WOUT + wo)) * COUT + nt * 16 + lq * 4)
            = *reinterpret_cast<uint2*>(ov);
    }
}

// ============ MFMA transpose-conv stride 1 (32->16) + fused 1x1 (16->3) ============
// in [img][32][32][32] bf16; out dec [img][3][32][32] fp32 NCHW; wtb [9][16][32]
__global__ __launch_bounds__(256)
void convt1_mfma_fused(const bf16* __restrict__ xg, const bf16* __restrict__ wtb,
                       const float* __restrict__ bias,
                       const float* __restrict__ w4, const float* __restrict__ b4,
                       float* __restrict__ dec)
{
    constexpr int CIN = 32, C8 = 4;
    constexpr int H = 32, W = 32, HR = 18, WR = 34, NPOS = HR * WR;
    __shared__ short8 Xs[NPOS * C8];

    const int img  = blockIdx.x >> 1;
    const int half = blockIdx.x & 1;
    const int hbase = half * 16;
    const bf16* xi = xg + (size_t)img * H * W * CIN;

    for (int e = threadIdx.x; e < NPOS * C8; e += 256) {
        int c8 = e & 3, pos = e >> 2;
        int hr = pos / WR, wr = pos % WR;
        int hi = hbase - 1 + hr, wi = wr - 1;
        short8 v = s8zero();
        if ((unsigned)hi < (unsigned)H && (unsigned)wi < (unsigned)W)
            v = *reinterpret_cast<const short8*>(xi + ((size_t)(hi * W + wi)) * CIN + c8 * 8);
        Xs[pos * C8 + (c8 ^ (pos & 3))] = v;
    }
    __syncthreads();

    const int wv = threadIdx.x >> 6, lane = threadIdx.x & 63;
    const int lp = lane & 15, lq = lane >> 4;

    short8 wf[9];
    #pragma unroll
    for (int t = 0; t < 9; ++t)
        wf[t] = *reinterpret_cast<const short8*>(wtb + ((size_t)t * 16 + lp) * CIN + lq * 8);
    float bv[4];
    #pragma unroll
    for (int r = 0; r < 4; ++r) bv[r] = bias[lq * 4 + r];
    float w4r[3][4];
    #pragma unroll
    for (int j = 0; j < 3; ++j)
        #pragma unroll
        for (int r = 0; r < 4; ++r) w4r[j][r] = w4[j * 16 + lq * 4 + r];
    float b4r[3] = {b4[0], b4[1], b4[2]};

    for (int mt = wv; mt < 32; mt += 4) {
        int m = mt * 16 + lp;
        int hol = m >> 5, wo = m & 31;
        f32x4 acc = {0.f, 0.f, 0.f, 0.f};
        #pragma unroll
        for (int t = 0; t < 9; ++t) {
            int kh = t / 3, kw = t % 3;
            int pos = (hol + 2 - kh) * WR + (wo + 2 - kw);
            short8 b0 = Xs[pos * C8 + (lq ^ (pos & 3))];
            acc = __builtin_amdgcn_mfma_f32_16x16x32_bf16(wf[t], b0, acc, 0, 0, 0);
        }
        float s0 = 0.f, s1 = 0.f, s2 = 0.f;
        #pragma unroll
        for (int r = 0; r < 4; ++r) {
            float v = fmaxf(acc[r] + bv[r], 0.f);
            s0 += v * w4r[0][r]; s1 += v * w4r[1][r]; s2 += v * w4r[2][r];
        }
        s0 += __shfl_xor(s0, 16); s0 += __shfl_xor(s0, 32);
        s1 += __shfl_xor(s1, 16); s1 += __shfl_xor(s1, 32);
        s2 += __shfl_xor(s2, 16); s2 += __shfl_xor(s2, 32);
        if (lq == 0) {
            int ho = hbase + hol;
            size_t base = (size_t)img * 3072 + ho * 32 + wo;
            dec[base]        = s0 + b4r[0];
            dec[base + 1024] = s1 + b4r[1];
            dec[base + 2048] = s2 + b4r[2];
        }
    }
}

// ---------------- embedding: sigmoid(h3_nhwc . kw^T + kb); dual-writes h3 bf16 ----------------
__global__ void emb_kernel(const float* __restrict__ h3, const float* __restrict__ kw,
                           const float* __restrict__ kb, float* __restrict__ emb,
                           bf16* __restrict__ h3b)
{
    __shared__ float rt[64 * 68];
    const int n = blockIdx.x;
    const float4* src = (const float4*)(h3 + (size_t)n * 4096);
    for (int k4 = threadIdx.x; k4 < 1024; k4 += blockDim.x) {
        float4 v = src[k4];
        int k = k4 * 4, p = k >> 6, ci = k & 63;
        rt[(ci + 0) * 68 + p] = v.x;
        rt[(ci + 1) * 68 + p] = v.y;
        rt[(ci + 2) * 68 + p] = v.z;
        rt[(ci + 3) * 68 + p] = v.w;
        __align__(8) bf16 ov[4] = {f2b(v.x), f2b(v.y), f2b(v.z), f2b(v.w)};
        *reinterpret_cast<uint2*>(h3b + (size_t)n * 4096 + k) = *reinterpret_cast<uint2*>(ov);
    }
    __syncthreads();
    const int e = threadIdx.x;
    if (e < 110) {
        const float4* kwr = (const float4*)(kw + (size_t)e * 4096);
        float s0 = 0.f, s1 = 0.f, s2 = 0.f, s3 = 0.f;
        for (int k4 = 0; k4 < 1024; ++k4) {
            float4 wv = kwr[k4];
            int k = k4 * 4, ci = k >> 6, p = k & 63;
            const float* rp = &rt[ci * 68 + p];
            s0 += rp[0] * wv.x; s1 += rp[1] * wv.y;
            s2 += rp[2] * wv.z; s3 += rp[3] * wv.w;
        }
        float acc = kb[e] + ((s0 + s1) + (s2 + s3));
        emb[(size_t)n * 110 + e] = 1.f / (1.f + expf(-acc));
    }
}

// ---------------- KDE ----------------
__global__ void kde_kernel(const float* __restrict__ emb, float* __restrict__ fd)
{
    int idx = blockIdx.x * blockDim.x + threadIdx.x;
    if (idx >= 64 * 110) return;
    int f = idx % 110, b = idx / 110;
    float dens[11];
    #pragma unroll
    for (int j = 0; j < 11; ++j) dens[j] = 0.f;
    const float* ep = emb + (size_t)b * 32 * 110 + f;
    for (int n = 0; n < 32; ++n) {
        float e = ep[n * 110];
        #pragma unroll
        for (int j = 0; j < 11; ++j) {
            float d = 0.1f * j - e;
            dens[j] += expf(-50.f * d * d);
        }
    }
    float s = 0.f;
    #pragma unroll
    for (int j = 0; j < 11; ++j) s += dens[j];
    float inv = 1.f / s;
    float* op = fd + (size_t)b * 1210 + f * 11;
    #pragma unroll
    for (int j = 0; j < 11; ++j) op[j] = dens[j] * inv;
}

// ---------------- dense ----------------
template<int K, int OUT>
__global__ void dense_kernel(const float* __restrict__ in, const float* __restrict__ w,
                             const float* __restrict__ b, float* __restrict__ out,
                             int rows, int relu)
{
    int idx = blockIdx.x * blockDim.x + threadIdx.x;
    if (idx >= rows * OUT) return;
    int o = idx % OUT, r = idx / OUT;
    float acc = b[o];
    const float* ir = in + (size_t)r * K;
    const float* wr = w  + (size_t)o * K;
    for (int k = 0; k < K; ++k) acc += ir[k] * wr[k];
    if (relu) acc = fmaxf(acc, 0.f);
    out[idx] = acc;
}

// ===================== host side =====================
static Taps4 mk_conv9()
{
    Taps4 T = {};
    T.t[0].n = 9;
    int q = 0;
    for (int kh = 0; kh < 3; ++kh)
        for (int kw = 0; kw < 3; ++kw) {
            T.t[0].oh[q] = kh - 1; T.t[0].ow[q] = kw - 1; T.t[0].ti[q] = kh * 3 + kw; ++q;
        }
    return T;
}

extern "C" void kernel_launch(void* const* d_in, const int* in_sizes, int n_in,
                              void* d_out, int out_size, void* d_ws, size_t ws_size,
                              hipStream_t stream)
{
    const float* x    = (const float*)d_in[0];
    const float* ew1  = (const float*)d_in[1];
    const float* eb1  = (const float*)d_in[2];
    const float* ew2  = (const float*)d_in[3];
    const float* eb2  = (const float*)d_in[4];
    const float* ew3  = (const float*)d_in[5];
    const float* eb3  = (const float*)d_in[6];
    const float* kw   = (const float*)d_in[7];
    const float* kb   = (const float*)d_in[8];
    const float* dw1  = (const float*)d_in[9];
    const float* db1  = (const float*)d_in[10];
    const float* dw2  = (const float*)d_in[11];
    const float* db2  = (const float*)d_in[12];
    const float* dw3  = (const float*)d_in[13];
    const float* db3  = (const float*)d_in[14];
    const float* dw4  = (const float*)d_in[15];
    const float* db4  = (const float*)d_in[16];
    const float* f1w  = (const float*)d_in[17];
    const float* f1b  = (const float*)d_in[18];
    const float* f2w  = (const float*)d_in[19];
    const float* f2b_ = (const float*)d_in[20];
    const float* f3w  = (const float*)d_in[21];
    const float* f3b  = (const float*)d_in[22];

    // ---------- workspace ----------
    char* ws = (char*)d_ws;
    float* emb  = (float*)(ws + 0);         //   901,120
    float* fd   = (float*)(ws + 901120);    //   309,760
    float* m1   = (float*)(ws + 1210880);   //   131,072
    float* m2   = (float*)(ws + 1341952);   //    65,536
    float* wt1  = (float*)(ws + 1407488);   //     1,792
    float* wt2  = (float*)(ws + 1409280);   //    18,432
    float* wt3  = (float*)(ws + 1427712);   //    73,728
    bf16*  wtb4 = (bf16*) (ws + 1501440);   //    73,728 (9*64*64 bf16)
    bf16*  wtb5 = (bf16*) (ws + 1575168);   //    36,864 (9*64*32)
    bf16*  wtb6 = (bf16*) (ws + 1612032);   //     9,216 (9*16*32)
    const size_t FIXED = 1621248;

    // per image: h1(fp32,64K, d1b overlays) | h2 32K | h3 16K | h3b 8K | d2b 64K
    const size_t PER_IMG = 188416;
    int CHUNK = 512;
    while (CHUNK > 8 && FIXED + (size_t)CHUNK * PER_IMG > ws_size) CHUNK >>= 1;
    const int NCHUNK = 2048 / CHUNK;

    char* p   = ws + FIXED;
    float* h1  = (float*)(p);
    float* h2  = (float*)(p + (size_t)CHUNK * 65536);
    float* h3  = (float*)(p + (size_t)CHUNK * 98304);
    bf16*  h3b = (bf16*) (p + (size_t)CHUNK * 114688);
    bf16*  d2b = (bf16*) (p + (size_t)CHUNK * 122880);
    bf16*  d1b = (bf16*)h1;                  // overlay: h1 dead after enc2

    float* logits = (float*)d_out;           // 64*4
    float* dec    = (float*)d_out + 256;     // 2048*3*32*32 NCHW

    // ---- weight transforms (once per launch) ----
    wtr_conv  <<<(16*3*9  + 255)/256, 256, 0, stream>>>(ew1, wt1, 16, 3);
    wtr_conv  <<<(32*16*9 + 255)/256, 256, 0, stream>>>(ew2, wt2, 32, 16);
    wtr_conv  <<<(64*32*9 + 255)/256, 256, 0, stream>>>(ew3, wt3, 64, 32);
    wtrb_convt<<<(64*64*9 + 255)/256, 256, 0, stream>>>(dw1, wtb4, 64, 64);
    wtrb_convt<<<(64*32*9 + 255)/256, 256, 0, stream>>>(dw2, wtb5, 64, 32);
    wtrb_convt<<<(32*16*9 + 255)/256, 256, 0, stream>>>(dw3, wtb6, 32, 16);

    const Taps4 T9 = mk_conv9();

    for (int c = 0; c < NCHUNK; ++c) {
        const float* xc   = x   + (size_t)c * CHUNK * 3 * 1024;
        float*       decc = dec + (size_t)c * CHUNK * 3 * 1024;
        float*       embc = emb + (size_t)c * CHUNK * 110;

        // encoder (fp32)
        conv_gemm<3,16,32,32,32,32, 1,1, 16,16, 3, true>
            <<<dim3(CHUNK*4,1), 256, 0, stream>>>(xc, wt1, eb1, h1, T9);
        conv_gemm<16,32,32,32,16,16, 2,1, 8,16, 16, false>
            <<<dim3(CHUNK*2,1), 256, 0, stream>>>(h1, wt2, eb2, h2, T9);
        conv_gemm<32,64,16,16,8,8, 2,1, 8,8, 16, false>
            <<<dim3(CHUNK,1), 256, 0, stream>>>(h2, wt3, eb3, h3, T9);

        // embedding (+h3 bf16 cast)
        emb_kernel<<<CHUNK, 128, 0, stream>>>(h3, kw, kb, embc, h3b);

        // decoder (bf16 MFMA)
        convt2_mfma<64, 8, 8>  <<<dim3(CHUNK,4), 256, 0, stream>>>(h3b, wtb4, db1, d1b);
        convt2_mfma<32, 16, 16><<<dim3(CHUNK,4), 256, 0, stream>>>(d1b, wtb5, db2, d2b);
        convt1_mfma_fused      <<<dim3(CHUNK*2,1), 256, 0, stream>>>(d2b, wtb6, db3, dw4, db4, decc);
    }

    // classifier (fp32)
    kde_kernel<<<(64*110+255)/256, 256, 0, stream>>>(emb, fd);
    dense_kernel<1210,512><<<(64*512+255)/256, 256, 0, stream>>>(fd, f1w, f1b, m1, 64, 1);
    dense_kernel<512,256><<<(64*256+255)/256, 256, 0, stream>>>(m1, f2w, f2b_, m2, 64, 1);
    dense_kernel<256,4><<<1, 256, 0, stream>>>(m2, f3w, f3b, logits, 64, 0);
}

// Round 9
// 1112.289 us; speedup vs baseline: 7.4899x; 7.4899x over previous
//
#include <hip/hip_runtime.h>
#include <hip/hip_bf16.h>
#include <stdint.h>

typedef __hip_bfloat16 bf16;
typedef __attribute__((ext_vector_type(8))) short short8;
typedef __attribute__((ext_vector_type(4))) float f32x4;

__device__ __forceinline__ bf16 f2b(float v){ return __float2bfloat16(v); }
__device__ __forceinline__ short8 s8zero()
{
    short8 z;
    for (int i = 0; i < 8; ++i) z[i] = 0;
    return z;
}

struct Taps  { int n; int oh[9]; int ow[9]; int ti[9]; };
struct Taps4 { Taps t[4]; };

// ===================== fp32 implicit-GEMM conv (encoder) =====================
template<int CIN, int COUT, int HIN, int WIN, int HOUT, int WOUT,
         int A, int OST, int MH, int MW, int KC, bool IN_NCHW>
__global__ __launch_bounds__(256)
void conv_gemm(const float* __restrict__ x, const float* __restrict__ wt,
               const float* __restrict__ bias, float* __restrict__ y, Taps4 ts)
{
    constexpr int M   = MH * MW;
    constexpr int N   = COUT;
    constexpr int NT4 = N / 4;
    constexpr int HQ  = HOUT / OST, WQ = WOUT / OST;
    constexpr int TH  = HQ / MH,   TW = WQ / MW;
    constexpr int XSTR = M + 4;
    static_assert(M * N == 4096, "block tile must be 4096");

    __shared__ float Xs[KC * XSTR];
    __shared__ float Ws[KC * N];

    const int tid = threadIdx.x;
    const int mt = tid / NT4, nt = tid % NT4;

    int bx = blockIdx.x;
    const int tw = bx % TW; bx /= TW;
    const int th = bx % TH;
    const int n  = bx / TH;
    const int hq0 = th * MH, wq0 = tw * MW;

    float bv[4];
    #pragma unroll
    for (int j = 0; j < 4; ++j) bv[j] = bias[nt * 4 + j];

    float acc[4][4];
    #pragma unroll
    for (int i = 0; i < 4; ++i)
        #pragma unroll
        for (int j = 0; j < 4; ++j) acc[i][j] = 0.f;

    const int ntaps = ts.t[0].n;
    for (int t = 0; t < ntaps; ++t) {
        const int oh = ts.t[0].oh[t];
        const int ow = ts.t[0].ow[t];
        const int ti = ts.t[0].ti[t];
        const float* wtp = wt + (size_t)(ti * CIN) * N;
        for (int c0 = 0; c0 < CIN; c0 += KC) {
            __syncthreads();
            for (int e = tid; e < KC * N; e += 256)
                Ws[e] = wtp[(size_t)c0 * N + e];
            for (int e = tid; e < M * KC; e += 256) {
                int k, m;
                if (IN_NCHW) { k = e / M;  m = e % M; }
                else         { k = e % KC; m = e / KC; }
                const int hq = hq0 + m / MW;
                const int wq = wq0 + m % MW;
                const int hi = hq * A + oh;
                const int wi = wq * A + ow;
                float v = 0.f;
                if ((unsigned)hi < (unsigned)HIN && (unsigned)wi < (unsigned)WIN) {
                    if (IN_NCHW)
                        v = x[(((size_t)n * CIN + c0 + k) * HIN + hi) * WIN + wi];
                    else
                        v = x[(((size_t)n * HIN + hi) * WIN + wi) * CIN + c0 + k];
                }
                Xs[k * XSTR + m] = v;
            }
            __syncthreads();
            #pragma unroll
            for (int k = 0; k < KC; ++k) {
                float4 av = *reinterpret_cast<const float4*>(&Xs[k * XSTR + mt * 4]);
                float4 bw = *reinterpret_cast<const float4*>(&Ws[k * N + nt * 4]);
                acc[0][0] += av.x * bw.x; acc[0][1] += av.x * bw.y;
                acc[0][2] += av.x * bw.z; acc[0][3] += av.x * bw.w;
                acc[1][0] += av.y * bw.x; acc[1][1] += av.y * bw.y;
                acc[1][2] += av.y * bw.z; acc[1][3] += av.y * bw.w;
                acc[2][0] += av.z * bw.x; acc[2][1] += av.z * bw.y;
                acc[2][2] += av.z * bw.z; acc[2][3] += av.z * bw.w;
                acc[3][0] += av.w * bw.x; acc[3][1] += av.w * bw.y;
                acc[3][2] += av.w * bw.z; acc[3][3] += av.w * bw.w;
            }
        }
    }
    #pragma unroll
    for (int i = 0; i < 4; ++i) {
        const int m  = mt * 4 + i;
        const int ho = (hq0 + m / MW);
        const int wo = (wq0 + m % MW);
        float4 o;
        o.x = fmaxf(acc[i][0] + bv[0], 0.f);
        o.y = fmaxf(acc[i][1] + bv[1], 0.f);
        o.z = fmaxf(acc[i][2] + bv[2], 0.f);
        o.w = fmaxf(acc[i][3] + bv[3], 0.f);
        *reinterpret_cast<float4*>(&y[(((size_t)n * HOUT + ho) * WOUT + wo) * N + nt * 4]) = o;
    }
}

__global__ void wtr_conv(const float* __restrict__ w, float* __restrict__ wt,
                         int COUT, int CIN)   // w[co][ci][9] -> wt[t][ci][co]
{
    int idx = blockIdx.x * blockDim.x + threadIdx.x;
    if (idx >= COUT * CIN * 9) return;
    int co = idx / (CIN * 9);
    int r  = idx - co * CIN * 9;
    int ci = r / 9, t = r - ci * 9;
    wt[((size_t)t * CIN + ci) * COUT + co] = w[idx];
}

// ============ decoder weight transform: w[ci][co][9] -> wtb[t][co][ci] bf16 ============
__global__ void wtrb_convt(const float* __restrict__ w, bf16* __restrict__ wt,
                           int CIN, int COUT)
{
    int idx = blockIdx.x * blockDim.x + threadIdx.x;
    if (idx >= CIN * COUT * 9) return;
    int ci = idx / (COUT * 9);
    int r  = idx - ci * COUT * 9;
    int co = r / 9, t = r - co * 9;
    wt[((size_t)t * COUT + co) * CIN + ci] = f2b(w[idx]);
}

// ============ MFMA transpose-conv stride 2: ALL 4 parity classes per block ============
// in [img][HIN][WIN][64] bf16, out [img][2H][2W][COUT] bf16; wtb [9][COUT][64]
// Fully compile-time tap loop: no runtime-indexed register arrays (rule #20).
// HSPLIT splits the image rows across blockIdx.y for parallelism.
template<int COUT, int HIN, int WIN, int HSPLIT>
__global__ __launch_bounds__(256)
void convt2_mfma(const bf16* __restrict__ xg, const bf16* __restrict__ wtb,
                 const float* __restrict__ bias, bf16* __restrict__ yg)
{
    constexpr int CIN = 64, C8 = 8;
    constexpr int WP  = WIN + 1;
    constexpr int HS  = HIN / HSPLIT;        // quarter-res rows per block
    constexpr int HPS = HS + 1;              // staged padded rows
    constexpr int NPOS = HPS * WP;
    constexpr int HOUT = HIN * 2, WOUT = WIN * 2;
    constexpr int NT = COUT / 16;            // 4 (dec1) or 2 (dec2)
    constexpr int MT = (HS * WIN) / 16;      // m-tiles per block
    __shared__ short8 Xs[NPOS * C8];

    const int img = blockIdx.x;
    const int s   = blockIdx.y;
    const int hqb = s * HS;
    const bf16* xi = xg + (size_t)img * HIN * WIN * CIN;

    for (int e = threadIdx.x; e < NPOS * C8; e += 256) {
        int c8 = e & 7, pos = e >> 3;
        int hl = pos / WP, wi = pos % WP;
        int hi = hqb + hl;
        short8 v = s8zero();
        if (hi < HIN && wi < WIN)
            v = *reinterpret_cast<const short8*>(xi + ((size_t)(hi * WIN + wi)) * CIN + c8 * 8);
        Xs[pos * C8 + (c8 ^ (pos & 7))] = v;
    }
    __syncthreads();

    const int wv = threadIdx.x >> 6, lane = threadIdx.x & 63;
    const int lp = lane & 15, lq = lane >> 4;
    const int nt    = (NT == 4) ? wv : (wv & 1);
    const int mt0   = (NT == 4) ? 0  : (wv >> 1) * (MT / 2);
    const int mtend = (NT == 4) ? MT : mt0 + (MT / 2);

    // all 9 taps, 2 K-chunks each — static indices only
    short8 wf[9][2];
    #pragma unroll
    for (int t = 0; t < 9; ++t) {
        const bf16* wp = wtb + ((size_t)t * COUT + nt * 16 + lp) * CIN + lq * 8;
        wf[t][0] = *reinterpret_cast<const short8*>(wp);
        wf[t][1] = *reinterpret_cast<const short8*>(wp + 32);
    }
    float bv[4];
    #pragma unroll
    for (int r = 0; r < 4; ++r) bv[r] = bias[nt * 16 + lq * 4 + r];

    bf16* yi = yg + (size_t)img * HOUT * WOUT * COUT;
    for (int mt = mt0; mt < mtend; ++mt) {
        int m = mt * 16 + lp;
        int hql = m / WIN, wq = m % WIN;      // local quarter-res coords
        f32x4 zero = {0.f, 0.f, 0.f, 0.f};
        f32x4 acc[4] = {zero, zero, zero, zero};
        #pragma unroll
        for (int kh = 0; kh < 3; ++kh) {
            #pragma unroll
            for (int kw = 0; kw < 3; ++kw) {
                const int pa = (kh + 1) & 1, pb = (kw + 1) & 1;
                const int oh = (pa + 1 - kh) >> 1, ow = (pb + 1 - kw) >> 1;
                const int cls = pa * 2 + pb;
                const int t = kh * 3 + kw;
                int pos = (hql + oh) * WP + (wq + ow);
                int sw = pos & 7;
                short8 b0 = Xs[pos * C8 + (lq ^ sw)];
                acc[cls] = __builtin_amdgcn_mfma_f32_16x16x32_bf16(wf[t][0], b0, acc[cls], 0, 0, 0);
                short8 b1 = Xs[pos * C8 + ((4 + lq) ^ sw)];
                acc[cls] = __builtin_amdgcn_mfma_f32_16x16x32_bf16(wf[t][1], b1, acc[cls], 0, 0, 0);
            }
        }
        int hq = hqb + hql;
        #pragma unroll
        for (int cls = 0; cls < 4; ++cls) {
            int pa = cls >> 1, pb = cls & 1;
            int ho = hq * 2 + pa, wo = wq * 2 + pb;
            __align__(8) bf16 ov[4];
            #pragma unroll
            for (int r = 0; r < 4; ++r) ov[r] = f2b(fmaxf(acc[cls][r] + bv[r], 0.f));
            *reinterpret_cast<uint2*>(yi + ((size_t)(ho * WOUT + wo)) * COUT + nt * 16 + lq * 4)
                = *reinterpret_cast<uint2*>(ov);
        }
    }
}

// ============ MFMA transpose-conv stride 1 (32->16) + fused 1x1 (16->3) ============
// in [img][32][32][32] bf16; out dec [img][3][32][32] fp32 NCHW; wtb [9][16][32]
__global__ __launch_bounds__(256)
void convt1_mfma_fused(const bf16* __restrict__ xg, const bf16* __restrict__ wtb,
                       const float* __restrict__ bias,
                       const float* __restrict__ w4, const float* __restrict__ b4,
                       float* __restrict__ dec)
{
    constexpr int CIN = 32, C8 = 4;
    constexpr int H = 32, W = 32, HR = 18, WR = 34, NPOS = HR * WR;
    __shared__ short8 Xs[NPOS * C8];

    const int img  = blockIdx.x >> 1;
    const int half = blockIdx.x & 1;
    const int hbase = half * 16;
    const bf16* xi = xg + (size_t)img * H * W * CIN;

    for (int e = threadIdx.x; e < NPOS * C8; e += 256) {
        int c8 = e & 3, pos = e >> 2;
        int hr = pos / WR, wr = pos % WR;
        int hi = hbase - 1 + hr, wi = wr - 1;
        short8 v = s8zero();
        if ((unsigned)hi < (unsigned)H && (unsigned)wi < (unsigned)W)
            v = *reinterpret_cast<const short8*>(xi + ((size_t)(hi * W + wi)) * CIN + c8 * 8);
        Xs[pos * C8 + (c8 ^ (pos & 3))] = v;
    }
    __syncthreads();

    const int wv = threadIdx.x >> 6, lane = threadIdx.x & 63;
    const int lp = lane & 15, lq = lane >> 4;

    short8 wf[9];
    #pragma unroll
    for (int t = 0; t < 9; ++t)
        wf[t] = *reinterpret_cast<const short8*>(wtb + ((size_t)t * 16 + lp) * CIN + lq * 8);
    float bv[4];
    #pragma unroll
    for (int r = 0; r < 4; ++r) bv[r] = bias[lq * 4 + r];
    float w4r[3][4];
    #pragma unroll
    for (int j = 0; j < 3; ++j)
        #pragma unroll
        for (int r = 0; r < 4; ++r) w4r[j][r] = w4[j * 16 + lq * 4 + r];
    float b4r[3] = {b4[0], b4[1], b4[2]};

    for (int mt = wv; mt < 32; mt += 4) {
        int m = mt * 16 + lp;
        int hol = m >> 5, wo = m & 31;
        f32x4 acc = {0.f, 0.f, 0.f, 0.f};
        #pragma unroll
        for (int t = 0; t < 9; ++t) {
            int kh = t / 3, kw = t % 3;
            int pos = (hol + 2 - kh) * WR + (wo + 2 - kw);
            short8 b0 = Xs[pos * C8 + (lq ^ (pos & 3))];
            acc = __builtin_amdgcn_mfma_f32_16x16x32_bf16(wf[t], b0, acc, 0, 0, 0);
        }
        float s0 = 0.f, s1 = 0.f, s2 = 0.f;
        #pragma unroll
        for (int r = 0; r < 4; ++r) {
            float v = fmaxf(acc[r] + bv[r], 0.f);
            s0 += v * w4r[0][r]; s1 += v * w4r[1][r]; s2 += v * w4r[2][r];
        }
        s0 += __shfl_xor(s0, 16); s0 += __shfl_xor(s0, 32);
        s1 += __shfl_xor(s1, 16); s1 += __shfl_xor(s1, 32);
        s2 += __shfl_xor(s2, 16); s2 += __shfl_xor(s2, 32);
        if (lq == 0) {
            int ho = hbase + hol;
            size_t base = (size_t)img * 3072 + ho * 32 + wo;
            dec[base]        = s0 + b4r[0];
            dec[base + 1024] = s1 + b4r[1];
            dec[base + 2048] = s2 + b4r[2];
        }
    }
}

// ---------------- embedding: sigmoid(h3_nhwc . kw^T + kb); dual-writes h3 bf16 ----------------
__global__ void emb_kernel(const float* __restrict__ h3, const float* __restrict__ kw,
                           const float* __restrict__ kb, float* __restrict__ emb,
                           bf16* __restrict__ h3b)
{
    __shared__ float rt[64 * 68];
    const int n = blockIdx.x;
    const float4* src = (const float4*)(h3 + (size_t)n * 4096);
    for (int k4 = threadIdx.x; k4 < 1024; k4 += blockDim.x) {
        float4 v = src[k4];
        int k = k4 * 4, p = k >> 6, ci = k & 63;
        rt[(ci + 0) * 68 + p] = v.x;
        rt[(ci + 1) * 68 + p] = v.y;
        rt[(ci + 2) * 68 + p] = v.z;
        rt[(ci + 3) * 68 + p] = v.w;
        __align__(8) bf16 ov[4] = {f2b(v.x), f2b(v.y), f2b(v.z), f2b(v.w)};
        *reinterpret_cast<uint2*>(h3b + (size_t)n * 4096 + k) = *reinterpret_cast<uint2*>(ov);
    }
    __syncthreads();
    const int e = threadIdx.x;
    if (e < 110) {
        const float4* kwr = (const float4*)(kw + (size_t)e * 4096);
        float s0 = 0.f, s1 = 0.f, s2 = 0.f, s3 = 0.f;
        for (int k4 = 0; k4 < 1024; ++k4) {
            float4 wv = kwr[k4];
            int k = k4 * 4, ci = k >> 6, p = k & 63;
            const float* rp = &rt[ci * 68 + p];
            s0 += rp[0] * wv.x; s1 += rp[1] * wv.y;
            s2 += rp[2] * wv.z; s3 += rp[3] * wv.w;
        }
        float acc = kb[e] + ((s0 + s1) + (s2 + s3));
        emb[(size_t)n * 110 + e] = 1.f / (1.f + expf(-acc));
    }
}

// ---------------- KDE ----------------
__global__ void kde_kernel(const float* __restrict__ emb, float* __restrict__ fd)
{
    int idx = blockIdx.x * blockDim.x + threadIdx.x;
    if (idx >= 64 * 110) return;
    int f = idx % 110, b = idx / 110;
    float dens[11];
    #pragma unroll
    for (int j = 0; j < 11; ++j) dens[j] = 0.f;
    const float* ep = emb + (size_t)b * 32 * 110 + f;
    for (int n = 0; n < 32; ++n) {
        float e = ep[n * 110];
        #pragma unroll
        for (int j = 0; j < 11; ++j) {
            float d = 0.1f * j - e;
            dens[j] += expf(-50.f * d * d);
        }
    }
    float s = 0.f;
    #pragma unroll
    for (int j = 0; j < 11; ++j) s += dens[j];
    float inv = 1.f / s;
    float* op = fd + (size_t)b * 1210 + f * 11;
    #pragma unroll
    for (int j = 0; j < 11; ++j) op[j] = dens[j] * inv;
}

// ---------------- dense ----------------
template<int K, int OUT>
__global__ void dense_kernel(const float* __restrict__ in, const float* __restrict__ w,
                             const float* __restrict__ b, float* __restrict__ out,
                             int rows, int relu)
{
    int idx = blockIdx.x * blockDim.x + threadIdx.x;
    if (idx >= rows * OUT) return;
    int o = idx % OUT, r = idx / OUT;
    float acc = b[o];
    const float* ir = in + (size_t)r * K;
    const float* wr = w  + (size_t)o * K;
    for (int k = 0; k < K; ++k) acc += ir[k] * wr[k];
    if (relu) acc = fmaxf(acc, 0.f);
    out[idx] = acc;
}

// ===================== host side =====================
static Taps4 mk_conv9()
{
    Taps4 T = {};
    T.t[0].n = 9;
    int q = 0;
    for (int kh = 0; kh < 3; ++kh)
        for (int kw = 0; kw < 3; ++kw) {
            T.t[0].oh[q] = kh - 1; T.t[0].ow[q] = kw - 1; T.t[0].ti[q] = kh * 3 + kw; ++q;
        }
    return T;
}

extern "C" void kernel_launch(void* const* d_in, const int* in_sizes, int n_in,
                              void* d_out, int out_size, void* d_ws, size_t ws_size,
                              hipStream_t stream)
{
    const float* x    = (const float*)d_in[0];
    const float* ew1  = (const float*)d_in[1];
    const float* eb1  = (const float*)d_in[2];
    const float* ew2  = (const float*)d_in[3];
    const float* eb2  = (const float*)d_in[4];
    const float* ew3  = (const float*)d_in[5];
    const float* eb3  = (const float*)d_in[6];
    const float* kw   = (const float*)d_in[7];
    const float* kb   = (const float*)d_in[8];
    const float* dw1  = (const float*)d_in[9];
    const float* db1  = (const float*)d_in[10];
    const float* dw2  = (const float*)d_in[11];
    const float* db2  = (const float*)d_in[12];
    const float* dw3  = (const float*)d_in[13];
    const float* db3  = (const float*)d_in[14];
    const float* dw4  = (const float*)d_in[15];
    const float* db4  = (const float*)d_in[16];
    const float* f1w  = (const float*)d_in[17];
    const float* f1b  = (const float*)d_in[18];
    const float* f2w  = (const float*)d_in[19];
    const float* f2b_ = (const float*)d_in[20];
    const float* f3w  = (const float*)d_in[21];
    const float* f3b  = (const float*)d_in[22];

    // ---------- workspace ----------
    char* ws = (char*)d_ws;
    float* emb  = (float*)(ws + 0);         //   901,120
    float* fd   = (float*)(ws + 901120);    //   309,760
    float* m1   = (float*)(ws + 1210880);   //   131,072
    float* m2   = (float*)(ws + 1341952);   //    65,536
    float* wt1  = (float*)(ws + 1407488);   //     1,792
    float* wt2  = (float*)(ws + 1409280);   //    18,432
    float* wt3  = (float*)(ws + 1427712);   //    73,728
    bf16*  wtb4 = (bf16*) (ws + 1501440);   //    73,728 (9*64*64 bf16)
    bf16*  wtb5 = (bf16*) (ws + 1575168);   //    36,864 (9*64*32)
    bf16*  wtb6 = (bf16*) (ws + 1612032);   //     9,216 (9*16*32)
    const size_t FIXED = 1621248;

    // per image: h1(fp32,64K, d1b overlays) | h2 32K | h3 16K | h3b 8K | d2b 64K
    const size_t PER_IMG = 188416;
    int CHUNK = 512;
    while (CHUNK > 8 && FIXED + (size_t)CHUNK * PER_IMG > ws_size) CHUNK >>= 1;
    const int NCHUNK = 2048 / CHUNK;

    char* p   = ws + FIXED;
    float* h1  = (float*)(p);
    float* h2  = (float*)(p + (size_t)CHUNK * 65536);
    float* h3  = (float*)(p + (size_t)CHUNK * 98304);
    bf16*  h3b = (bf16*) (p + (size_t)CHUNK * 114688);
    bf16*  d2b = (bf16*) (p + (size_t)CHUNK * 122880);
    bf16*  d1b = (bf16*)h1;                  // overlay: h1 dead after enc2

    float* logits = (float*)d_out;           // 64*4
    float* dec    = (float*)d_out + 256;     // 2048*3*32*32 NCHW

    // ---- weight transforms (once per launch) ----
    wtr_conv  <<<(16*3*9  + 255)/256, 256, 0, stream>>>(ew1, wt1, 16, 3);
    wtr_conv  <<<(32*16*9 + 255)/256, 256, 0, stream>>>(ew2, wt2, 32, 16);
    wtr_conv  <<<(64*32*9 + 255)/256, 256, 0, stream>>>(ew3, wt3, 64, 32);
    wtrb_convt<<<(64*64*9 + 255)/256, 256, 0, stream>>>(dw1, wtb4, 64, 64);
    wtrb_convt<<<(64*32*9 + 255)/256, 256, 0, stream>>>(dw2, wtb5, 64, 32);
    wtrb_convt<<<(32*16*9 + 255)/256, 256, 0, stream>>>(dw3, wtb6, 32, 16);

    const Taps4 T9 = mk_conv9();

    for (int c = 0; c < NCHUNK; ++c) {
        const float* xc   = x   + (size_t)c * CHUNK * 3 * 1024;
        float*       decc = dec + (size_t)c * CHUNK * 3 * 1024;
        float*       embc = emb + (size_t)c * CHUNK * 110;

        // encoder (fp32)
        conv_gemm<3,16,32,32,32,32, 1,1, 16,16, 3, true>
            <<<dim3(CHUNK*4,1), 256, 0, stream>>>(xc, wt1, eb1, h1, T9);
        conv_gemm<16,32,32,32,16,16, 2,1, 8,16, 16, false>
            <<<dim3(CHUNK*2,1), 256, 0, stream>>>(h1, wt2, eb2, h2, T9);
        conv_gemm<32,64,16,16,8,8, 2,1, 8,8, 16, false>
            <<<dim3(CHUNK,1), 256, 0, stream>>>(h2, wt3, eb3, h3, T9);

        // embedding (+h3 bf16 cast)
        emb_kernel<<<CHUNK, 128, 0, stream>>>(h3, kw, kb, embc, h3b);

        // decoder (bf16 MFMA, all-static tap loops)
        convt2_mfma<64, 8, 8, 1>  <<<dim3(CHUNK,1), 256, 0, stream>>>(h3b, wtb4, db1, d1b);
        convt2_mfma<32, 16, 16, 2><<<dim3(CHUNK,2), 256, 0, stream>>>(d1b, wtb5, db2, d2b);
        convt1_mfma_fused         <<<dim3(CHUNK*2,1), 256, 0, stream>>>(d2b, wtb6, db3, dw4, db4, decc);
    }

    // classifier (fp32)
    kde_kernel<<<(64*110+255)/256, 256, 0, stream>>>(emb, fd);
    dense_kernel<1210,512><<<(64*512+255)/256, 256, 0, stream>>>(fd, f1w, f1b, m1, 64, 1);
    dense_kernel<512,256><<<(64*256+255)/256, 256, 0, stream>>>(m1, f2w, f2b_, m2, 64, 1);
    dense_kernel<256,4><<<1, 256, 0, stream>>>(m2, f3w, f3b, logits, 64, 0);
}

// Round 10
// 849.074 us; speedup vs baseline: 9.8118x; 1.3100x over previous
//
#include <hip/hip_runtime.h>
#include <hip/hip_bf16.h>
#include <stdint.h>

typedef __hip_bfloat16 bf16;
typedef __attribute__((ext_vector_type(8))) short short8;
typedef __attribute__((ext_vector_type(4))) float f32x4;

__device__ __forceinline__ bf16 f2b(float v){ return __float2bfloat16(v); }
__device__ __forceinline__ short8 s8zero()
{
    short8 z;
    for (int i = 0; i < 8; ++i) z[i] = 0;
    return z;
}

struct Taps  { int n; int oh[9]; int ow[9]; int ti[9]; };
struct Taps4 { Taps t[4]; };

// ===================== fp32 implicit-GEMM conv (encoder) =====================
template<int CIN, int COUT, int HIN, int WIN, int HOUT, int WOUT,
         int A, int OST, int MH, int MW, int KC, bool IN_NCHW, bool OUT_BF16>
__global__ __launch_bounds__(256)
void conv_gemm(const float* __restrict__ x, const float* __restrict__ wt,
               const float* __restrict__ bias, void* __restrict__ yv, Taps4 ts)
{
    constexpr int M   = MH * MW;
    constexpr int N   = COUT;
    constexpr int NT4 = N / 4;
    constexpr int HQ  = HOUT / OST, WQ = WOUT / OST;
    constexpr int TH  = HQ / MH,   TW = WQ / MW;
    constexpr int XSTR = M + 4;
    static_assert(M * N == 4096, "block tile must be 4096");

    __shared__ float Xs[KC * XSTR];
    __shared__ float Ws[KC * N];

    const int tid = threadIdx.x;
    const int mt = tid / NT4, nt = tid % NT4;

    int bx = blockIdx.x;
    const int tw = bx % TW; bx /= TW;
    const int th = bx % TH;
    const int n  = bx / TH;
    const int hq0 = th * MH, wq0 = tw * MW;

    float bv[4];
    #pragma unroll
    for (int j = 0; j < 4; ++j) bv[j] = bias[nt * 4 + j];

    float acc[4][4];
    #pragma unroll
    for (int i = 0; i < 4; ++i)
        #pragma unroll
        for (int j = 0; j < 4; ++j) acc[i][j] = 0.f;

    const int ntaps = ts.t[0].n;
    for (int t = 0; t < ntaps; ++t) {
        const int oh = ts.t[0].oh[t];
        const int ow = ts.t[0].ow[t];
        const int ti = ts.t[0].ti[t];
        const float* wtp = wt + (size_t)(ti * CIN) * N;
        for (int c0 = 0; c0 < CIN; c0 += KC) {
            __syncthreads();
            for (int e = tid; e < KC * N; e += 256)
                Ws[e] = wtp[(size_t)c0 * N + e];
            for (int e = tid; e < M * KC; e += 256) {
                int k, m;
                if (IN_NCHW) { k = e / M;  m = e % M; }
                else         { k = e % KC; m = e / KC; }
                const int hq = hq0 + m / MW;
                const int wq = wq0 + m % MW;
                const int hi = hq * A + oh;
                const int wi = wq * A + ow;
                float v = 0.f;
                if ((unsigned)hi < (unsigned)HIN && (unsigned)wi < (unsigned)WIN) {
                    if (IN_NCHW)
                        v = x[(((size_t)n * CIN + c0 + k) * HIN + hi) * WIN + wi];
                    else
                        v = x[(((size_t)n * HIN + hi) * WIN + wi) * CIN + c0 + k];
                }
                Xs[k * XSTR + m] = v;
            }
            __syncthreads();
            #pragma unroll
            for (int k = 0; k < KC; ++k) {
                float4 av = *reinterpret_cast<const float4*>(&Xs[k * XSTR + mt * 4]);
                float4 bw = *reinterpret_cast<const float4*>(&Ws[k * N + nt * 4]);
                acc[0][0] += av.x * bw.x; acc[0][1] += av.x * bw.y;
                acc[0][2] += av.x * bw.z; acc[0][3] += av.x * bw.w;
                acc[1][0] += av.y * bw.x; acc[1][1] += av.y * bw.y;
                acc[1][2] += av.y * bw.z; acc[1][3] += av.y * bw.w;
                acc[2][0] += av.z * bw.x; acc[2][1] += av.z * bw.y;
                acc[2][2] += av.z * bw.z; acc[2][3] += av.z * bw.w;
                acc[3][0] += av.w * bw.x; acc[3][1] += av.w * bw.y;
                acc[3][2] += av.w * bw.z; acc[3][3] += av.w * bw.w;
            }
        }
    }
    #pragma unroll
    for (int i = 0; i < 4; ++i) {
        const int m  = mt * 4 + i;
        const int ho = (hq0 + m / MW);
        const int wo = (wq0 + m % MW);
        const size_t oidx = (((size_t)n * HOUT + ho) * WOUT + wo) * N + nt * 4;
        float o0 = fmaxf(acc[i][0] + bv[0], 0.f);
        float o1 = fmaxf(acc[i][1] + bv[1], 0.f);
        float o2 = fmaxf(acc[i][2] + bv[2], 0.f);
        float o3 = fmaxf(acc[i][3] + bv[3], 0.f);
        if (OUT_BF16) {
            __align__(8) bf16 ov[4] = {f2b(o0), f2b(o1), f2b(o2), f2b(o3)};
            *reinterpret_cast<uint2*>((bf16*)yv + oidx) = *reinterpret_cast<uint2*>(ov);
        } else {
            float4 o = {o0, o1, o2, o3};
            *reinterpret_cast<float4*>((float*)yv + oidx) = o;
        }
    }
}

__global__ void wtr_conv(const float* __restrict__ w, float* __restrict__ wt,
                         int COUT, int CIN)   // w[co][ci][9] -> wt[t][ci][co]
{
    int idx = blockIdx.x * blockDim.x + threadIdx.x;
    if (idx >= COUT * CIN * 9) return;
    int co = idx / (CIN * 9);
    int r  = idx - co * CIN * 9;
    int ci = r / 9, t = r - ci * 9;
    wt[((size_t)t * CIN + ci) * COUT + co] = w[idx];
}

// ============ decoder weight transform: w[ci][co][9] -> wtb[t][co][ci] bf16 ============
__global__ void wtrb_convt(const float* __restrict__ w, bf16* __restrict__ wt,
                           int CIN, int COUT)
{
    int idx = blockIdx.x * blockDim.x + threadIdx.x;
    if (idx >= CIN * COUT * 9) return;
    int ci = idx / (COUT * 9);
    int r  = idx - ci * COUT * 9;
    int co = r / 9, t = r - co * 9;
    wt[((size_t)t * COUT + co) * CIN + ci] = f2b(w[idx]);
}

// ============ kw transform: kw[e][ci*64+pos] -> kwt[e][pos*64+ci] bf16, padded to 112 rows ====
__global__ void wtr_kw(const float* __restrict__ kw, bf16* __restrict__ kwt)
{
    int idx = blockIdx.x * blockDim.x + threadIdx.x;
    if (idx >= 112 * 4096) return;
    int e = idx >> 12, kk = idx & 4095;
    int pos = kk >> 6, ci = kk & 63;
    float v = (e < 110) ? kw[(size_t)e * 4096 + ci * 64 + pos] : 0.f;
    kwt[idx] = f2b(v);
}

// ============ emb = sigmoid(h3b[CHUNK,4096]bf16 @ kwt^T[4096,112]bf16 + kb) -> fp32 ============
// One block per 16 images; 4 waves split K in quarters; LDS cross-wave reduction.
__global__ __launch_bounds__(256)
void emb_mfma(const bf16* __restrict__ h3b, const bf16* __restrict__ kwt,
              const float* __restrict__ kb, float* __restrict__ emb)
{
    __shared__ f32x4 Ls[3][7][64];     // 21,504 B
    const int imgbase = blockIdx.x * 16;
    const int w = threadIdx.x >> 6, lane = threadIdx.x & 63;
    const int lp = lane & 15, lq = lane >> 4;
    const int k0 = w * 1024;

    f32x4 zero = {0.f, 0.f, 0.f, 0.f};
    f32x4 acc[7] = {zero, zero, zero, zero, zero, zero, zero};

    const bf16* bp = h3b + (size_t)(imgbase + lp) * 4096 + k0 + lq * 8;
    const bf16* ap = kwt + (size_t)lp * 4096 + k0 + lq * 8;
    for (int ks = 0; ks < 32; ++ks) {
        short8 bfrag = *reinterpret_cast<const short8*>(bp + ks * 32);
        #pragma unroll
        for (int nt = 0; nt < 7; ++nt) {
            short8 afrag = *reinterpret_cast<const short8*>(ap + (size_t)nt * 16 * 4096 + ks * 32);
            acc[nt] = __builtin_amdgcn_mfma_f32_16x16x32_bf16(afrag, bfrag, acc[nt], 0, 0, 0);
        }
    }
    if (w > 0) {
        #pragma unroll
        for (int nt = 0; nt < 7; ++nt) Ls[w - 1][nt][lane] = acc[nt];
    }
    __syncthreads();
    if (w == 0) {
        #pragma unroll
        for (int nt = 0; nt < 7; ++nt) {
            f32x4 a = acc[nt];
            #pragma unroll
            for (int ww = 0; ww < 3; ++ww) a += Ls[ww][nt][lane];
            // D: col(lane&15)=img, row(lq*4+r)=emb dim within n-tile
            const int e0 = nt * 16 + lq * 4;
            #pragma unroll
            for (int r = 0; r < 4; ++r) {
                int e = e0 + r;
                if (e < 110) {
                    float v = a[r] + kb[e];
                    emb[(size_t)(imgbase + lp) * 110 + e] = 1.f / (1.f + expf(-v));
                }
            }
        }
    }
}

// ============ MFMA transpose-conv stride 2: ALL 4 parity classes per block ============
template<int COUT, int HIN, int WIN, int HSPLIT>
__global__ __launch_bounds__(256)
void convt2_mfma(const bf16* __restrict__ xg, const bf16* __restrict__ wtb,
                 const float* __restrict__ bias, bf16* __restrict__ yg)
{
    constexpr int CIN = 64, C8 = 8;
    constexpr int WP  = WIN + 1;
    constexpr int HS  = HIN / HSPLIT;
    constexpr int HPS = HS + 1;
    constexpr int NPOS = HPS * WP;
    constexpr int HOUT = HIN * 2, WOUT = WIN * 2;
    constexpr int NT = COUT / 16;
    constexpr int MT = (HS * WIN) / 16;
    __shared__ short8 Xs[NPOS * C8];

    const int img = blockIdx.x;
    const int s   = blockIdx.y;
    const int hqb = s * HS;
    const bf16* xi = xg + (size_t)img * HIN * WIN * CIN;

    for (int e = threadIdx.x; e < NPOS * C8; e += 256) {
        int c8 = e & 7, pos = e >> 3;
        int hl = pos / WP, wi = pos % WP;
        int hi = hqb + hl;
        short8 v = s8zero();
        if (hi < HIN && wi < WIN)
            v = *reinterpret_cast<const short8*>(xi + ((size_t)(hi * WIN + wi)) * CIN + c8 * 8);
        Xs[pos * C8 + (c8 ^ (pos & 7))] = v;
    }
    __syncthreads();

    const int wv = threadIdx.x >> 6, lane = threadIdx.x & 63;
    const int lp = lane & 15, lq = lane >> 4;
    const int nt    = (NT == 4) ? wv : (wv & 1);
    const int mt0   = (NT == 4) ? 0  : (wv >> 1) * (MT / 2);
    const int mtend = (NT == 4) ? MT : mt0 + (MT / 2);

    short8 wf[9][2];
    #pragma unroll
    for (int t = 0; t < 9; ++t) {
        const bf16* wp = wtb + ((size_t)t * COUT + nt * 16 + lp) * CIN + lq * 8;
        wf[t][0] = *reinterpret_cast<const short8*>(wp);
        wf[t][1] = *reinterpret_cast<const short8*>(wp + 32);
    }
    float bv[4];
    #pragma unroll
    for (int r = 0; r < 4; ++r) bv[r] = bias[nt * 16 + lq * 4 + r];

    bf16* yi = yg + (size_t)img * HOUT * WOUT * COUT;
    for (int mt = mt0; mt < mtend; ++mt) {
        int m = mt * 16 + lp;
        int hql = m / WIN, wq = m % WIN;
        f32x4 zero = {0.f, 0.f, 0.f, 0.f};
        f32x4 acc[4] = {zero, zero, zero, zero};
        #pragma unroll
        for (int kh = 0; kh < 3; ++kh) {
            #pragma unroll
            for (int kw = 0; kw < 3; ++kw) {
                const int pa = (kh + 1) & 1, pb = (kw + 1) & 1;
                const int oh = (pa + 1 - kh) >> 1, ow = (pb + 1 - kw) >> 1;
                const int cls = pa * 2 + pb;
                const int t = kh * 3 + kw;
                int pos = (hql + oh) * WP + (wq + ow);
                int sw = pos & 7;
                short8 b0 = Xs[pos * C8 + (lq ^ sw)];
                acc[cls] = __builtin_amdgcn_mfma_f32_16x16x32_bf16(wf[t][0], b0, acc[cls], 0, 0, 0);
                short8 b1 = Xs[pos * C8 + ((4 + lq) ^ sw)];
                acc[cls] = __builtin_amdgcn_mfma_f32_16x16x32_bf16(wf[t][1], b1, acc[cls], 0, 0, 0);
            }
        }
        int hq = hqb + hql;
        #pragma unroll
        for (int cls = 0; cls < 4; ++cls) {
            int pa = cls >> 1, pb = cls & 1;
            int ho = hq * 2 + pa, wo = wq * 2 + pb;
            __align__(8) bf16 ov[4];
            #pragma unroll
            for (int r = 0; r < 4; ++r) ov[r] = f2b(fmaxf(acc[cls][r] + bv[r], 0.f));
            *reinterpret_cast<uint2*>(yi + ((size_t)(ho * WOUT + wo)) * COUT + nt * 16 + lq * 4)
                = *reinterpret_cast<uint2*>(ov);
        }
    }
}

// ============ MFMA transpose-conv stride 1 (32->16) + fused 1x1 (16->3) ============
__global__ __launch_bounds__(256)
void convt1_mfma_fused(const bf16* __restrict__ xg, const bf16* __restrict__ wtb,
                       const float* __restrict__ bias,
                       const float* __restrict__ w4, const float* __restrict__ b4,
                       float* __restrict__ dec)
{
    constexpr int CIN = 32, C8 = 4;
    constexpr int H = 32, W = 32, HR = 18, WR = 34, NPOS = HR * WR;
    __shared__ short8 Xs[NPOS * C8];

    const int img  = blockIdx.x >> 1;
    const int half = blockIdx.x & 1;
    const int hbase = half * 16;
    const bf16* xi = xg + (size_t)img * H * W * CIN;

    for (int e = threadIdx.x; e < NPOS * C8; e += 256) {
        int c8 = e & 3, pos = e >> 2;
        int hr = pos / WR, wr = pos % WR;
        int hi = hbase - 1 + hr, wi = wr - 1;
        short8 v = s8zero();
        if ((unsigned)hi < (unsigned)H && (unsigned)wi < (unsigned)W)
            v = *reinterpret_cast<const short8*>(xi + ((size_t)(hi * W + wi)) * CIN + c8 * 8);
        Xs[pos * C8 + (c8 ^ (pos & 3))] = v;
    }
    __syncthreads();

    const int wv = threadIdx.x >> 6, lane = threadIdx.x & 63;
    const int lp = lane & 15, lq = lane >> 4;

    short8 wf[9];
    #pragma unroll
    for (int t = 0; t < 9; ++t)
        wf[t] = *reinterpret_cast<const short8*>(wtb + ((size_t)t * 16 + lp) * CIN + lq * 8);
    float bv[4];
    #pragma unroll
    for (int r = 0; r < 4; ++r) bv[r] = bias[lq * 4 + r];
    float w4r[3][4];
    #pragma unroll
    for (int j = 0; j < 3; ++j)
        #pragma unroll
        for (int r = 0; r < 4; ++r) w4r[j][r] = w4[j * 16 + lq * 4 + r];
    float b4r[3] = {b4[0], b4[1], b4[2]};

    for (int mt = wv; mt < 32; mt += 4) {
        int m = mt * 16 + lp;
        int hol = m >> 5, wo = m & 31;
        f32x4 acc = {0.f, 0.f, 0.f, 0.f};
        #pragma unroll
        for (int t = 0; t < 9; ++t) {
            int kh = t / 3, kw = t % 3;
            int pos = (hol + 2 - kh) * WR + (wo + 2 - kw);
            short8 b0 = Xs[pos * C8 + (lq ^ (pos & 3))];
            acc = __builtin_amdgcn_mfma_f32_16x16x32_bf16(wf[t], b0, acc, 0, 0, 0);
        }
        float s0 = 0.f, s1 = 0.f, s2 = 0.f;
        #pragma unroll
        for (int r = 0; r < 4; ++r) {
            float v = fmaxf(acc[r] + bv[r], 0.f);
            s0 += v * w4r[0][r]; s1 += v * w4r[1][r]; s2 += v * w4r[2][r];
        }
        s0 += __shfl_xor(s0, 16); s0 += __shfl_xor(s0, 32);
        s1 += __shfl_xor(s1, 16); s1 += __shfl_xor(s1, 32);
        s2 += __shfl_xor(s2, 16); s2 += __shfl_xor(s2, 32);
        if (lq == 0) {
            int ho = hbase + hol;
            size_t base = (size_t)img * 3072 + ho * 32 + wo;
            dec[base]        = s0 + b4r[0];
            dec[base + 1024] = s1 + b4r[1];
            dec[base + 2048] = s2 + b4r[2];
        }
    }
}

// ---------------- KDE ----------------
__global__ void kde_kernel(const float* __restrict__ emb, float* __restrict__ fd)
{
    int idx = blockIdx.x * blockDim.x + threadIdx.x;
    if (idx >= 64 * 110) return;
    int f = idx % 110, b = idx / 110;
    float dens[11];
    #pragma unroll
    for (int j = 0; j < 11; ++j) dens[j] = 0.f;
    const float* ep = emb + (size_t)b * 32 * 110 + f;
    for (int n = 0; n < 32; ++n) {
        float e = ep[n * 110];
        #pragma unroll
        for (int j = 0; j < 11; ++j) {
            float d = 0.1f * j - e;
            dens[j] += expf(-50.f * d * d);
        }
    }
    float s = 0.f;
    #pragma unroll
    for (int j = 0; j < 11; ++j) s += dens[j];
    float inv = 1.f / s;
    float* op = fd + (size_t)b * 1210 + f * 11;
    #pragma unroll
    for (int j = 0; j < 11; ++j) op[j] = dens[j] * inv;
}

// ---------------- dense ----------------
template<int K, int OUT>
__global__ void dense_kernel(const float* __restrict__ in, const float* __restrict__ w,
                             const float* __restrict__ b, float* __restrict__ out,
                             int rows, int relu)
{
    int idx = blockIdx.x * blockDim.x + threadIdx.x;
    if (idx >= rows * OUT) return;
    int o = idx % OUT, r = idx / OUT;
    float acc = b[o];
    const float* ir = in + (size_t)r * K;
    const float* wr = w  + (size_t)o * K;
    for (int k = 0; k < K; ++k) acc += ir[k] * wr[k];
    if (relu) acc = fmaxf(acc, 0.f);
    out[idx] = acc;
}

// ===================== host side =====================
static Taps4 mk_conv9()
{
    Taps4 T = {};
    T.t[0].n = 9;
    int q = 0;
    for (int kh = 0; kh < 3; ++kh)
        for (int kw = 0; kw < 3; ++kw) {
            T.t[0].oh[q] = kh - 1; T.t[0].ow[q] = kw - 1; T.t[0].ti[q] = kh * 3 + kw; ++q;
        }
    return T;
}

extern "C" void kernel_launch(void* const* d_in, const int* in_sizes, int n_in,
                              void* d_out, int out_size, void* d_ws, size_t ws_size,
                              hipStream_t stream)
{
    const float* x    = (const float*)d_in[0];
    const float* ew1  = (const float*)d_in[1];
    const float* eb1  = (const float*)d_in[2];
    const float* ew2  = (const float*)d_in[3];
    const float* eb2  = (const float*)d_in[4];
    const float* ew3  = (const float*)d_in[5];
    const float* eb3  = (const float*)d_in[6];
    const float* kw   = (const float*)d_in[7];
    const float* kb   = (const float*)d_in[8];
    const float* dw1  = (const float*)d_in[9];
    const float* db1  = (const float*)d_in[10];
    const float* dw2  = (const float*)d_in[11];
    const float* db2  = (const float*)d_in[12];
    const float* dw3  = (const float*)d_in[13];
    const float* db3  = (const float*)d_in[14];
    const float* dw4  = (const float*)d_in[15];
    const float* db4  = (const float*)d_in[16];
    const float* f1w  = (const float*)d_in[17];
    const float* f1b  = (const float*)d_in[18];
    const float* f2w  = (const float*)d_in[19];
    const float* f2b_ = (const float*)d_in[20];
    const float* f3w  = (const float*)d_in[21];
    const float* f3b  = (const float*)d_in[22];

    // ---------- workspace ----------
    char* ws = (char*)d_ws;
    float* emb  = (float*)(ws + 0);         //   901,120
    float* fd   = (float*)(ws + 901120);    //   309,760
    float* m1   = (float*)(ws + 1210880);   //   131,072
    float* m2   = (float*)(ws + 1341952);   //    65,536
    float* wt1  = (float*)(ws + 1407488);   //     1,792
    float* wt2  = (float*)(ws + 1409280);   //    18,432
    float* wt3  = (float*)(ws + 1427712);   //    73,728
    bf16*  wtb4 = (bf16*) (ws + 1501440);   //    73,728 (9*64*64 bf16)
    bf16*  wtb5 = (bf16*) (ws + 1575168);   //    36,864 (9*64*32)
    bf16*  wtb6 = (bf16*) (ws + 1612032);   //     9,216 (9*16*32)
    bf16*  kwt  = (bf16*) (ws + 1621248);   //   917,504 (112*4096 bf16)
    const size_t FIXED = 2538752;

    // per image: h1(fp32,64K; d1b overlays) | h2 32K | h3b 8K | d2b 64K
    const size_t PER_IMG = 172032;
    int CHUNK = 512;
    while (CHUNK > 16 && FIXED + (size_t)CHUNK * PER_IMG > ws_size) CHUNK >>= 1;
    const int NCHUNK = 2048 / CHUNK;

    char* p   = ws + FIXED;
    float* h1  = (float*)(p);
    float* h2  = (float*)(p + (size_t)CHUNK * 65536);
    bf16*  h3b = (bf16*) (p + (size_t)CHUNK * 98304);
    bf16*  d2b = (bf16*) (p + (size_t)CHUNK * 106496);
    bf16*  d1b = (bf16*)h1;                  // overlay: h1 dead after enc2

    float* logits = (float*)d_out;           // 64*4
    float* dec    = (float*)d_out + 256;     // 2048*3*32*32 NCHW

    // ---- weight transforms (once per launch) ----
    wtr_conv  <<<(16*3*9  + 255)/256, 256, 0, stream>>>(ew1, wt1, 16, 3);
    wtr_conv  <<<(32*16*9 + 255)/256, 256, 0, stream>>>(ew2, wt2, 32, 16);
    wtr_conv  <<<(64*32*9 + 255)/256, 256, 0, stream>>>(ew3, wt3, 64, 32);
    wtrb_convt<<<(64*64*9 + 255)/256, 256, 0, stream>>>(dw1, wtb4, 64, 64);
    wtrb_convt<<<(64*32*9 + 255)/256, 256, 0, stream>>>(dw2, wtb5, 64, 32);
    wtrb_convt<<<(32*16*9 + 255)/256, 256, 0, stream>>>(dw3, wtb6, 32, 16);
    wtr_kw    <<<(112*4096 + 255)/256, 256, 0, stream>>>(kw, kwt);

    const Taps4 T9 = mk_conv9();

    for (int c = 0; c < NCHUNK; ++c) {
        const float* xc   = x   + (size_t)c * CHUNK * 3 * 1024;
        float*       decc = dec + (size_t)c * CHUNK * 3 * 1024;
        float*       embc = emb + (size_t)c * CHUNK * 110;

        // encoder (fp32; enc3 writes bf16 NHWC h3b directly)
        conv_gemm<3,16,32,32,32,32, 1,1, 16,16, 3, true, false>
            <<<dim3(CHUNK*4,1), 256, 0, stream>>>(xc, wt1, eb1, h1, T9);
        conv_gemm<16,32,32,32,16,16, 2,1, 8,16, 16, false, false>
            <<<dim3(CHUNK*2,1), 256, 0, stream>>>(h1, wt2, eb2, h2, T9);
        conv_gemm<32,64,16,16,8,8, 2,1, 8,8, 16, false, true>
            <<<dim3(CHUNK,1), 256, 0, stream>>>(h2, wt3, eb3, h3b, T9);

        // embedding (bf16 MFMA GEMM)
        emb_mfma<<<CHUNK/16, 256, 0, stream>>>(h3b, kwt, kb, embc);

        // decoder (bf16 MFMA, all-static tap loops)
        convt2_mfma<64, 8, 8, 1>  <<<dim3(CHUNK,1), 256, 0, stream>>>(h3b, wtb4, db1, d1b);
        convt2_mfma<32, 16, 16, 2><<<dim3(CHUNK,2), 256, 0, stream>>>(d1b, wtb5, db2, d2b);
        convt1_mfma_fused         <<<dim3(CHUNK*2,1), 256, 0, stream>>>(d2b, wtb6, db3, dw4, db4, decc);
    }

    // classifier (fp32)
    kde_kernel<<<(64*110+255)/256, 256, 0, stream>>>(emb, fd);
    dense_kernel<1210,512><<<(64*512+255)/256, 256, 0, stream>>>(fd, f1w, f1b, m1, 64, 1);
    dense_kernel<512,256><<<(64*256+255)/256, 256, 0, stream>>>(m1, f2w, f2b_, m2, 64, 1);
    dense_kernel<256,4><<<1, 256, 0, stream>>>(m2, f3w, f3b, logits, 64, 0);
}

// Round 11
// 608.477 us; speedup vs baseline: 13.6914x; 1.3954x over previous
//
#include <hip/hip_runtime.h>
#include <hip/hip_bf16.h>
#include <stdint.h>

typedef __hip_bfloat16 bf16;
typedef __attribute__((ext_vector_type(8))) short short8;
typedef __attribute__((ext_vector_type(4))) float f32x4;

__device__ __forceinline__ bf16 f2b(float v){ return __float2bfloat16(v); }
__device__ __forceinline__ short8 s8zero()
{
    short8 z;
    for (int i = 0; i < 8; ++i) z[i] = 0;
    return z;
}

struct Taps  { int n; int oh[9]; int ow[9]; int ti[9]; };
struct Taps4 { Taps t[4]; };

// ===================== fp32 implicit-GEMM conv (enc1 only) =====================
template<int CIN, int COUT, int HIN, int WIN, int HOUT, int WOUT,
         int A, int OST, int MH, int MW, int KC, bool IN_NCHW, bool OUT_BF16>
__global__ __launch_bounds__(256)
void conv_gemm(const float* __restrict__ x, const float* __restrict__ wt,
               const float* __restrict__ bias, void* __restrict__ yv, Taps4 ts)
{
    constexpr int M   = MH * MW;
    constexpr int N   = COUT;
    constexpr int NT4 = N / 4;
    constexpr int HQ  = HOUT / OST, WQ = WOUT / OST;
    constexpr int TH  = HQ / MH,   TW = WQ / MW;
    constexpr int XSTR = M + 4;
    static_assert(M * N == 4096, "block tile must be 4096");

    __shared__ float Xs[KC * XSTR];
    __shared__ float Ws[KC * N];

    const int tid = threadIdx.x;
    const int mt = tid / NT4, nt = tid % NT4;

    int bx = blockIdx.x;
    const int tw = bx % TW; bx /= TW;
    const int th = bx % TH;
    const int n  = bx / TH;
    const int hq0 = th * MH, wq0 = tw * MW;

    float bv[4];
    #pragma unroll
    for (int j = 0; j < 4; ++j) bv[j] = bias[nt * 4 + j];

    float acc[4][4];
    #pragma unroll
    for (int i = 0; i < 4; ++i)
        #pragma unroll
        for (int j = 0; j < 4; ++j) acc[i][j] = 0.f;

    const int ntaps = ts.t[0].n;
    for (int t = 0; t < ntaps; ++t) {
        const int oh = ts.t[0].oh[t];
        const int ow = ts.t[0].ow[t];
        const int ti = ts.t[0].ti[t];
        const float* wtp = wt + (size_t)(ti * CIN) * N;
        for (int c0 = 0; c0 < CIN; c0 += KC) {
            __syncthreads();
            for (int e = tid; e < KC * N; e += 256)
                Ws[e] = wtp[(size_t)c0 * N + e];
            for (int e = tid; e < M * KC; e += 256) {
                int k, m;
                if (IN_NCHW) { k = e / M;  m = e % M; }
                else         { k = e % KC; m = e / KC; }
                const int hq = hq0 + m / MW;
                const int wq = wq0 + m % MW;
                const int hi = hq * A + oh;
                const int wi = wq * A + ow;
                float v = 0.f;
                if ((unsigned)hi < (unsigned)HIN && (unsigned)wi < (unsigned)WIN) {
                    if (IN_NCHW)
                        v = x[(((size_t)n * CIN + c0 + k) * HIN + hi) * WIN + wi];
                    else
                        v = x[(((size_t)n * HIN + hi) * WIN + wi) * CIN + c0 + k];
                }
                Xs[k * XSTR + m] = v;
            }
            __syncthreads();
            #pragma unroll
            for (int k = 0; k < KC; ++k) {
                float4 av = *reinterpret_cast<const float4*>(&Xs[k * XSTR + mt * 4]);
                float4 bw = *reinterpret_cast<const float4*>(&Ws[k * N + nt * 4]);
                acc[0][0] += av.x * bw.x; acc[0][1] += av.x * bw.y;
                acc[0][2] += av.x * bw.z; acc[0][3] += av.x * bw.w;
                acc[1][0] += av.y * bw.x; acc[1][1] += av.y * bw.y;
                acc[1][2] += av.y * bw.z; acc[1][3] += av.y * bw.w;
                acc[2][0] += av.z * bw.x; acc[2][1] += av.z * bw.y;
                acc[2][2] += av.z * bw.z; acc[2][3] += av.z * bw.w;
                acc[3][0] += av.w * bw.x; acc[3][1] += av.w * bw.y;
                acc[3][2] += av.w * bw.z; acc[3][3] += av.w * bw.w;
            }
        }
    }
    #pragma unroll
    for (int i = 0; i < 4; ++i) {
        const int m  = mt * 4 + i;
        const int ho = (hq0 + m / MW);
        const int wo = (wq0 + m % MW);
        const size_t oidx = (((size_t)n * HOUT + ho) * WOUT + wo) * N + nt * 4;
        float o0 = fmaxf(acc[i][0] + bv[0], 0.f);
        float o1 = fmaxf(acc[i][1] + bv[1], 0.f);
        float o2 = fmaxf(acc[i][2] + bv[2], 0.f);
        float o3 = fmaxf(acc[i][3] + bv[3], 0.f);
        if (OUT_BF16) {
            __align__(8) bf16 ov[4] = {f2b(o0), f2b(o1), f2b(o2), f2b(o3)};
            *reinterpret_cast<uint2*>((bf16*)yv + oidx) = *reinterpret_cast<uint2*>(ov);
        } else {
            float4 o = {o0, o1, o2, o3};
            *reinterpret_cast<float4*>((float*)yv + oidx) = o;
        }
    }
}

__global__ void wtr_conv(const float* __restrict__ w, float* __restrict__ wt,
                         int COUT, int CIN)   // w[co][ci][9] -> wt[t][ci][co]
{
    int idx = blockIdx.x * blockDim.x + threadIdx.x;
    if (idx >= COUT * CIN * 9) return;
    int co = idx / (CIN * 9);
    int r  = idx - co * CIN * 9;
    int ci = r / 9, t = r - ci * 9;
    wt[((size_t)t * CIN + ci) * COUT + co] = w[idx];
}

// ==== enc2 paired weights: ew2[co 32][ci 16][9] -> wte2[p 5][co 32][k 32] bf16 ====
// k<16: ch k of tap 2p; k>=16: ch k-16 of tap 2p+1 (p=4 upper half = 0)
__global__ void wtrb_enc2(const float* __restrict__ w, bf16* __restrict__ wt)
{
    int idx = blockIdx.x * blockDim.x + threadIdx.x;
    if (idx >= 5 * 32 * 32) return;
    int p = idx >> 10, r = idx & 1023;
    int co = r >> 5, k = r & 31;
    int t = 2 * p + (k >> 4);
    int ch = k & 15;
    float v = (t <= 8) ? w[((size_t)co * 16 + ch) * 9 + t] : 0.f;
    wt[idx] = f2b(v);
}

// ==== enc3 weights: ew3[co 64][ci 32][9] -> wte3[t 9][co 64][ci 32] bf16 ====
__global__ void wtrb_enc3(const float* __restrict__ w, bf16* __restrict__ wt)
{
    int idx = blockIdx.x * blockDim.x + threadIdx.x;
    if (idx >= 64 * 32 * 9) return;
    int co = idx / 288;
    int r  = idx - co * 288;
    int ci = r / 9, t = r - ci * 9;
    wt[((size_t)t * 64 + co) * 32 + ci] = f2b(w[idx]);
}

// ============ decoder weight transform: w[ci][co][9] -> wtb[t][co][ci] bf16 ============
__global__ void wtrb_convt(const float* __restrict__ w, bf16* __restrict__ wt,
                           int CIN, int COUT)
{
    int idx = blockIdx.x * blockDim.x + threadIdx.x;
    if (idx >= CIN * COUT * 9) return;
    int ci = idx / (COUT * 9);
    int r  = idx - ci * COUT * 9;
    int co = r / 9, t = r - co * 9;
    wt[((size_t)t * COUT + co) * CIN + ci] = f2b(w[idx]);
}

// ============ kw transform: kw[e][ci*64+pos] -> kwt[e][pos*64+ci] bf16, padded to 112 ====
__global__ void wtr_kw(const float* __restrict__ kw, bf16* __restrict__ kwt)
{
    int idx = blockIdx.x * blockDim.x + threadIdx.x;
    if (idx >= 112 * 4096) return;
    int e = idx >> 12, kk = idx & 4095;
    int pos = kk >> 6, ci = kk & 63;
    float v = (e < 110) ? kw[(size_t)e * 4096 + ci * 64 + pos] : 0.f;
    kwt[idx] = f2b(v);
}

// ==== dense weight transpose: w[OUT][K] -> wT[K][OUT] fp32 ====
__global__ void wtr_dense(const float* __restrict__ w, float* __restrict__ wT,
                          int OUT, int K)
{
    int idx = blockIdx.x * blockDim.x + threadIdx.x;
    if (idx >= OUT * K) return;
    int o = idx / K, k = idx - o * K;
    wT[(size_t)k * OUT + o] = w[idx];
}

// ============ enc2 MFMA: h1b[img][32][32][16] -> h2b[img][16][16][32], stride 2 ============
// Parity-split LDS planes Pl[pa][pb][17x17], C8=2; 2 taps packed per MFMA (K=32=2x16ch)
__global__ __launch_bounds__(256)
void enc2_mfma(const bf16* __restrict__ xg, const bf16* __restrict__ wte,
               const float* __restrict__ bias, bf16* __restrict__ yg)
{
    __shared__ short8 Xs[4 * 289 * 2];          // 36,992 B
    const int img = blockIdx.x;
    const bf16* xi = xg + (size_t)img * 32 * 32 * 16;
    for (int e = threadIdx.x; e < 4 * 289 * 2; e += 256) {
        int c8 = e & 1, q = e >> 1;
        int pl = q / 289, pos = q - pl * 289;
        int pr = pos / 17, pc = pos - pr * 17;
        int pa = pl >> 1, pb = pl & 1;
        int ihr = 2 * (pr - 1) + pa, iwc = 2 * (pc - 1) + pb;
        short8 v = s8zero();
        if ((unsigned)ihr < 32u && (unsigned)iwc < 32u)
            v = *reinterpret_cast<const short8*>(xi + ((size_t)(ihr * 32 + iwc)) * 16 + c8 * 8);
        Xs[(pl * 289 + pos) * 2 + (c8 ^ (pos & 1))] = v;
    }
    __syncthreads();

    const int wv = threadIdx.x >> 6, lane = threadIdx.x & 63;
    const int lp = lane & 15, lq = lane >> 4;
    const int nt = wv & 1, mh = wv >> 1;

    short8 wf[5];
    #pragma unroll
    for (int p = 0; p < 5; ++p)
        wf[p] = *reinterpret_cast<const short8*>(wte + ((size_t)(p * 32 + nt * 16 + lp)) * 32 + lq * 8);
    float bv[4];
    #pragma unroll
    for (int r = 0; r < 4; ++r) bv[r] = bias[nt * 16 + lq * 4 + r];

    bf16* yi = yg + (size_t)img * 16 * 16 * 32;
    for (int mt = mh * 8; mt < mh * 8 + 8; ++mt) {
        int m = mt * 16 + lp;
        int ho = m >> 4, wo = m & 15;
        f32x4 acc = {0.f, 0.f, 0.f, 0.f};
        #pragma unroll
        for (int p = 0; p < 5; ++p) {
            const int tA = 2 * p, tB = (p < 4) ? 2 * p + 1 : 8;
            const int khA = tA / 3, kwA = tA % 3;
            const int paA = (khA == 1) ? 0 : 1, dhA = (khA == 0) ? -1 : 0;
            const int pbA = (kwA == 1) ? 0 : 1, dwA = (kwA == 0) ? -1 : 0;
            const int khB = tB / 3, kwB = tB % 3;
            const int paB = (khB == 1) ? 0 : 1, dhB = (khB == 0) ? -1 : 0;
            const int pbB = (kwB == 1) ? 0 : 1, dwB = (kwB == 0) ? -1 : 0;
            int posA = (ho + dhA + 1) * 17 + (wo + dwA + 1);
            int posB = (ho + dhB + 1) * 17 + (wo + dwB + 1);
            int idxA = ((paA * 2 + pbA) * 289 + posA) * 2 + ((lq & 1) ^ (posA & 1));
            int idxB = ((paB * 2 + pbB) * 289 + posB) * 2 + ((lq & 1) ^ (posB & 1));
            short8 b = Xs[(lq < 2) ? idxA : idxB];
            acc = __builtin_amdgcn_mfma_f32_16x16x32_bf16(wf[p], b, acc, 0, 0, 0);
        }
        __align__(8) bf16 ov[4];
        #pragma unroll
        for (int r = 0; r < 4; ++r) ov[r] = f2b(fmaxf(acc[r] + bv[r], 0.f));
        *reinterpret_cast<uint2*>(yi + ((size_t)(ho * 16 + wo)) * 32 + nt * 16 + lq * 4)
            = *reinterpret_cast<uint2*>(ov);
    }
}

// ============ enc3 MFMA: h2b[img][16][16][32] -> h3b[img][8][8][64], stride 2 ============
__global__ __launch_bounds__(256)
void enc3_mfma(const bf16* __restrict__ xg, const bf16* __restrict__ wte,
               const float* __restrict__ bias, bf16* __restrict__ yg)
{
    __shared__ short8 Xs[4 * 81 * 4];            // 20,736 B
    const int img = blockIdx.x;
    const bf16* xi = xg + (size_t)img * 16 * 16 * 32;
    for (int e = threadIdx.x; e < 4 * 81 * 4; e += 256) {
        int c8 = e & 3, q = e >> 2;
        int pl = q / 81, pos = q - pl * 81;
        int pr = pos / 9, pc = pos - pr * 9;
        int pa = pl >> 1, pb = pl & 1;
        int ihr = 2 * (pr - 1) + pa, iwc = 2 * (pc - 1) + pb;
        short8 v = s8zero();
        if ((unsigned)ihr < 16u && (unsigned)iwc < 16u)
            v = *reinterpret_cast<const short8*>(xi + ((size_t)(ihr * 16 + iwc)) * 32 + c8 * 8);
        Xs[(pl * 81 + pos) * 4 + (c8 ^ (pos & 3))] = v;
    }
    __syncthreads();

    const int wv = threadIdx.x >> 6, lane = threadIdx.x & 63;
    const int lp = lane & 15, lq = lane >> 4;
    const int nt = wv;

    short8 wf[9];
    #pragma unroll
    for (int t = 0; t < 9; ++t)
        wf[t] = *reinterpret_cast<const short8*>(wte + ((size_t)(t * 64 + nt * 16 + lp)) * 32 + lq * 8);
    float bv[4];
    #pragma unroll
    for (int r = 0; r < 4; ++r) bv[r] = bias[nt * 16 + lq * 4 + r];

    bf16* yi = yg + (size_t)img * 8 * 8 * 64;
    for (int mt = 0; mt < 4; ++mt) {
        int m = mt * 16 + lp;
        int ho = m >> 3, wo = m & 7;
        f32x4 acc = {0.f, 0.f, 0.f, 0.f};
        #pragma unroll
        for (int t = 0; t < 9; ++t) {
            const int kh = t / 3, kw2 = t % 3;
            const int pa = (kh == 1) ? 0 : 1, dh = (kh == 0) ? -1 : 0;
            const int pb = (kw2 == 1) ? 0 : 1, dw = (kw2 == 0) ? -1 : 0;
            int pos = (ho + dh + 1) * 9 + (wo + dw + 1);
            int idx = ((pa * 2 + pb) * 81 + pos) * 4 + (lq ^ (pos & 3));
            acc = __builtin_amdgcn_mfma_f32_16x16x32_bf16(wf[t], Xs[idx], acc, 0, 0, 0);
        }
        __align__(8) bf16 ov[4];
        #pragma unroll
        for (int r = 0; r < 4; ++r) ov[r] = f2b(fmaxf(acc[r] + bv[r], 0.f));
        *reinterpret_cast<uint2*>(yi + ((size_t)(ho * 8 + wo)) * 64 + nt * 16 + lq * 4)
            = *reinterpret_cast<uint2*>(ov);
    }
}

// ============ emb = sigmoid(h3b @ kwt^T + kb) -> fp32 ============
__global__ __launch_bounds__(256)
void emb_mfma(const bf16* __restrict__ h3b, const bf16* __restrict__ kwt,
              const float* __restrict__ kb, float* __restrict__ emb)
{
    __shared__ f32x4 Ls[3][7][64];
    const int imgbase = blockIdx.x * 16;
    const int w = threadIdx.x >> 6, lane = threadIdx.x & 63;
    const int lp = lane & 15, lq = lane >> 4;
    const int k0 = w * 1024;

    f32x4 zero = {0.f, 0.f, 0.f, 0.f};
    f32x4 acc[7] = {zero, zero, zero, zero, zero, zero, zero};

    const bf16* bp = h3b + (size_t)(imgbase + lp) * 4096 + k0 + lq * 8;
    const bf16* ap = kwt + (size_t)lp * 4096 + k0 + lq * 8;
    for (int ks = 0; ks < 32; ++ks) {
        short8 bfrag = *reinterpret_cast<const short8*>(bp + ks * 32);
        #pragma unroll
        for (int nt = 0; nt < 7; ++nt) {
            short8 afrag = *reinterpret_cast<const short8*>(ap + (size_t)nt * 16 * 4096 + ks * 32);
            acc[nt] = __builtin_amdgcn_mfma_f32_16x16x32_bf16(afrag, bfrag, acc[nt], 0, 0, 0);
        }
    }
    if (w > 0) {
        #pragma unroll
        for (int nt = 0; nt < 7; ++nt) Ls[w - 1][nt][lane] = acc[nt];
    }
    __syncthreads();
    if (w == 0) {
        #pragma unroll
        for (int nt = 0; nt < 7; ++nt) {
            f32x4 a = acc[nt];
            #pragma unroll
            for (int ww = 0; ww < 3; ++ww) a += Ls[ww][nt][lane];
            const int e0 = nt * 16 + lq * 4;
            #pragma unroll
            for (int r = 0; r < 4; ++r) {
                int e = e0 + r;
                if (e < 110) {
                    float v = a[r] + kb[e];
                    emb[(size_t)(imgbase + lp) * 110 + e] = 1.f / (1.f + expf(-v));
                }
            }
        }
    }
}

// ============ MFMA transpose-conv stride 2 (decoder) ============
template<int COUT, int HIN, int WIN, int HSPLIT>
__global__ __launch_bounds__(256)
void convt2_mfma(const bf16* __restrict__ xg, const bf16* __restrict__ wtb,
                 const float* __restrict__ bias, bf16* __restrict__ yg)
{
    constexpr int CIN = 64, C8 = 8;
    constexpr int WP  = WIN + 1;
    constexpr int HS  = HIN / HSPLIT;
    constexpr int HPS = HS + 1;
    constexpr int NPOS = HPS * WP;
    constexpr int HOUT = HIN * 2, WOUT = WIN * 2;
    constexpr int NT = COUT / 16;
    constexpr int MT = (HS * WIN) / 16;
    __shared__ short8 Xs[NPOS * C8];

    const int img = blockIdx.x;
    const int s   = blockIdx.y;
    const int hqb = s * HS;
    const bf16* xi = xg + (size_t)img * HIN * WIN * CIN;

    for (int e = threadIdx.x; e < NPOS * C8; e += 256) {
        int c8 = e & 7, pos = e >> 3;
        int hl = pos / WP, wi = pos % WP;
        int hi = hqb + hl;
        short8 v = s8zero();
        if (hi < HIN && wi < WIN)
            v = *reinterpret_cast<const short8*>(xi + ((size_t)(hi * WIN + wi)) * CIN + c8 * 8);
        Xs[pos * C8 + (c8 ^ (pos & 7))] = v;
    }
    __syncthreads();

    const int wv = threadIdx.x >> 6, lane = threadIdx.x & 63;
    const int lp = lane & 15, lq = lane >> 4;
    const int nt    = (NT == 4) ? wv : (wv & 1);
    const int mt0   = (NT == 4) ? 0  : (wv >> 1) * (MT / 2);
    const int mtend = (NT == 4) ? MT : mt0 + (MT / 2);

    short8 wf[9][2];
    #pragma unroll
    for (int t = 0; t < 9; ++t) {
        const bf16* wp = wtb + ((size_t)t * COUT + nt * 16 + lp) * CIN + lq * 8;
        wf[t][0] = *reinterpret_cast<const short8*>(wp);
        wf[t][1] = *reinterpret_cast<const short8*>(wp + 32);
    }
    float bv[4];
    #pragma unroll
    for (int r = 0; r < 4; ++r) bv[r] = bias[nt * 16 + lq * 4 + r];

    bf16* yi = yg + (size_t)img * HOUT * WOUT * COUT;
    for (int mt = mt0; mt < mtend; ++mt) {
        int m = mt * 16 + lp;
        int hql = m / WIN, wq = m % WIN;
        f32x4 zero = {0.f, 0.f, 0.f, 0.f};
        f32x4 acc[4] = {zero, zero, zero, zero};
        #pragma unroll
        for (int kh = 0; kh < 3; ++kh) {
            #pragma unroll
            for (int kw = 0; kw < 3; ++kw) {
                const int pa = (kh + 1) & 1, pb = (kw + 1) & 1;
                const int oh = (pa + 1 - kh) >> 1, ow = (pb + 1 - kw) >> 1;
                const int cls = pa * 2 + pb;
                const int t = kh * 3 + kw;
                int pos = (hql + oh) * WP + (wq + ow);
                int sw = pos & 7;
                short8 b0 = Xs[pos * C8 + (lq ^ sw)];
                acc[cls] = __builtin_amdgcn_mfma_f32_16x16x32_bf16(wf[t][0], b0, acc[cls], 0, 0, 0);
                short8 b1 = Xs[pos * C8 + ((4 + lq) ^ sw)];
                acc[cls] = __builtin_amdgcn_mfma_f32_16x16x32_bf16(wf[t][1], b1, acc[cls], 0, 0, 0);
            }
        }
        int hq = hqb + hql;
        #pragma unroll
        for (int cls = 0; cls < 4; ++cls) {
            int pa = cls >> 1, pb = cls & 1;
            int ho = hq * 2 + pa, wo = wq * 2 + pb;
            __align__(8) bf16 ov[4];
            #pragma unroll
            for (int r = 0; r < 4; ++r) ov[r] = f2b(fmaxf(acc[cls][r] + bv[r], 0.f));
            *reinterpret_cast<uint2*>(yi + ((size_t)(ho * WOUT + wo)) * COUT + nt * 16 + lq * 4)
                = *reinterpret_cast<uint2*>(ov);
        }
    }
}

// ============ MFMA transpose-conv stride 1 (32->16) + fused 1x1 (16->3) ============
__global__ __launch_bounds__(256)
void convt1_mfma_fused(const bf16* __restrict__ xg, const bf16* __restrict__ wtb,
                       const float* __restrict__ bias,
                       const float* __restrict__ w4, const float* __restrict__ b4,
                       float* __restrict__ dec)
{
    constexpr int CIN = 32, C8 = 4;
    constexpr int H = 32, W = 32, HR = 18, WR = 34, NPOS = HR * WR;
    __shared__ short8 Xs[NPOS * C8];

    const int img  = blockIdx.x >> 1;
    const int half = blockIdx.x & 1;
    const int hbase = half * 16;
    const bf16* xi = xg + (size_t)img * H * W * CIN;

    for (int e = threadIdx.x; e < NPOS * C8; e += 256) {
        int c8 = e & 3, pos = e >> 2;
        int hr = pos / WR, wr = pos % WR;
        int hi = hbase - 1 + hr, wi = wr - 1;
        short8 v = s8zero();
        if ((unsigned)hi < (unsigned)H && (unsigned)wi < (unsigned)W)
            v = *reinterpret_cast<const short8*>(xi + ((size_t)(hi * W + wi)) * CIN + c8 * 8);
        Xs[pos * C8 + (c8 ^ (pos & 3))] = v;
    }
    __syncthreads();

    const int wv = threadIdx.x >> 6, lane = threadIdx.x & 63;
    const int lp = lane & 15, lq = lane >> 4;

    short8 wf[9];
    #pragma unroll
    for (int t = 0; t < 9; ++t)
        wf[t] = *reinterpret_cast<const short8*>(wtb + ((size_t)t * 16 + lp) * CIN + lq * 8);
    float bv[4];
    #pragma unroll
    for (int r = 0; r < 4; ++r) bv[r] = bias[lq * 4 + r];
    float w4r[3][4];
    #pragma unroll
    for (int j = 0; j < 3; ++j)
        #pragma unroll
        for (int r = 0; r < 4; ++r) w4r[j][r] = w4[j * 16 + lq * 4 + r];
    float b4r[3] = {b4[0], b4[1], b4[2]};

    for (int mt = wv; mt < 32; mt += 4) {
        int m = mt * 16 + lp;
        int hol = m >> 5, wo = m & 31;
        f32x4 acc = {0.f, 0.f, 0.f, 0.f};
        #pragma unroll
        for (int t = 0; t < 9; ++t) {
            int kh = t / 3, kw = t % 3;
            int pos = (hol + 2 - kh) * WR + (wo + 2 - kw);
            short8 b0 = Xs[pos * C8 + (lq ^ (pos & 3))];
            acc = __builtin_amdgcn_mfma_f32_16x16x32_bf16(wf[t], b0, acc, 0, 0, 0);
        }
        float s0 = 0.f, s1 = 0.f, s2 = 0.f;
        #pragma unroll
        for (int r = 0; r < 4; ++r) {
            float v = fmaxf(acc[r] + bv[r], 0.f);
            s0 += v * w4r[0][r]; s1 += v * w4r[1][r]; s2 += v * w4r[2][r];
        }
        s0 += __shfl_xor(s0, 16); s0 += __shfl_xor(s0, 32);
        s1 += __shfl_xor(s1, 16); s1 += __shfl_xor(s1, 32);
        s2 += __shfl_xor(s2, 16); s2 += __shfl_xor(s2, 32);
        if (lq == 0) {
            int ho = hbase + hol;
            size_t base = (size_t)img * 3072 + ho * 32 + wo;
            dec[base]        = s0 + b4r[0];
            dec[base + 1024] = s1 + b4r[1];
            dec[base + 2048] = s2 + b4r[2];
        }
    }
}

// ---------------- KDE ----------------
__global__ void kde_kernel(const float* __restrict__ emb, float* __restrict__ fd)
{
    int idx = blockIdx.x * blockDim.x + threadIdx.x;
    if (idx >= 64 * 110) return;
    int f = idx % 110, b = idx / 110;
    float dens[11];
    #pragma unroll
    for (int j = 0; j < 11; ++j) dens[j] = 0.f;
    const float* ep = emb + (size_t)b * 32 * 110 + f;
    for (int n = 0; n < 32; ++n) {
        float e = ep[n * 110];
        #pragma unroll
        for (int j = 0; j < 11; ++j) {
            float d = 0.1f * j - e;
            dens[j] += expf(-50.f * d * d);
        }
    }
    float s = 0.f;
    #pragma unroll
    for (int j = 0; j < 11; ++j) s += dens[j];
    float inv = 1.f / s;
    float* op = fd + (size_t)b * 1210 + f * 11;
    #pragma unroll
    for (int j = 0; j < 11; ++j) op[j] = dens[j] * inv;
}

// ---------------- dense (coalesced via transposed weights) ----------------
template<int K, int OUT>
__global__ void dense_t(const float* __restrict__ in, const float* __restrict__ wT,
                        const float* __restrict__ b, float* __restrict__ out,
                        int rows, int relu)
{
    int idx = blockIdx.x * blockDim.x + threadIdx.x;
    if (idx >= rows * OUT) return;
    int o = idx % OUT, r = idx / OUT;
    float acc = b[o];
    const float* ir = in + (size_t)r * K;
    const float* wp = wT + o;
    #pragma unroll 4
    for (int k = 0; k < K; ++k) acc += ir[k] * wp[(size_t)k * OUT];
    if (relu) acc = fmaxf(acc, 0.f);
    out[idx] = acc;
}

template<int K, int OUT>
__global__ void dense_kernel(const float* __restrict__ in, const float* __restrict__ w,
                             const float* __restrict__ b, float* __restrict__ out,
                             int rows, int relu)
{
    int idx = blockIdx.x * blockDim.x + threadIdx.x;
    if (idx >= rows * OUT) return;
    int o = idx % OUT, r = idx / OUT;
    float acc = b[o];
    const float* ir = in + (size_t)r * K;
    const float* wr = w  + (size_t)o * K;
    for (int k = 0; k < K; ++k) acc += ir[k] * wr[k];
    if (relu) acc = fmaxf(acc, 0.f);
    out[idx] = acc;
}

// ===================== host side =====================
static Taps4 mk_conv9()
{
    Taps4 T = {};
    T.t[0].n = 9;
    int q = 0;
    for (int kh = 0; kh < 3; ++kh)
        for (int kw = 0; kw < 3; ++kw) {
            T.t[0].oh[q] = kh - 1; T.t[0].ow[q] = kw - 1; T.t[0].ti[q] = kh * 3 + kw; ++q;
        }
    return T;
}

extern "C" void kernel_launch(void* const* d_in, const int* in_sizes, int n_in,
                              void* d_out, int out_size, void* d_ws, size_t ws_size,
                              hipStream_t stream)
{
    const float* x    = (const float*)d_in[0];
    const float* ew1  = (const float*)d_in[1];
    const float* eb1  = (const float*)d_in[2];
    const float* ew2  = (const float*)d_in[3];
    const float* eb2  = (const float*)d_in[4];
    const float* ew3  = (const float*)d_in[5];
    const float* eb3  = (const float*)d_in[6];
    const float* kw   = (const float*)d_in[7];
    const float* kb   = (const float*)d_in[8];
    const float* dw1  = (const float*)d_in[9];
    const float* db1  = (const float*)d_in[10];
    const float* dw2  = (const float*)d_in[11];
    const float* db2  = (const float*)d_in[12];
    const float* dw3  = (const float*)d_in[13];
    const float* db3  = (const float*)d_in[14];
    const float* dw4  = (const float*)d_in[15];
    const float* db4  = (const float*)d_in[16];
    const float* f1w  = (const float*)d_in[17];
    const float* f1b  = (const float*)d_in[18];
    const float* f2w  = (const float*)d_in[19];
    const float* f2b_ = (const float*)d_in[20];
    const float* f3w  = (const float*)d_in[21];
    const float* f3b  = (const float*)d_in[22];

    // ---------- workspace ----------
    char* ws = (char*)d_ws;
    float* emb  = (float*)(ws + 0);          //   901,120
    float* fd   = (float*)(ws + 901120);     //   309,760
    float* m1   = (float*)(ws + 1210880);    //   131,072
    float* m2   = (float*)(ws + 1341952);    //    65,536
    float* wt1  = (float*)(ws + 1407488);    //     1,792
    bf16*  wte2 = (bf16*) (ws + 1409280);    //    10,240 (5*32*32)
    bf16*  wte3 = (bf16*) (ws + 1419520);    //    36,864 (9*64*32)
    bf16*  wtb4 = (bf16*) (ws + 1456384);    //    73,728 (9*64*64)
    bf16*  wtb5 = (bf16*) (ws + 1530112);    //    36,864 (9*64*32)
    bf16*  wtb6 = (bf16*) (ws + 1566976);    //     9,216 (9*16*32)
    bf16*  kwt  = (bf16*) (ws + 1576192);    //   917,504 (112*4096)
    float* f1wT = (float*)(ws + 2493696);    // 2,478,080 (1210*512)
    float* f2wT = (float*)(ws + 4971776);    //   524,288 (512*256)
    const size_t FIXED = 5496064;

    // per image (bf16 NHWC): h1b 32K (d1b overlays) | h2b 16K | h3b 8K | d2b 64K
    const size_t PER_IMG = 122880;
    int CHUNK = 1024;
    while (CHUNK > 16 && FIXED + (size_t)CHUNK * PER_IMG > ws_size) CHUNK >>= 1;
    const int NCHUNK = 2048 / CHUNK;

    char* p   = ws + FIXED;
    bf16* h1b = (bf16*)(p);
    bf16* h2b = (bf16*)(p + (size_t)CHUNK * 32768);
    bf16* h3b = (bf16*)(p + (size_t)CHUNK * 49152);
    bf16* d2b = (bf16*)(p + (size_t)CHUNK * 57344);
    bf16* d1b = h1b;                          // overlay: h1b dead after enc2

    float* logits = (float*)d_out;            // 64*4
    float* dec    = (float*)d_out + 256;      // 2048*3*32*32 NCHW

    // ---- weight transforms (once per launch) ----
    wtr_conv  <<<(16*3*9  + 255)/256, 256, 0, stream>>>(ew1, wt1, 16, 3);
    wtrb_enc2 <<<(5*32*32 + 255)/256, 256, 0, stream>>>(ew2, wte2);
    wtrb_enc3 <<<(64*32*9 + 255)/256, 256, 0, stream>>>(ew3, wte3);
    wtrb_convt<<<(64*64*9 + 255)/256, 256, 0, stream>>>(dw1, wtb4, 64, 64);
    wtrb_convt<<<(64*32*9 + 255)/256, 256, 0, stream>>>(dw2, wtb5, 64, 32);
    wtrb_convt<<<(32*16*9 + 255)/256, 256, 0, stream>>>(dw3, wtb6, 32, 16);
    wtr_kw    <<<(112*4096 + 255)/256, 256, 0, stream>>>(kw, kwt);
    wtr_dense <<<(512*1210 + 255)/256, 256, 0, stream>>>(f1w, f1wT, 512, 1210);
    wtr_dense <<<(256*512  + 255)/256, 256, 0, stream>>>(f2w, f2wT, 256, 512);

    const Taps4 T9 = mk_conv9();

    for (int c = 0; c < NCHUNK; ++c) {
        const float* xc   = x   + (size_t)c * CHUNK * 3 * 1024;
        float*       decc = dec + (size_t)c * CHUNK * 3 * 1024;
        float*       embc = emb + (size_t)c * CHUNK * 110;

        // encoder
        conv_gemm<3,16,32,32,32,32, 1,1, 16,16, 3, true, true>
            <<<dim3(CHUNK*4,1), 256, 0, stream>>>(xc, wt1, eb1, h1b, T9);
        enc2_mfma<<<CHUNK, 256, 0, stream>>>(h1b, wte2, eb2, h2b);
        enc3_mfma<<<CHUNK, 256, 0, stream>>>(h2b, wte3, eb3, h3b);

        // embedding
        emb_mfma<<<CHUNK/16, 256, 0, stream>>>(h3b, kwt, kb, embc);

        // decoder
        convt2_mfma<64, 8, 8, 1>  <<<dim3(CHUNK,1), 256, 0, stream>>>(h3b, wtb4, db1, d1b);
        convt2_mfma<32, 16, 16, 2><<<dim3(CHUNK,2), 256, 0, stream>>>(d1b, wtb5, db2, d2b);
        convt1_mfma_fused         <<<dim3(CHUNK*2,1), 256, 0, stream>>>(d2b, wtb6, db3, dw4, db4, decc);
    }

    // classifier
    kde_kernel<<<(64*110+255)/256, 256, 0, stream>>>(emb, fd);
    dense_t<1210,512><<<(64*512+255)/256, 256, 0, stream>>>(fd, f1wT, f1b, m1, 64, 1);
    dense_t<512,256> <<<(64*256+255)/256, 256, 0, stream>>>(m1, f2wT, f2b_, m2, 64, 1);
    dense_kernel<256,4><<<1, 256, 0, stream>>>(m2, f3w, f3b, logits, 64, 0);
}

// Round 12
// 429.503 us; speedup vs baseline: 19.3967x; 1.4167x over previous
//
#include <hip/hip_runtime.h>
#include <hip/hip_bf16.h>
#include <stdint.h>

typedef __hip_bfloat16 bf16;
typedef __attribute__((ext_vector_type(8))) short short8;
typedef __attribute__((ext_vector_type(4))) float f32x4;

__device__ __forceinline__ bf16 f2b(float v){ return __float2bfloat16(v); }
__device__ __forceinline__ short8 s8zero()
{
    short8 z;
    for (int i = 0; i < 8; ++i) z[i] = 0;
    return z;
}

struct Taps  { int n; int oh[9]; int ow[9]; int ti[9]; };
struct Taps4 { Taps t[4]; };

// ===================== fp32 implicit-GEMM conv (enc1 only) =====================
template<int CIN, int COUT, int HIN, int WIN, int HOUT, int WOUT,
         int A, int OST, int MH, int MW, int KC, bool IN_NCHW, bool OUT_BF16>
__global__ __launch_bounds__(256)
void conv_gemm(const float* __restrict__ x, const float* __restrict__ wt,
               const float* __restrict__ bias, void* __restrict__ yv, Taps4 ts)
{
    constexpr int M   = MH * MW;
    constexpr int N   = COUT;
    constexpr int NT4 = N / 4;
    constexpr int HQ  = HOUT / OST, WQ = WOUT / OST;
    constexpr int TH  = HQ / MH,   TW = WQ / MW;
    constexpr int XSTR = M + 4;
    static_assert(M * N == 4096, "block tile must be 4096");

    __shared__ float Xs[KC * XSTR];
    __shared__ float Ws[KC * N];

    const int tid = threadIdx.x;
    const int mt = tid / NT4, nt = tid % NT4;

    int bx = blockIdx.x;
    const int tw = bx % TW; bx /= TW;
    const int th = bx % TH;
    const int n  = bx / TH;
    const int hq0 = th * MH, wq0 = tw * MW;

    float bv[4];
    #pragma unroll
    for (int j = 0; j < 4; ++j) bv[j] = bias[nt * 4 + j];

    float acc[4][4];
    #pragma unroll
    for (int i = 0; i < 4; ++i)
        #pragma unroll
        for (int j = 0; j < 4; ++j) acc[i][j] = 0.f;

    const int ntaps = ts.t[0].n;
    for (int t = 0; t < ntaps; ++t) {
        const int oh = ts.t[0].oh[t];
        const int ow = ts.t[0].ow[t];
        const int ti = ts.t[0].ti[t];
        const float* wtp = wt + (size_t)(ti * CIN) * N;
        for (int c0 = 0; c0 < CIN; c0 += KC) {
            __syncthreads();
            for (int e = tid; e < KC * N; e += 256)
                Ws[e] = wtp[(size_t)c0 * N + e];
            for (int e = tid; e < M * KC; e += 256) {
                int k, m;
                if (IN_NCHW) { k = e / M;  m = e % M; }
                else         { k = e % KC; m = e / KC; }
                const int hq = hq0 + m / MW;
                const int wq = wq0 + m % MW;
                const int hi = hq * A + oh;
                const int wi = wq * A + ow;
                float v = 0.f;
                if ((unsigned)hi < (unsigned)HIN && (unsigned)wi < (unsigned)WIN) {
                    if (IN_NCHW)
                        v = x[(((size_t)n * CIN + c0 + k) * HIN + hi) * WIN + wi];
                    else
                        v = x[(((size_t)n * HIN + hi) * WIN + wi) * CIN + c0 + k];
                }
                Xs[k * XSTR + m] = v;
            }
            __syncthreads();
            #pragma unroll
            for (int k = 0; k < KC; ++k) {
                float4 av = *reinterpret_cast<const float4*>(&Xs[k * XSTR + mt * 4]);
                float4 bw = *reinterpret_cast<const float4*>(&Ws[k * N + nt * 4]);
                acc[0][0] += av.x * bw.x; acc[0][1] += av.x * bw.y;
                acc[0][2] += av.x * bw.z; acc[0][3] += av.x * bw.w;
                acc[1][0] += av.y * bw.x; acc[1][1] += av.y * bw.y;
                acc[1][2] += av.y * bw.z; acc[1][3] += av.y * bw.w;
                acc[2][0] += av.z * bw.x; acc[2][1] += av.z * bw.y;
                acc[2][2] += av.z * bw.z; acc[2][3] += av.z * bw.w;
                acc[3][0] += av.w * bw.x; acc[3][1] += av.w * bw.y;
                acc[3][2] += av.w * bw.z; acc[3][3] += av.w * bw.w;
            }
        }
    }
    #pragma unroll
    for (int i = 0; i < 4; ++i) {
        const int m  = mt * 4 + i;
        const int ho = (hq0 + m / MW);
        const int wo = (wq0 + m % MW);
        const size_t oidx = (((size_t)n * HOUT + ho) * WOUT + wo) * N + nt * 4;
        float o0 = fmaxf(acc[i][0] + bv[0], 0.f);
        float o1 = fmaxf(acc[i][1] + bv[1], 0.f);
        float o2 = fmaxf(acc[i][2] + bv[2], 0.f);
        float o3 = fmaxf(acc[i][3] + bv[3], 0.f);
        if (OUT_BF16) {
            __align__(8) bf16 ov[4] = {f2b(o0), f2b(o1), f2b(o2), f2b(o3)};
            *reinterpret_cast<uint2*>((bf16*)yv + oidx) = *reinterpret_cast<uint2*>(ov);
        } else {
            float4 o = {o0, o1, o2, o3};
            *reinterpret_cast<float4*>((float*)yv + oidx) = o;
        }
    }
}

__global__ void wtr_conv(const float* __restrict__ w, float* __restrict__ wt,
                         int COUT, int CIN)   // w[co][ci][9] -> wt[t][ci][co]
{
    int idx = blockIdx.x * blockDim.x + threadIdx.x;
    if (idx >= COUT * CIN * 9) return;
    int co = idx / (CIN * 9);
    int r  = idx - co * CIN * 9;
    int ci = r / 9, t = r - ci * 9;
    wt[((size_t)t * CIN + ci) * COUT + co] = w[idx];
}

// ==== enc2 paired weights: ew2[co 32][ci 16][9] -> wte2[p 5][co 32][k 32] bf16 ====
__global__ void wtrb_enc2(const float* __restrict__ w, bf16* __restrict__ wt)
{
    int idx = blockIdx.x * blockDim.x + threadIdx.x;
    if (idx >= 5 * 32 * 32) return;
    int p = idx >> 10, r = idx & 1023;
    int co = r >> 5, k = r & 31;
    int t = 2 * p + (k >> 4);
    int ch = k & 15;
    float v = (t <= 8) ? w[((size_t)co * 16 + ch) * 9 + t] : 0.f;
    wt[idx] = f2b(v);
}

// ==== enc3 weights: ew3[co 64][ci 32][9] -> wte3[t 9][co 64][ci 32] bf16 ====
__global__ void wtrb_enc3(const float* __restrict__ w, bf16* __restrict__ wt)
{
    int idx = blockIdx.x * blockDim.x + threadIdx.x;
    if (idx >= 64 * 32 * 9) return;
    int co = idx / 288;
    int r  = idx - co * 288;
    int ci = r / 9, t = r - ci * 9;
    wt[((size_t)t * 64 + co) * 32 + ci] = f2b(w[idx]);
}

// ============ decoder weight transform: w[ci][co][9] -> wtb[t][co][ci] bf16 ============
__global__ void wtrb_convt(const float* __restrict__ w, bf16* __restrict__ wt,
                           int CIN, int COUT)
{
    int idx = blockIdx.x * blockDim.x + threadIdx.x;
    if (idx >= CIN * COUT * 9) return;
    int ci = idx / (COUT * 9);
    int r  = idx - ci * COUT * 9;
    int co = r / 9, t = r - co * 9;
    wt[((size_t)t * COUT + co) * CIN + ci] = f2b(w[idx]);
}

// ============ kw transform -> kwt[e][pos*64+ci] bf16, padded to 112 ====
__global__ void wtr_kw(const float* __restrict__ kw, bf16* __restrict__ kwt)
{
    int idx = blockIdx.x * blockDim.x + threadIdx.x;
    if (idx >= 112 * 4096) return;
    int e = idx >> 12, kk = idx & 4095;
    int pos = kk >> 6, ci = kk & 63;
    float v = (e < 110) ? kw[(size_t)e * 4096 + ci * 64 + pos] : 0.f;
    kwt[idx] = f2b(v);
}

// ==== dense weight transpose: w[OUT][K] -> wT[K][OUT] fp32 ====
__global__ void wtr_dense(const float* __restrict__ w, float* __restrict__ wT,
                          int OUT, int K)
{
    int idx = blockIdx.x * blockDim.x + threadIdx.x;
    if (idx >= OUT * K) return;
    int o = idx / K, k = idx - o * K;
    wT[(size_t)k * OUT + o] = w[idx];
}

// ============ enc2 MFMA: h1b[img][32][32][16] -> h2b[img][16][16][32], stride 2 ============
__global__ __launch_bounds__(256)
void enc2_mfma(const bf16* __restrict__ xg, const bf16* __restrict__ wte,
               const float* __restrict__ bias, bf16* __restrict__ yg)
{
    __shared__ short8 Xs[4 * 289 * 2];
    const int img = blockIdx.x;
    const bf16* xi = xg + (size_t)img * 32 * 32 * 16;
    for (int e = threadIdx.x; e < 4 * 289 * 2; e += 256) {
        int c8 = e & 1, q = e >> 1;
        int pl = q / 289, pos = q - pl * 289;
        int pr = pos / 17, pc = pos - pr * 17;
        int pa = pl >> 1, pb = pl & 1;
        int ihr = 2 * (pr - 1) + pa, iwc = 2 * (pc - 1) + pb;
        short8 v = s8zero();
        if ((unsigned)ihr < 32u && (unsigned)iwc < 32u)
            v = *reinterpret_cast<const short8*>(xi + ((size_t)(ihr * 32 + iwc)) * 16 + c8 * 8);
        Xs[(pl * 289 + pos) * 2 + (c8 ^ (pos & 1))] = v;
    }
    __syncthreads();

    const int wv = threadIdx.x >> 6, lane = threadIdx.x & 63;
    const int lp = lane & 15, lq = lane >> 4;
    const int nt = wv & 1, mh = wv >> 1;

    short8 wf[5];
    #pragma unroll
    for (int p = 0; p < 5; ++p)
        wf[p] = *reinterpret_cast<const short8*>(wte + ((size_t)(p * 32 + nt * 16 + lp)) * 32 + lq * 8);
    float bv[4];
    #pragma unroll
    for (int r = 0; r < 4; ++r) bv[r] = bias[nt * 16 + lq * 4 + r];

    bf16* yi = yg + (size_t)img * 16 * 16 * 32;
    for (int mt = mh * 8; mt < mh * 8 + 8; ++mt) {
        int m = mt * 16 + lp;
        int ho = m >> 4, wo = m & 15;
        f32x4 acc = {0.f, 0.f, 0.f, 0.f};
        #pragma unroll
        for (int p = 0; p < 5; ++p) {
            const int tA = 2 * p, tB = (p < 4) ? 2 * p + 1 : 8;
            const int khA = tA / 3, kwA = tA % 3;
            const int paA = (khA == 1) ? 0 : 1, dhA = (khA == 0) ? -1 : 0;
            const int pbA = (kwA == 1) ? 0 : 1, dwA = (kwA == 0) ? -1 : 0;
            const int khB = tB / 3, kwB = tB % 3;
            const int paB = (khB == 1) ? 0 : 1, dhB = (khB == 0) ? -1 : 0;
            const int pbB = (kwB == 1) ? 0 : 1, dwB = (kwB == 0) ? -1 : 0;
            int posA = (ho + dhA + 1) * 17 + (wo + dwA + 1);
            int posB = (ho + dhB + 1) * 17 + (wo + dwB + 1);
            int idxA = ((paA * 2 + pbA) * 289 + posA) * 2 + ((lq & 1) ^ (posA & 1));
            int idxB = ((paB * 2 + pbB) * 289 + posB) * 2 + ((lq & 1) ^ (posB & 1));
            short8 b = Xs[(lq < 2) ? idxA : idxB];
            acc = __builtin_amdgcn_mfma_f32_16x16x32_bf16(wf[p], b, acc, 0, 0, 0);
        }
        __align__(8) bf16 ov[4];
        #pragma unroll
        for (int r = 0; r < 4; ++r) ov[r] = f2b(fmaxf(acc[r] + bv[r], 0.f));
        *reinterpret_cast<uint2*>(yi + ((size_t)(ho * 16 + wo)) * 32 + nt * 16 + lq * 4)
            = *reinterpret_cast<uint2*>(ov);
    }
}

// ============ enc3 MFMA: h2b[img][16][16][32] -> h3b[img][8][8][64], stride 2 ============
__global__ __launch_bounds__(256)
void enc3_mfma(const bf16* __restrict__ xg, const bf16* __restrict__ wte,
               const float* __restrict__ bias, bf16* __restrict__ yg)
{
    __shared__ short8 Xs[4 * 81 * 4];
    const int img = blockIdx.x;
    const bf16* xi = xg + (size_t)img * 16 * 16 * 32;
    for (int e = threadIdx.x; e < 4 * 81 * 4; e += 256) {
        int c8 = e & 3, q = e >> 2;
        int pl = q / 81, pos = q - pl * 81;
        int pr = pos / 9, pc = pos - pr * 9;
        int pa = pl >> 1, pb = pl & 1;
        int ihr = 2 * (pr - 1) + pa, iwc = 2 * (pc - 1) + pb;
        short8 v = s8zero();
        if ((unsigned)ihr < 16u && (unsigned)iwc < 16u)
            v = *reinterpret_cast<const short8*>(xi + ((size_t)(ihr * 16 + iwc)) * 32 + c8 * 8);
        Xs[(pl * 81 + pos) * 4 + (c8 ^ (pos & 3))] = v;
    }
    __syncthreads();

    const int wv = threadIdx.x >> 6, lane = threadIdx.x & 63;
    const int lp = lane & 15, lq = lane >> 4;
    const int nt = wv;

    short8 wf[9];
    #pragma unroll
    for (int t = 0; t < 9; ++t)
        wf[t] = *reinterpret_cast<const short8*>(wte + ((size_t)(t * 64 + nt * 16 + lp)) * 32 + lq * 8);
    float bv[4];
    #pragma unroll
    for (int r = 0; r < 4; ++r) bv[r] = bias[nt * 16 + lq * 4 + r];

    bf16* yi = yg + (size_t)img * 8 * 8 * 64;
    for (int mt = 0; mt < 4; ++mt) {
        int m = mt * 16 + lp;
        int ho = m >> 3, wo = m & 7;
        f32x4 acc = {0.f, 0.f, 0.f, 0.f};
        #pragma unroll
        for (int t = 0; t < 9; ++t) {
            const int kh = t / 3, kw2 = t % 3;
            const int pa = (kh == 1) ? 0 : 1, dh = (kh == 0) ? -1 : 0;
            const int pb = (kw2 == 1) ? 0 : 1, dw = (kw2 == 0) ? -1 : 0;
            int pos = (ho + dh + 1) * 9 + (wo + dw + 1);
            int idx = ((pa * 2 + pb) * 81 + pos) * 4 + (lq ^ (pos & 3));
            acc = __builtin_amdgcn_mfma_f32_16x16x32_bf16(wf[t], Xs[idx], acc, 0, 0, 0);
        }
        __align__(8) bf16 ov[4];
        #pragma unroll
        for (int r = 0; r < 4; ++r) ov[r] = f2b(fmaxf(acc[r] + bv[r], 0.f));
        *reinterpret_cast<uint2*>(yi + ((size_t)(ho * 8 + wo)) * 64 + nt * 16 + lq * 4)
            = *reinterpret_cast<uint2*>(ov);
    }
}

// ============ emb = sigmoid(h3b @ kwt^T + kb) -> fp32 ============
__global__ __launch_bounds__(256)
void emb_mfma(const bf16* __restrict__ h3b, const bf16* __restrict__ kwt,
              const float* __restrict__ kb, float* __restrict__ emb)
{
    __shared__ f32x4 Ls[3][7][64];
    const int imgbase = blockIdx.x * 16;
    const int w = threadIdx.x >> 6, lane = threadIdx.x & 63;
    const int lp = lane & 15, lq = lane >> 4;
    const int k0 = w * 1024;

    f32x4 zero = {0.f, 0.f, 0.f, 0.f};
    f32x4 acc[7] = {zero, zero, zero, zero, zero, zero, zero};

    const bf16* bp = h3b + (size_t)(imgbase + lp) * 4096 + k0 + lq * 8;
    const bf16* ap = kwt + (size_t)lp * 4096 + k0 + lq * 8;
    for (int ks = 0; ks < 32; ++ks) {
        short8 bfrag = *reinterpret_cast<const short8*>(bp + ks * 32);
        #pragma unroll
        for (int nt = 0; nt < 7; ++nt) {
            short8 afrag = *reinterpret_cast<const short8*>(ap + (size_t)nt * 16 * 4096 + ks * 32);
            acc[nt] = __builtin_amdgcn_mfma_f32_16x16x32_bf16(afrag, bfrag, acc[nt], 0, 0, 0);
        }
    }
    if (w > 0) {
        #pragma unroll
        for (int nt = 0; nt < 7; ++nt) Ls[w - 1][nt][lane] = acc[nt];
    }
    __syncthreads();
    if (w == 0) {
        #pragma unroll
        for (int nt = 0; nt < 7; ++nt) {
            f32x4 a = acc[nt];
            #pragma unroll
            for (int ww = 0; ww < 3; ++ww) a += Ls[ww][nt][lane];
            const int e0 = nt * 16 + lq * 4;
            #pragma unroll
            for (int r = 0; r < 4; ++r) {
                int e = e0 + r;
                if (e < 110) {
                    float v = a[r] + kb[e];
                    emb[(size_t)(imgbase + lp) * 110 + e] = 1.f / (1.f + expf(-v));
                }
            }
        }
    }
}

// ============ MFMA transpose-conv stride 2 (decoder) ============
template<int COUT, int HIN, int WIN, int HSPLIT>
__global__ __launch_bounds__(256)
void convt2_mfma(const bf16* __restrict__ xg, const bf16* __restrict__ wtb,
                 const float* __restrict__ bias, bf16* __restrict__ yg)
{
    constexpr int CIN = 64, C8 = 8;
    constexpr int WP  = WIN + 1;
    constexpr int HS  = HIN / HSPLIT;
    constexpr int HPS = HS + 1;
    constexpr int NPOS = HPS * WP;
    constexpr int HOUT = HIN * 2, WOUT = WIN * 2;
    constexpr int NT = COUT / 16;
    constexpr int MT = (HS * WIN) / 16;
    __shared__ short8 Xs[NPOS * C8];

    const int img = blockIdx.x;
    const int s   = blockIdx.y;
    const int hqb = s * HS;
    const bf16* xi = xg + (size_t)img * HIN * WIN * CIN;

    for (int e = threadIdx.x; e < NPOS * C8; e += 256) {
        int c8 = e & 7, pos = e >> 3;
        int hl = pos / WP, wi = pos % WP;
        int hi = hqb + hl;
        short8 v = s8zero();
        if (hi < HIN && wi < WIN)
            v = *reinterpret_cast<const short8*>(xi + ((size_t)(hi * WIN + wi)) * CIN + c8 * 8);
        Xs[pos * C8 + (c8 ^ (pos & 7))] = v;
    }
    __syncthreads();

    const int wv = threadIdx.x >> 6, lane = threadIdx.x & 63;
    const int lp = lane & 15, lq = lane >> 4;
    const int nt    = (NT == 4) ? wv : (wv & 1);
    const int mt0   = (NT == 4) ? 0  : (wv >> 1) * (MT / 2);
    const int mtend = (NT == 4) ? MT : mt0 + (MT / 2);

    short8 wf[9][2];
    #pragma unroll
    for (int t = 0; t < 9; ++t) {
        const bf16* wp = wtb + ((size_t)t * COUT + nt * 16 + lp) * CIN + lq * 8;
        wf[t][0] = *reinterpret_cast<const short8*>(wp);
        wf[t][1] = *reinterpret_cast<const short8*>(wp + 32);
    }
    float bv[4];
    #pragma unroll
    for (int r = 0; r < 4; ++r) bv[r] = bias[nt * 16 + lq * 4 + r];

    bf16* yi = yg + (size_t)img * HOUT * WOUT * COUT;
    for (int mt = mt0; mt < mtend; ++mt) {
        int m = mt * 16 + lp;
        int hql = m / WIN, wq = m % WIN;
        f32x4 zero = {0.f, 0.f, 0.f, 0.f};
        f32x4 acc[4] = {zero, zero, zero, zero};
        #pragma unroll
        for (int kh = 0; kh < 3; ++kh) {
            #pragma unroll
            for (int kw = 0; kw < 3; ++kw) {
                const int pa = (kh + 1) & 1, pb = (kw + 1) & 1;
                const int oh = (pa + 1 - kh) >> 1, ow = (pb + 1 - kw) >> 1;
                const int cls = pa * 2 + pb;
                const int t = kh * 3 + kw;
                int pos = (hql + oh) * WP + (wq + ow);
                int sw = pos & 7;
                short8 b0 = Xs[pos * C8 + (lq ^ sw)];
                acc[cls] = __builtin_amdgcn_mfma_f32_16x16x32_bf16(wf[t][0], b0, acc[cls], 0, 0, 0);
                short8 b1 = Xs[pos * C8 + ((4 + lq) ^ sw)];
                acc[cls] = __builtin_amdgcn_mfma_f32_16x16x32_bf16(wf[t][1], b1, acc[cls], 0, 0, 0);
            }
        }
        int hq = hqb + hql;
        #pragma unroll
        for (int cls = 0; cls < 4; ++cls) {
            int pa = cls >> 1, pb = cls & 1;
            int ho = hq * 2 + pa, wo = wq * 2 + pb;
            __align__(8) bf16 ov[4];
            #pragma unroll
            for (int r = 0; r < 4; ++r) ov[r] = f2b(fmaxf(acc[cls][r] + bv[r], 0.f));
            *reinterpret_cast<uint2*>(yi + ((size_t)(ho * WOUT + wo)) * COUT + nt * 16 + lq * 4)
                = *reinterpret_cast<uint2*>(ov);
        }
    }
}

// ============ MFMA transpose-conv stride 1 (32->16) + fused 1x1 (16->3) ============
__global__ __launch_bounds__(256)
void convt1_mfma_fused(const bf16* __restrict__ xg, const bf16* __restrict__ wtb,
                       const float* __restrict__ bias,
                       const float* __restrict__ w4, const float* __restrict__ b4,
                       float* __restrict__ dec)
{
    constexpr int CIN = 32, C8 = 4;
    constexpr int H = 32, W = 32, HR = 18, WR = 34, NPOS = HR * WR;
    __shared__ short8 Xs[NPOS * C8];

    const int img  = blockIdx.x >> 1;
    const int half = blockIdx.x & 1;
    const int hbase = half * 16;
    const bf16* xi = xg + (size_t)img * H * W * CIN;

    for (int e = threadIdx.x; e < NPOS * C8; e += 256) {
        int c8 = e & 3, pos = e >> 2;
        int hr = pos / WR, wr = pos % WR;
        int hi = hbase - 1 + hr, wi = wr - 1;
        short8 v = s8zero();
        if ((unsigned)hi < (unsigned)H && (unsigned)wi < (unsigned)W)
            v = *reinterpret_cast<const short8*>(xi + ((size_t)(hi * W + wi)) * CIN + c8 * 8);
        Xs[pos * C8 + (c8 ^ (pos & 3))] = v;
    }
    __syncthreads();

    const int wv = threadIdx.x >> 6, lane = threadIdx.x & 63;
    const int lp = lane & 15, lq = lane >> 4;

    short8 wf[9];
    #pragma unroll
    for (int t = 0; t < 9; ++t)
        wf[t] = *reinterpret_cast<const short8*>(wtb + ((size_t)t * 16 + lp) * CIN + lq * 8);
    float bv[4];
    #pragma unroll
    for (int r = 0; r < 4; ++r) bv[r] = bias[lq * 4 + r];
    float w4r[3][4];
    #pragma unroll
    for (int j = 0; j < 3; ++j)
        #pragma unroll
        for (int r = 0; r < 4; ++r) w4r[j][r] = w4[j * 16 + lq * 4 + r];
    float b4r[3] = {b4[0], b4[1], b4[2]};

    for (int mt = wv; mt < 32; mt += 4) {
        int m = mt * 16 + lp;
        int hol = m >> 5, wo = m & 31;
        f32x4 acc = {0.f, 0.f, 0.f, 0.f};
        #pragma unroll
        for (int t = 0; t < 9; ++t) {
            int kh = t / 3, kw = t % 3;
            int pos = (hol + 2 - kh) * WR + (wo + 2 - kw);
            short8 b0 = Xs[pos * C8 + (lq ^ (pos & 3))];
            acc = __builtin_amdgcn_mfma_f32_16x16x32_bf16(wf[t], b0, acc, 0, 0, 0);
        }
        float s0 = 0.f, s1 = 0.f, s2 = 0.f;
        #pragma unroll
        for (int r = 0; r < 4; ++r) {
            float v = fmaxf(acc[r] + bv[r], 0.f);
            s0 += v * w4r[0][r]; s1 += v * w4r[1][r]; s2 += v * w4r[2][r];
        }
        s0 += __shfl_xor(s0, 16); s0 += __shfl_xor(s0, 32);
        s1 += __shfl_xor(s1, 16); s1 += __shfl_xor(s1, 32);
        s2 += __shfl_xor(s2, 16); s2 += __shfl_xor(s2, 32);
        if (lq == 0) {
            int ho = hbase + hol;
            size_t base = (size_t)img * 3072 + ho * 32 + wo;
            dec[base]        = s0 + b4r[0];
            dec[base + 1024] = s1 + b4r[1];
            dec[base + 2048] = s2 + b4r[2];
        }
    }
}

// ============ fused classifier: KDE + f1 + f2 + f3, one block per batch element ============
__global__ __launch_bounds__(256)
void mlp_fused(const float* __restrict__ emb, const float* __restrict__ f1wT,
               const float* __restrict__ f1b, const float* __restrict__ f2wT,
               const float* __restrict__ f2b, const float* __restrict__ f3w,
               const float* __restrict__ f3b, float* __restrict__ logits)
{
    __shared__ float es[3520];     // emb[b]: 32 x 110
    __shared__ float fds[1210];
    __shared__ float part[1024];
    __shared__ float m1s[512];
    __shared__ float m2s[256];
    const int b = blockIdx.x, tid = threadIdx.x;

    for (int i = tid; i < 3520; i += 256) es[i] = emb[(size_t)b * 3520 + i];
    __syncthreads();

    // KDE (same math/order as reference path)
    if (tid < 110) {
        float dens[11];
        #pragma unroll
        for (int j = 0; j < 11; ++j) dens[j] = 0.f;
        for (int n = 0; n < 32; ++n) {
            float e = es[n * 110 + tid];
            #pragma unroll
            for (int j = 0; j < 11; ++j) {
                float d = 0.1f * j - e;
                dens[j] += expf(-50.f * d * d);
            }
        }
        float s = 0.f;
        #pragma unroll
        for (int j = 0; j < 11; ++j) s += dens[j];
        float inv = 1.f / s;
        #pragma unroll
        for (int j = 0; j < 11; ++j) fds[tid * 11 + j] = dens[j] * inv;
    }
    __syncthreads();

    // f1: 1210 -> 512 | 128 float4 output groups x 2-way K split
    {
        const int o4 = (tid & 127) * 4, s = tid >> 7;
        const int k0 = s * 605;
        float4 a = {0.f, 0.f, 0.f, 0.f};
        for (int k = k0; k < k0 + 605; ++k) {
            float fv = fds[k];
            float4 wv = *reinterpret_cast<const float4*>(&f1wT[(size_t)k * 512 + o4]);
            a.x += fv * wv.x; a.y += fv * wv.y; a.z += fv * wv.z; a.w += fv * wv.w;
        }
        *reinterpret_cast<float4*>(&part[s * 512 + o4]) = a;
    }
    __syncthreads();
    if (tid < 128) {
        #pragma unroll
        for (int j = 0; j < 4; ++j) {
            int o = tid * 4 + j;
            m1s[o] = fmaxf(part[o] + part[512 + o] + f1b[o], 0.f);
        }
    }
    __syncthreads();

    // f2: 512 -> 256 | 64 float4 groups x 4-way K split
    {
        const int o4 = (tid & 63) * 4, s = tid >> 6;
        const int k0 = s * 128;
        float4 a = {0.f, 0.f, 0.f, 0.f};
        for (int k = k0; k < k0 + 128; ++k) {
            float mv = m1s[k];
            float4 wv = *reinterpret_cast<const float4*>(&f2wT[(size_t)k * 256 + o4]);
            a.x += mv * wv.x; a.y += mv * wv.y; a.z += mv * wv.z; a.w += mv * wv.w;
        }
        *reinterpret_cast<float4*>(&part[s * 256 + o4]) = a;
    }
    __syncthreads();
    if (tid < 64) {
        #pragma unroll
        for (int j = 0; j < 4; ++j) {
            int o = tid * 4 + j;
            m2s[o] = fmaxf(part[o] + part[256 + o] + part[512 + o] + part[768 + o] + f2b[o], 0.f);
        }
    }
    __syncthreads();

    // f3: 256 -> 4
    if (tid < 4) {
        float a = f3b[tid];
        for (int k = 0; k < 256; ++k) a += m2s[k] * f3w[tid * 256 + k];
        logits[b * 4 + tid] = a;
    }
}

// ===================== host side =====================
static Taps4 mk_conv9()
{
    Taps4 T = {};
    T.t[0].n = 9;
    int q = 0;
    for (int kh = 0; kh < 3; ++kh)
        for (int kw = 0; kw < 3; ++kw) {
            T.t[0].oh[q] = kh - 1; T.t[0].ow[q] = kw - 1; T.t[0].ti[q] = kh * 3 + kw; ++q;
        }
    return T;
}

extern "C" void kernel_launch(void* const* d_in, const int* in_sizes, int n_in,
                              void* d_out, int out_size, void* d_ws, size_t ws_size,
                              hipStream_t stream)
{
    const float* x    = (const float*)d_in[0];
    const float* ew1  = (const float*)d_in[1];
    const float* eb1  = (const float*)d_in[2];
    const float* ew2  = (const float*)d_in[3];
    const float* eb2  = (const float*)d_in[4];
    const float* ew3  = (const float*)d_in[5];
    const float* eb3  = (const float*)d_in[6];
    const float* kw   = (const float*)d_in[7];
    const float* kb   = (const float*)d_in[8];
    const float* dw1  = (const float*)d_in[9];
    const float* db1  = (const float*)d_in[10];
    const float* dw2  = (const float*)d_in[11];
    const float* db2  = (const float*)d_in[12];
    const float* dw3  = (const float*)d_in[13];
    const float* db3  = (const float*)d_in[14];
    const float* dw4  = (const float*)d_in[15];
    const float* db4  = (const float*)d_in[16];
    const float* f1w  = (const float*)d_in[17];
    const float* f1b  = (const float*)d_in[18];
    const float* f2w  = (const float*)d_in[19];
    const float* f2b_ = (const float*)d_in[20];
    const float* f3w  = (const float*)d_in[21];
    const float* f3b  = (const float*)d_in[22];

    // ---------- workspace ----------
    char* ws = (char*)d_ws;
    float* emb  = (float*)(ws + 0);          //   901,120
    float* wt1  = (float*)(ws + 901120);     //     1,792
    bf16*  wte2 = (bf16*) (ws + 902912);     //    10,240
    bf16*  wte3 = (bf16*) (ws + 913152);     //    36,864
    bf16*  wtb4 = (bf16*) (ws + 950016);     //    73,728
    bf16*  wtb5 = (bf16*) (ws + 1023744);    //    36,864
    bf16*  wtb6 = (bf16*) (ws + 1060608);    //     9,216
    bf16*  kwt  = (bf16*) (ws + 1069824);    //   917,504
    float* f1wT = (float*)(ws + 1987328);    // 2,478,080 (1210*512)
    float* f2wT = (float*)(ws + 4465408);    //   524,288 (512*256)
    const size_t FIXED = 4989696;

    // per image (bf16 NHWC): h1b 32K (d1b overlays) | h2b 16K | h3b 8K | d2b 64K
    const size_t PER_IMG = 122880;
    int CHUNK = 1024;
    while (CHUNK > 16 && FIXED + (size_t)CHUNK * PER_IMG > ws_size) CHUNK >>= 1;
    const int NCHUNK = 2048 / CHUNK;

    char* p   = ws + FIXED;
    bf16* h1b = (bf16*)(p);
    bf16* h2b = (bf16*)(p + (size_t)CHUNK * 32768);
    bf16* h3b = (bf16*)(p + (size_t)CHUNK * 49152);
    bf16* d2b = (bf16*)(p + (size_t)CHUNK * 57344);
    bf16* d1b = h1b;                          // overlay: h1b dead after enc2

    float* logits = (float*)d_out;            // 64*4
    float* dec    = (float*)d_out + 256;      // 2048*3*32*32 NCHW

    // ---- weight transforms (once per launch) ----
    wtr_conv  <<<(16*3*9  + 255)/256, 256, 0, stream>>>(ew1, wt1, 16, 3);
    wtrb_enc2 <<<(5*32*32 + 255)/256, 256, 0, stream>>>(ew2, wte2);
    wtrb_enc3 <<<(64*32*9 + 255)/256, 256, 0, stream>>>(ew3, wte3);
    wtrb_convt<<<(64*64*9 + 255)/256, 256, 0, stream>>>(dw1, wtb4, 64, 64);
    wtrb_convt<<<(64*32*9 + 255)/256, 256, 0, stream>>>(dw2, wtb5, 64, 32);
    wtrb_convt<<<(32*16*9 + 255)/256, 256, 0, stream>>>(dw3, wtb6, 32, 16);
    wtr_kw    <<<(112*4096 + 255)/256, 256, 0, stream>>>(kw, kwt);
    wtr_dense <<<(512*1210 + 255)/256, 256, 0, stream>>>(f1w, f1wT, 512, 1210);
    wtr_dense <<<(256*512  + 255)/256, 256, 0, stream>>>(f2w, f2wT, 256, 512);

    const Taps4 T9 = mk_conv9();

    for (int c = 0; c < NCHUNK; ++c) {
        const float* xc   = x   + (size_t)c * CHUNK * 3 * 1024;
        float*       decc = dec + (size_t)c * CHUNK * 3 * 1024;
        float*       embc = emb + (size_t)c * CHUNK * 110;

        // encoder
        conv_gemm<3,16,32,32,32,32, 1,1, 16,16, 3, true, true>
            <<<dim3(CHUNK*4,1), 256, 0, stream>>>(xc, wt1, eb1, h1b, T9);
        enc2_mfma<<<CHUNK, 256, 0, stream>>>(h1b, wte2, eb2, h2b);
        enc3_mfma<<<CHUNK, 256, 0, stream>>>(h2b, wte3, eb3, h3b);

        // embedding
        emb_mfma<<<CHUNK/16, 256, 0, stream>>>(h3b, kwt, kb, embc);

        // decoder
        convt2_mfma<64, 8, 8, 1>  <<<dim3(CHUNK,1), 256, 0, stream>>>(h3b, wtb4, db1, d1b);
        convt2_mfma<32, 16, 16, 2><<<dim3(CHUNK,2), 256, 0, stream>>>(d1b, wtb5, db2, d2b);
        convt1_mfma_fused         <<<dim3(CHUNK*2,1), 256, 0, stream>>>(d2b, wtb6, db3, dw4, db4, decc);
    }

    // classifier (fused KDE + MLP, fp32)
    mlp_fused<<<64, 256, 0, stream>>>(emb, f1wT, f1b, f2wT, f2b_, f3w, f3b, logits);
}

// Round 13
// 376.223 us; speedup vs baseline: 22.1436x; 1.1416x over previous
//
#include <hip/hip_runtime.h>
#include <hip/hip_bf16.h>
#include <stdint.h>

typedef __hip_bfloat16 bf16;
typedef __attribute__((ext_vector_type(8))) short short8;
typedef __attribute__((ext_vector_type(4))) float f32x4;

__device__ __forceinline__ bf16 f2b(float v){ return __float2bfloat16(v); }
__device__ __forceinline__ short s2s(float v){ bf16 b = __float2bfloat16(v); return *reinterpret_cast<short*>(&b); }
__device__ __forceinline__ short8 s8zero()
{
    short8 z;
    for (int i = 0; i < 8; ++i) z[i] = 0;
    return z;
}

// ==== enc1 weights: ew1[co 16][ci 3][9] -> wte1[q 3][co 16][k 32], k=j*8+ci, tap=4q+j ====
__global__ void wtrb_enc1(const float* __restrict__ w, bf16* __restrict__ wt)
{
    int idx = blockIdx.x * blockDim.x + threadIdx.x;
    if (idx >= 3 * 16 * 32) return;
    int q = idx >> 9, r = idx & 511;
    int co = r >> 5, k = r & 31;
    int j = k >> 3, ci = k & 7;
    int t = 4 * q + j;
    float v = (ci < 3 && t < 9) ? w[((size_t)co * 3 + ci) * 9 + t] : 0.f;
    wt[idx] = f2b(v);
}

// ==== enc2 paired weights: ew2[co 32][ci 16][9] -> wte2[p 5][co 32][k 32] bf16 ====
__global__ void wtrb_enc2(const float* __restrict__ w, bf16* __restrict__ wt)
{
    int idx = blockIdx.x * blockDim.x + threadIdx.x;
    if (idx >= 5 * 32 * 32) return;
    int p = idx >> 10, r = idx & 1023;
    int co = r >> 5, k = r & 31;
    int t = 2 * p + (k >> 4);
    int ch = k & 15;
    float v = (t <= 8) ? w[((size_t)co * 16 + ch) * 9 + t] : 0.f;
    wt[idx] = f2b(v);
}

// ==== enc3 weights: ew3[co 64][ci 32][9] -> wte3[t 9][co 64][ci 32] bf16 ====
__global__ void wtrb_enc3(const float* __restrict__ w, bf16* __restrict__ wt)
{
    int idx = blockIdx.x * blockDim.x + threadIdx.x;
    if (idx >= 64 * 32 * 9) return;
    int co = idx / 288;
    int r  = idx - co * 288;
    int ci = r / 9, t = r - ci * 9;
    wt[((size_t)t * 64 + co) * 32 + ci] = f2b(w[idx]);
}

// ============ decoder weight transform: w[ci][co][9] -> wtb[t][co][ci] bf16 ============
__global__ void wtrb_convt(const float* __restrict__ w, bf16* __restrict__ wt,
                           int CIN, int COUT)
{
    int idx = blockIdx.x * blockDim.x + threadIdx.x;
    if (idx >= CIN * COUT * 9) return;
    int ci = idx / (COUT * 9);
    int r  = idx - ci * COUT * 9;
    int co = r / 9, t = r - co * 9;
    wt[((size_t)t * COUT + co) * CIN + ci] = f2b(w[idx]);
}

// ============ kw transform -> kwt[e][pos*64+ci] bf16, padded to 112 ====
__global__ void wtr_kw(const float* __restrict__ kw, bf16* __restrict__ kwt)
{
    int idx = blockIdx.x * blockDim.x + threadIdx.x;
    if (idx >= 112 * 4096) return;
    int e = idx >> 12, kk = idx & 4095;
    int pos = kk >> 6, ci = kk & 63;
    float v = (e < 110) ? kw[(size_t)e * 4096 + ci * 64 + pos] : 0.f;
    kwt[idx] = f2b(v);
}

// ==== dense weight transpose: w[OUT][K] -> wT[K][OUT] fp32 ====
__global__ void wtr_dense(const float* __restrict__ w, float* __restrict__ wT,
                          int OUT, int K)
{
    int idx = blockIdx.x * blockDim.x + threadIdx.x;
    if (idx >= OUT * K) return;
    int o = idx / K, k = idx - o * K;
    wT[(size_t)k * OUT + o] = w[idx];
}

// ============ enc1 MFMA: x[img][3][32][32] fp32 -> h1b[img][32][32][16], K=4taps x 8ch ============
__global__ __launch_bounds__(256)
void enc1_mfma(const float* __restrict__ xg, const bf16* __restrict__ wte,
               const float* __restrict__ bias, bf16* __restrict__ yg)
{
    __shared__ short8 Xs[34 * 34];               // 18,496 B; pos padded 1 halo; 8ch packed (3 real)
    const int img = blockIdx.x;
    const float* xi = xg + (size_t)img * 3072;
    for (int e = threadIdx.x; e < 1156; e += 256) {
        int hr = e / 34, wc = e % 34;
        int hi = hr - 1, wi = wc - 1;
        short8 v = s8zero();
        if ((unsigned)hi < 32u && (unsigned)wi < 32u) {
            int p = hi * 32 + wi;
            v[0] = s2s(xi[p]);
            v[1] = s2s(xi[p + 1024]);
            v[2] = s2s(xi[p + 2048]);
        }
        Xs[e] = v;
    }
    __syncthreads();

    const int wv = threadIdx.x >> 6, lane = threadIdx.x & 63;
    const int lp = lane & 15, lq = lane >> 4;

    short8 wf[3];
    #pragma unroll
    for (int q = 0; q < 3; ++q)
        wf[q] = *reinterpret_cast<const short8*>(wte + ((size_t)(q * 16 + lp)) * 32 + lq * 8);
    float bv[4];
    #pragma unroll
    for (int r = 0; r < 4; ++r) bv[r] = bias[lq * 4 + r];

    bf16* yi = yg + (size_t)img * 1024 * 16;
    for (int mt = wv * 16; mt < wv * 16 + 16; ++mt) {
        int m = mt * 16 + lp;
        int ho = m >> 5, wo = m & 31;
        f32x4 acc = {0.f, 0.f, 0.f, 0.f};
        #pragma unroll
        for (int q = 0; q < 3; ++q) {
            int t = 4 * q + lq;
            if (t > 8) t = 8;                     // padded taps: weights are zero
            int dh = t / 3 - 1, dw = t % 3 - 1;
            int pos = (ho + dh + 1) * 34 + (wo + dw + 1);
            acc = __builtin_amdgcn_mfma_f32_16x16x32_bf16(wf[q], Xs[pos], acc, 0, 0, 0);
        }
        __align__(8) bf16 ov[4];
        #pragma unroll
        for (int r = 0; r < 4; ++r) ov[r] = f2b(fmaxf(acc[r] + bv[r], 0.f));
        *reinterpret_cast<uint2*>(yi + (size_t)m * 16 + lq * 4) = *reinterpret_cast<uint2*>(ov);
    }
}

// ============ enc2 MFMA: h1b[img][32][32][16] -> h2b[img][16][16][32], stride 2 ============
__global__ __launch_bounds__(256)
void enc2_mfma(const bf16* __restrict__ xg, const bf16* __restrict__ wte,
               const float* __restrict__ bias, bf16* __restrict__ yg)
{
    __shared__ short8 Xs[4 * 289 * 2];
    const int img = blockIdx.x;
    const bf16* xi = xg + (size_t)img * 32 * 32 * 16;
    for (int e = threadIdx.x; e < 4 * 289 * 2; e += 256) {
        int c8 = e & 1, q = e >> 1;
        int pl = q / 289, pos = q - pl * 289;
        int pr = pos / 17, pc = pos - pr * 17;
        int pa = pl >> 1, pb = pl & 1;
        int ihr = 2 * (pr - 1) + pa, iwc = 2 * (pc - 1) + pb;
        short8 v = s8zero();
        if ((unsigned)ihr < 32u && (unsigned)iwc < 32u)
            v = *reinterpret_cast<const short8*>(xi + ((size_t)(ihr * 32 + iwc)) * 16 + c8 * 8);
        Xs[(pl * 289 + pos) * 2 + (c8 ^ (pos & 1))] = v;
    }
    __syncthreads();

    const int wv = threadIdx.x >> 6, lane = threadIdx.x & 63;
    const int lp = lane & 15, lq = lane >> 4;
    const int nt = wv & 1, mh = wv >> 1;

    short8 wf[5];
    #pragma unroll
    for (int p = 0; p < 5; ++p)
        wf[p] = *reinterpret_cast<const short8*>(wte + ((size_t)(p * 32 + nt * 16 + lp)) * 32 + lq * 8);
    float bv[4];
    #pragma unroll
    for (int r = 0; r < 4; ++r) bv[r] = bias[nt * 16 + lq * 4 + r];

    bf16* yi = yg + (size_t)img * 16 * 16 * 32;
    for (int mt = mh * 8; mt < mh * 8 + 8; ++mt) {
        int m = mt * 16 + lp;
        int ho = m >> 4, wo = m & 15;
        f32x4 acc = {0.f, 0.f, 0.f, 0.f};
        #pragma unroll
        for (int p = 0; p < 5; ++p) {
            const int tA = 2 * p, tB = (p < 4) ? 2 * p + 1 : 8;
            const int khA = tA / 3, kwA = tA % 3;
            const int paA = (khA == 1) ? 0 : 1, dhA = (khA == 0) ? -1 : 0;
            const int pbA = (kwA == 1) ? 0 : 1, dwA = (kwA == 0) ? -1 : 0;
            const int khB = tB / 3, kwB = tB % 3;
            const int paB = (khB == 1) ? 0 : 1, dhB = (khB == 0) ? -1 : 0;
            const int pbB = (kwB == 1) ? 0 : 1, dwB = (kwB == 0) ? -1 : 0;
            int posA = (ho + dhA + 1) * 17 + (wo + dwA + 1);
            int posB = (ho + dhB + 1) * 17 + (wo + dwB + 1);
            int idxA = ((paA * 2 + pbA) * 289 + posA) * 2 + ((lq & 1) ^ (posA & 1));
            int idxB = ((paB * 2 + pbB) * 289 + posB) * 2 + ((lq & 1) ^ (posB & 1));
            short8 b = Xs[(lq < 2) ? idxA : idxB];
            acc = __builtin_amdgcn_mfma_f32_16x16x32_bf16(wf[p], b, acc, 0, 0, 0);
        }
        __align__(8) bf16 ov[4];
        #pragma unroll
        for (int r = 0; r < 4; ++r) ov[r] = f2b(fmaxf(acc[r] + bv[r], 0.f));
        *reinterpret_cast<uint2*>(yi + ((size_t)(ho * 16 + wo)) * 32 + nt * 16 + lq * 4)
            = *reinterpret_cast<uint2*>(ov);
    }
}

// ============ enc3 MFMA: h2b[img][16][16][32] -> h3b[img][8][8][64], stride 2 ============
__global__ __launch_bounds__(256)
void enc3_mfma(const bf16* __restrict__ xg, const bf16* __restrict__ wte,
               const float* __restrict__ bias, bf16* __restrict__ yg)
{
    __shared__ short8 Xs[4 * 81 * 4];
    const int img = blockIdx.x;
    const bf16* xi = xg + (size_t)img * 16 * 16 * 32;
    for (int e = threadIdx.x; e < 4 * 81 * 4; e += 256) {
        int c8 = e & 3, q = e >> 2;
        int pl = q / 81, pos = q - pl * 81;
        int pr = pos / 9, pc = pos - pr * 9;
        int pa = pl >> 1, pb = pl & 1;
        int ihr = 2 * (pr - 1) + pa, iwc = 2 * (pc - 1) + pb;
        short8 v = s8zero();
        if ((unsigned)ihr < 16u && (unsigned)iwc < 16u)
            v = *reinterpret_cast<const short8*>(xi + ((size_t)(ihr * 16 + iwc)) * 32 + c8 * 8);
        Xs[(pl * 81 + pos) * 4 + (c8 ^ (pos & 3))] = v;
    }
    __syncthreads();

    const int wv = threadIdx.x >> 6, lane = threadIdx.x & 63;
    const int lp = lane & 15, lq = lane >> 4;
    const int nt = wv;

    short8 wf[9];
    #pragma unroll
    for (int t = 0; t < 9; ++t)
        wf[t] = *reinterpret_cast<const short8*>(wte + ((size_t)(t * 64 + nt * 16 + lp)) * 32 + lq * 8);
    float bv[4];
    #pragma unroll
    for (int r = 0; r < 4; ++r) bv[r] = bias[nt * 16 + lq * 4 + r];

    bf16* yi = yg + (size_t)img * 8 * 8 * 64;
    for (int mt = 0; mt < 4; ++mt) {
        int m = mt * 16 + lp;
        int ho = m >> 3, wo = m & 7;
        f32x4 acc = {0.f, 0.f, 0.f, 0.f};
        #pragma unroll
        for (int t = 0; t < 9; ++t) {
            const int kh = t / 3, kw2 = t % 3;
            const int pa = (kh == 1) ? 0 : 1, dh = (kh == 0) ? -1 : 0;
            const int pb = (kw2 == 1) ? 0 : 1, dw = (kw2 == 0) ? -1 : 0;
            int pos = (ho + dh + 1) * 9 + (wo + dw + 1);
            int idx = ((pa * 2 + pb) * 81 + pos) * 4 + (lq ^ (pos & 3));
            acc = __builtin_amdgcn_mfma_f32_16x16x32_bf16(wf[t], Xs[idx], acc, 0, 0, 0);
        }
        __align__(8) bf16 ov[4];
        #pragma unroll
        for (int r = 0; r < 4; ++r) ov[r] = f2b(fmaxf(acc[r] + bv[r], 0.f));
        *reinterpret_cast<uint2*>(yi + ((size_t)(ho * 8 + wo)) * 64 + nt * 16 + lq * 4)
            = *reinterpret_cast<uint2*>(ov);
    }
}

// ============ emb = sigmoid(h3b @ kwt^T + kb); n-tile via blockIdx.y ============
__global__ __launch_bounds__(256)
void emb_mfma(const bf16* __restrict__ h3b, const bf16* __restrict__ kwt,
              const float* __restrict__ kb, float* __restrict__ emb)
{
    __shared__ f32x4 Ls[3][64];
    const int imgbase = blockIdx.x * 16;
    const int nt = blockIdx.y;
    const int w = threadIdx.x >> 6, lane = threadIdx.x & 63;
    const int lp = lane & 15, lq = lane >> 4;
    const int k0 = w * 1024;

    f32x4 acc = {0.f, 0.f, 0.f, 0.f};
    const bf16* bp = h3b + (size_t)(imgbase + lp) * 4096 + k0 + lq * 8;
    const bf16* ap = kwt + (size_t)(nt * 16 + lp) * 4096 + k0 + lq * 8;
    for (int ks = 0; ks < 32; ++ks) {
        short8 bfrag = *reinterpret_cast<const short8*>(bp + ks * 32);
        short8 afrag = *reinterpret_cast<const short8*>(ap + ks * 32);
        acc = __builtin_amdgcn_mfma_f32_16x16x32_bf16(afrag, bfrag, acc, 0, 0, 0);
    }
    if (w > 0) Ls[w - 1][lane] = acc;
    __syncthreads();
    if (w == 0) {
        #pragma unroll
        for (int ww = 0; ww < 3; ++ww) acc += Ls[ww][lane];
        const int e0 = nt * 16 + lq * 4;
        #pragma unroll
        for (int r = 0; r < 4; ++r) {
            int e = e0 + r;
            if (e < 110) {
                float v = acc[r] + kb[e];
                emb[(size_t)(imgbase + lp) * 110 + e] = 1.f / (1.f + expf(-v));
            }
        }
    }
}

// ============ MFMA transpose-conv stride 2 (decoder) ============
template<int COUT, int HIN, int WIN, int HSPLIT>
__global__ __launch_bounds__(256)
void convt2_mfma(const bf16* __restrict__ xg, const bf16* __restrict__ wtb,
                 const float* __restrict__ bias, bf16* __restrict__ yg)
{
    constexpr int CIN = 64, C8 = 8;
    constexpr int WP  = WIN + 1;
    constexpr int HS  = HIN / HSPLIT;
    constexpr int HPS = HS + 1;
    constexpr int NPOS = HPS * WP;
    constexpr int HOUT = HIN * 2, WOUT = WIN * 2;
    constexpr int NT = COUT / 16;
    constexpr int MT = (HS * WIN) / 16;
    __shared__ short8 Xs[NPOS * C8];

    const int img = blockIdx.x;
    const int s   = blockIdx.y;
    const int hqb = s * HS;
    const bf16* xi = xg + (size_t)img * HIN * WIN * CIN;

    for (int e = threadIdx.x; e < NPOS * C8; e += 256) {
        int c8 = e & 7, pos = e >> 3;
        int hl = pos / WP, wi = pos % WP;
        int hi = hqb + hl;
        short8 v = s8zero();
        if (hi < HIN && wi < WIN)
            v = *reinterpret_cast<const short8*>(xi + ((size_t)(hi * WIN + wi)) * CIN + c8 * 8);
        Xs[pos * C8 + (c8 ^ (pos & 7))] = v;
    }
    __syncthreads();

    const int wv = threadIdx.x >> 6, lane = threadIdx.x & 63;
    const int lp = lane & 15, lq = lane >> 4;
    const int nt    = (NT == 4) ? wv : (wv & 1);
    const int mt0   = (NT == 4) ? 0  : (wv >> 1) * (MT / 2);
    const int mtend = (NT == 4) ? MT : mt0 + (MT / 2);

    short8 wf[9][2];
    #pragma unroll
    for (int t = 0; t < 9; ++t) {
        const bf16* wp = wtb + ((size_t)t * COUT + nt * 16 + lp) * CIN + lq * 8;
        wf[t][0] = *reinterpret_cast<const short8*>(wp);
        wf[t][1] = *reinterpret_cast<const short8*>(wp + 32);
    }
    float bv[4];
    #pragma unroll
    for (int r = 0; r < 4; ++r) bv[r] = bias[nt * 16 + lq * 4 + r];

    bf16* yi = yg + (size_t)img * HOUT * WOUT * COUT;
    for (int mt = mt0; mt < mtend; ++mt) {
        int m = mt * 16 + lp;
        int hql = m / WIN, wq = m % WIN;
        f32x4 zero = {0.f, 0.f, 0.f, 0.f};
        f32x4 acc[4] = {zero, zero, zero, zero};
        #pragma unroll
        for (int kh = 0; kh < 3; ++kh) {
            #pragma unroll
            for (int kw = 0; kw < 3; ++kw) {
                const int pa = (kh + 1) & 1, pb = (kw + 1) & 1;
                const int oh = (pa + 1 - kh) >> 1, ow = (pb + 1 - kw) >> 1;
                const int cls = pa * 2 + pb;
                const int t = kh * 3 + kw;
                int pos = (hql + oh) * WP + (wq + ow);
                int sw = pos & 7;
                short8 b0 = Xs[pos * C8 + (lq ^ sw)];
                acc[cls] = __builtin_amdgcn_mfma_f32_16x16x32_bf16(wf[t][0], b0, acc[cls], 0, 0, 0);
                short8 b1 = Xs[pos * C8 + ((4 + lq) ^ sw)];
                acc[cls] = __builtin_amdgcn_mfma_f32_16x16x32_bf16(wf[t][1], b1, acc[cls], 0, 0, 0);
            }
        }
        int hq = hqb + hql;
        #pragma unroll
        for (int cls = 0; cls < 4; ++cls) {
            int pa = cls >> 1, pb = cls & 1;
            int ho = hq * 2 + pa, wo = wq * 2 + pb;
            __align__(8) bf16 ov[4];
            #pragma unroll
            for (int r = 0; r < 4; ++r) ov[r] = f2b(fmaxf(acc[cls][r] + bv[r], 0.f));
            *reinterpret_cast<uint2*>(yi + ((size_t)(ho * WOUT + wo)) * COUT + nt * 16 + lq * 4)
                = *reinterpret_cast<uint2*>(ov);
        }
    }
}

// ============ MFMA transpose-conv stride 1 (32->16) + fused 1x1 (16->3) ============
__global__ __launch_bounds__(256)
void convt1_mfma_fused(const bf16* __restrict__ xg, const bf16* __restrict__ wtb,
                       const float* __restrict__ bias,
                       const float* __restrict__ w4, const float* __restrict__ b4,
                       float* __restrict__ dec)
{
    constexpr int CIN = 32, C8 = 4;
    constexpr int H = 32, W = 32, HR = 18, WR = 34, NPOS = HR * WR;
    __shared__ short8 Xs[NPOS * C8];

    const int img  = blockIdx.x >> 1;
    const int half = blockIdx.x & 1;
    const int hbase = half * 16;
    const bf16* xi = xg + (size_t)img * H * W * CIN;

    for (int e = threadIdx.x; e < NPOS * C8; e += 256) {
        int c8 = e & 3, pos = e >> 2;
        int hr = pos / WR, wr = pos % WR;
        int hi = hbase - 1 + hr, wi = wr - 1;
        short8 v = s8zero();
        if ((unsigned)hi < (unsigned)H && (unsigned)wi < (unsigned)W)
            v = *reinterpret_cast<const short8*>(xi + ((size_t)(hi * W + wi)) * CIN + c8 * 8);
        Xs[pos * C8 + (c8 ^ (pos & 3))] = v;
    }
    __syncthreads();

    const int wv = threadIdx.x >> 6, lane = threadIdx.x & 63;
    const int lp = lane & 15, lq = lane >> 4;

    short8 wf[9];
    #pragma unroll
    for (int t = 0; t < 9; ++t)
        wf[t] = *reinterpret_cast<const short8*>(wtb + ((size_t)t * 16 + lp) * CIN + lq * 8);
    float bv[4];
    #pragma unroll
    for (int r = 0; r < 4; ++r) bv[r] = bias[lq * 4 + r];
    float w4r[3][4];
    #pragma unroll
    for (int j = 0; j < 3; ++j)
        #pragma unroll
        for (int r = 0; r < 4; ++r) w4r[j][r] = w4[j * 16 + lq * 4 + r];
    float b4r[3] = {b4[0], b4[1], b4[2]};

    for (int mt = wv; mt < 32; mt += 4) {
        int m = mt * 16 + lp;
        int hol = m >> 5, wo = m & 31;
        f32x4 acc = {0.f, 0.f, 0.f, 0.f};
        #pragma unroll
        for (int t = 0; t < 9; ++t) {
            int kh = t / 3, kw = t % 3;
            int pos = (hol + 2 - kh) * WR + (wo + 2 - kw);
            short8 b0 = Xs[pos * C8 + (lq ^ (pos & 3))];
            acc = __builtin_amdgcn_mfma_f32_16x16x32_bf16(wf[t], b0, acc, 0, 0, 0);
        }
        float s0 = 0.f, s1 = 0.f, s2 = 0.f;
        #pragma unroll
        for (int r = 0; r < 4; ++r) {
            float v = fmaxf(acc[r] + bv[r], 0.f);
            s0 += v * w4r[0][r]; s1 += v * w4r[1][r]; s2 += v * w4r[2][r];
        }
        s0 += __shfl_xor(s0, 16); s0 += __shfl_xor(s0, 32);
        s1 += __shfl_xor(s1, 16); s1 += __shfl_xor(s1, 32);
        s2 += __shfl_xor(s2, 16); s2 += __shfl_xor(s2, 32);
        if (lq == 0) {
            int ho = hbase + hol;
            size_t base = (size_t)img * 3072 + ho * 32 + wo;
            dec[base]        = s0 + b4r[0];
            dec[base + 1024] = s1 + b4r[1];
            dec[base + 2048] = s2 + b4r[2];
        }
    }
}

// ============ KDE + f1 slice: grid (64 batch, 4 output-slices of 128) ============
__global__ __launch_bounds__(256)
void kde_f1(const float* __restrict__ emb, const float* __restrict__ f1wT,
            const float* __restrict__ f1b, float* __restrict__ m1g)
{
    __shared__ float es[3520];
    __shared__ float fds[1210];
    __shared__ float part[8 * 128];
    const int b = blockIdx.x, s4 = blockIdx.y, tid = threadIdx.x;

    for (int i = tid; i < 3520; i += 256) es[i] = emb[(size_t)b * 3520 + i];
    __syncthreads();

    if (tid < 110) {
        float dens[11];
        #pragma unroll
        for (int j = 0; j < 11; ++j) dens[j] = 0.f;
        for (int n = 0; n < 32; ++n) {
            float e = es[n * 110 + tid];
            #pragma unroll
            for (int j = 0; j < 11; ++j) {
                float d = 0.1f * j - e;
                dens[j] += expf(-50.f * d * d);
            }
        }
        float s = 0.f;
        #pragma unroll
        for (int j = 0; j < 11; ++j) s += dens[j];
        float inv = 1.f / s;
        #pragma unroll
        for (int j = 0; j < 11; ++j) fds[tid * 11 + j] = dens[j] * inv;
    }
    __syncthreads();

    // f1 slice: outputs [s4*128, s4*128+128); 32 float4-groups x 8-way K split
    {
        const int g = tid & 31, s = tid >> 5;
        const int o4 = s4 * 128 + g * 4;
        const int k0 = s * 152, kend = (k0 + 152 < 1210) ? k0 + 152 : 1210;
        float4 a = {0.f, 0.f, 0.f, 0.f};
        for (int k = k0; k < kend; ++k) {
            float fv = fds[k];
            float4 wv = *reinterpret_cast<const float4*>(&f1wT[(size_t)k * 512 + o4]);
            a.x += fv * wv.x; a.y += fv * wv.y; a.z += fv * wv.z; a.w += fv * wv.w;
        }
        *reinterpret_cast<float4*>(&part[s * 128 + g * 4]) = a;
    }
    __syncthreads();
    if (tid < 128) {
        float v = 0.f;
        #pragma unroll
        for (int s = 0; s < 8; ++s) v += part[s * 128 + tid];
        int o = s4 * 128 + tid;
        m1g[(size_t)b * 512 + o] = fmaxf(v + f1b[o], 0.f);
    }
}

// ============ f2 + f3: grid 64 ============
__global__ __launch_bounds__(256)
void f2f3(const float* __restrict__ m1g, const float* __restrict__ f2wT,
          const float* __restrict__ f2b, const float* __restrict__ f3w,
          const float* __restrict__ f3b, float* __restrict__ logits)
{
    __shared__ float m1s[512];
    __shared__ float part[1024];
    __shared__ float m2s[256];
    const int b = blockIdx.x, tid = threadIdx.x;

    for (int i = tid; i < 512; i += 256) m1s[i] = m1g[(size_t)b * 512 + i];
    __syncthreads();

    {
        const int o4 = (tid & 63) * 4, s = tid >> 6;
        const int k0 = s * 128;
        float4 a = {0.f, 0.f, 0.f, 0.f};
        for (int k = k0; k < k0 + 128; ++k) {
            float mv = m1s[k];
            float4 wv = *reinterpret_cast<const float4*>(&f2wT[(size_t)k * 256 + o4]);
            a.x += mv * wv.x; a.y += mv * wv.y; a.z += mv * wv.z; a.w += mv * wv.w;
        }
        *reinterpret_cast<float4*>(&part[s * 256 + o4]) = a;
    }
    __syncthreads();
    if (tid < 64) {
        #pragma unroll
        for (int j = 0; j < 4; ++j) {
            int o = tid * 4 + j;
            m2s[o] = fmaxf(part[o] + part[256 + o] + part[512 + o] + part[768 + o] + f2b[o], 0.f);
        }
    }
    __syncthreads();
    if (tid < 4) {
        float a = f3b[tid];
        for (int k = 0; k < 256; ++k) a += m2s[k] * f3w[tid * 256 + k];
        logits[b * 4 + tid] = a;
    }
}

extern "C" void kernel_launch(void* const* d_in, const int* in_sizes, int n_in,
                              void* d_out, int out_size, void* d_ws, size_t ws_size,
                              hipStream_t stream)
{
    const float* x    = (const float*)d_in[0];
    const float* ew1  = (const float*)d_in[1];
    const float* eb1  = (const float*)d_in[2];
    const float* ew2  = (const float*)d_in[3];
    const float* eb2  = (const float*)d_in[4];
    const float* ew3  = (const float*)d_in[5];
    const float* eb3  = (const float*)d_in[6];
    const float* kw   = (const float*)d_in[7];
    const float* kb   = (const float*)d_in[8];
    const float* dw1  = (const float*)d_in[9];
    const float* db1  = (const float*)d_in[10];
    const float* dw2  = (const float*)d_in[11];
    const float* db2  = (const float*)d_in[12];
    const float* dw3  = (const float*)d_in[13];
    const float* db3  = (const float*)d_in[14];
    const float* dw4  = (const float*)d_in[15];
    const float* db4  = (const float*)d_in[16];
    const float* f1w  = (const float*)d_in[17];
    const float* f1b  = (const float*)d_in[18];
    const float* f2w  = (const float*)d_in[19];
    const float* f2b_ = (const float*)d_in[20];
    const float* f3w  = (const float*)d_in[21];
    const float* f3b  = (const float*)d_in[22];

    // ---------- workspace ----------
    char* ws = (char*)d_ws;
    float* emb  = (float*)(ws + 0);          //   901,120
    float* m1g  = (float*)(ws + 901120);     //   131,072
    bf16*  wte1 = (bf16*) (ws + 1032192);    //     3,072
    bf16*  wte2 = (bf16*) (ws + 1035264);    //    10,240
    bf16*  wte3 = (bf16*) (ws + 1045504);    //    36,864
    bf16*  wtb4 = (bf16*) (ws + 1082368);    //    73,728
    bf16*  wtb5 = (bf16*) (ws + 1156096);    //    36,864
    bf16*  wtb6 = (bf16*) (ws + 1192960);    //     9,216
    bf16*  kwt  = (bf16*) (ws + 1202176);    //   917,504
    float* f1wT = (float*)(ws + 2119680);    // 2,478,080
    float* f2wT = (float*)(ws + 4597760);    //   524,288
    const size_t FIXED = 5122048;

    // per image (bf16 NHWC): h1b 32K (d1b overlays) | h2b 16K | h3b 8K | d2b 64K
    const size_t PER_IMG = 122880;
    int CHUNK = 1024;
    while (CHUNK > 16 && FIXED + (size_t)CHUNK * PER_IMG > ws_size) CHUNK >>= 1;
    const int NCHUNK = 2048 / CHUNK;

    char* p   = ws + FIXED;
    bf16* h1b = (bf16*)(p);
    bf16* h2b = (bf16*)(p + (size_t)CHUNK * 32768);
    bf16* h3b = (bf16*)(p + (size_t)CHUNK * 49152);
    bf16* d2b = (bf16*)(p + (size_t)CHUNK * 57344);
    bf16* d1b = h1b;                          // overlay: h1b dead after enc2

    float* logits = (float*)d_out;            // 64*4
    float* dec    = (float*)d_out + 256;      // 2048*3*32*32 NCHW

    // ---- weight transforms (once per launch) ----
    wtrb_enc1 <<<(3*16*32 + 255)/256, 256, 0, stream>>>(ew1, wte1);
    wtrb_enc2 <<<(5*32*32 + 255)/256, 256, 0, stream>>>(ew2, wte2);
    wtrb_enc3 <<<(64*32*9 + 255)/256, 256, 0, stream>>>(ew3, wte3);
    wtrb_convt<<<(64*64*9 + 255)/256, 256, 0, stream>>>(dw1, wtb4, 64, 64);
    wtrb_convt<<<(64*32*9 + 255)/256, 256, 0, stream>>>(dw2, wtb5, 64, 32);
    wtrb_convt<<<(32*16*9 + 255)/256, 256, 0, stream>>>(dw3, wtb6, 32, 16);
    wtr_kw    <<<(112*4096 + 255)/256, 256, 0, stream>>>(kw, kwt);
    wtr_dense <<<(512*1210 + 255)/256, 256, 0, stream>>>(f1w, f1wT, 512, 1210);
    wtr_dense <<<(256*512  + 255)/256, 256, 0, stream>>>(f2w, f2wT, 256, 512);

    for (int c = 0; c < NCHUNK; ++c) {
        const float* xc   = x   + (size_t)c * CHUNK * 3 * 1024;
        float*       decc = dec + (size_t)c * CHUNK * 3 * 1024;
        float*       embc = emb + (size_t)c * CHUNK * 110;

        // encoder (all MFMA)
        enc1_mfma<<<CHUNK, 256, 0, stream>>>(xc, wte1, eb1, h1b);
        enc2_mfma<<<CHUNK, 256, 0, stream>>>(h1b, wte2, eb2, h2b);
        enc3_mfma<<<CHUNK, 256, 0, stream>>>(h2b, wte3, eb3, h3b);

        // embedding (n-split grid)
        emb_mfma<<<dim3(CHUNK/16, 7), 256, 0, stream>>>(h3b, kwt, kb, embc);

        // decoder
        convt2_mfma<64, 8, 8, 1>  <<<dim3(CHUNK,1), 256, 0, stream>>>(h3b, wtb4, db1, d1b);
        convt2_mfma<32, 16, 16, 2><<<dim3(CHUNK,2), 256, 0, stream>>>(d1b, wtb5, db2, d2b);
        convt1_mfma_fused         <<<dim3(CHUNK*2,1), 256, 0, stream>>>(d2b, wtb6, db3, dw4, db4, decc);
    }

    // classifier (fp32, parallel-split)
    kde_f1<<<dim3(64, 4), 256, 0, stream>>>(emb, f1wT, f1b, m1g);
    f2f3  <<<64, 256, 0, stream>>>(m1g, f2wT, f2b_, f3w, f3b, logits);
}

// Round 14
// 307.995 us; speedup vs baseline: 27.0489x; 1.2215x over previous
//
#include <hip/hip_runtime.h>
#include <hip/hip_bf16.h>
#include <stdint.h>

typedef __hip_bfloat16 bf16;
typedef __attribute__((ext_vector_type(8))) short short8;
typedef __attribute__((ext_vector_type(4))) float f32x4;

__device__ __forceinline__ bf16 f2b(float v){ return __float2bfloat16(v); }
__device__ __forceinline__ short s2s(float v){ bf16 b = __float2bfloat16(v); return *reinterpret_cast<short*>(&b); }
__device__ __forceinline__ short8 s8zero()
{
    short8 z;
    for (int i = 0; i < 8; ++i) z[i] = 0;
    return z;
}

// ============ ONE fused weight-prep kernel (9 transforms, segment if-chain) ============
__global__ void prep_weights(const float* __restrict__ ew1, const float* __restrict__ ew2,
                             const float* __restrict__ ew3, const float* __restrict__ dw1,
                             const float* __restrict__ dw2, const float* __restrict__ dw3,
                             const float* __restrict__ kw,  const float* __restrict__ f1w,
                             const float* __restrict__ f2w,
                             bf16* __restrict__ wte1, bf16* __restrict__ wte2,
                             bf16* __restrict__ wte3, bf16* __restrict__ wtb4,
                             bf16* __restrict__ wtb5, bf16* __restrict__ wtb6,
                             bf16* __restrict__ kwt,  bf16* __restrict__ wtf1,
                             bf16* __restrict__ wtf2)
{
    int idx = blockIdx.x * blockDim.x + threadIdx.x;
    // seg0: enc1 wte1[q 3][co 16][k 32], k=j*8+ci, tap=4q+j
    if (idx < 1536) {
        int q = idx >> 9, r = idx & 511;
        int co = r >> 5, k = r & 31;
        int j = k >> 3, ci = k & 7;
        int t = 4 * q + j;
        float v = (ci < 3 && t < 9) ? ew1[((size_t)co * 3 + ci) * 9 + t] : 0.f;
        wte1[idx] = f2b(v);
        return;
    }
    idx -= 1536;
    // seg1: enc2 wte2[p 5][co 32][k 32], t=2p+(k>>4)
    if (idx < 5120) {
        int p = idx >> 10, r = idx & 1023;
        int co = r >> 5, k = r & 31;
        int t = 2 * p + (k >> 4);
        int ch = k & 15;
        float v = (t <= 8) ? ew2[((size_t)co * 16 + ch) * 9 + t] : 0.f;
        wte2[idx] = f2b(v);
        return;
    }
    idx -= 5120;
    // seg2: enc3 wte3[t 9][co 64][ci 32]
    if (idx < 18432) {
        int co = idx / 288;
        int r  = idx - co * 288;
        int ci = r / 9, t = r - ci * 9;
        wte3[((size_t)t * 64 + co) * 32 + ci] = f2b(ew3[idx]);
        return;
    }
    idx -= 18432;
    // seg3: dec1 wtb4[t][co 64][ci 64]   (dw1[ci 64][co 64][9])
    if (idx < 36864) {
        int ci = idx / 576;
        int r  = idx - ci * 576;
        int co = r / 9, t = r - co * 9;
        wtb4[((size_t)t * 64 + co) * 64 + ci] = f2b(dw1[idx]);
        return;
    }
    idx -= 36864;
    // seg4: dec2 wtb5[t][co 32][ci 64]   (dw2[ci 64][co 32][9])
    if (idx < 18432) {
        int ci = idx / 288;
        int r  = idx - ci * 288;
        int co = r / 9, t = r - co * 9;
        wtb5[((size_t)t * 32 + co) * 64 + ci] = f2b(dw2[idx]);
        return;
    }
    idx -= 18432;
    // seg5: dec3 wtb6[t][co 16][ci 32]   (dw3[ci 32][co 16][9])
    if (idx < 4608) {
        int ci = idx / 144;
        int r  = idx - ci * 144;
        int co = r / 9, t = r - co * 9;
        wtb6[((size_t)t * 16 + co) * 32 + ci] = f2b(dw3[idx]);
        return;
    }
    idx -= 4608;
    // seg6: kwt[e 112][pos*64+ci] from kw[e][ci*64+pos]
    if (idx < 458752) {
        int e = idx >> 12, kk = idx & 4095;
        int pos = kk >> 6, ci = kk & 63;
        float v = (e < 110) ? kw[(size_t)e * 4096 + ci * 64 + pos] : 0.f;
        kwt[idx] = f2b(v);
        return;
    }
    idx -= 458752;
    // seg7: wtf1[n 512][k 1280] from f1w[n][1210]
    if (idx < 655360) {
        int n = idx / 1280, k = idx - n * 1280;
        float v = (k < 1210) ? f1w[(size_t)n * 1210 + k] : 0.f;
        wtf1[idx] = f2b(v);
        return;
    }
    idx -= 655360;
    // seg8: wtf2[n 256][k 512]
    if (idx < 131072) {
        wtf2[idx] = f2b(f2w[idx]);
        return;
    }
}

// ============ enc1 MFMA: x[img][3][32][32] fp32 -> h1b[img][32][32][16], K=4taps x 8ch ============
__global__ __launch_bounds__(256)
void enc1_mfma(const float* __restrict__ xg, const bf16* __restrict__ wte,
               const float* __restrict__ bias, bf16* __restrict__ yg)
{
    __shared__ short8 Xs[34 * 34];
    const int img = blockIdx.x;
    const float* xi = xg + (size_t)img * 3072;
    for (int e = threadIdx.x; e < 1156; e += 256) {
        int hr = e / 34, wc = e % 34;
        int hi = hr - 1, wi = wc - 1;
        short8 v = s8zero();
        if ((unsigned)hi < 32u && (unsigned)wi < 32u) {
            int p = hi * 32 + wi;
            v[0] = s2s(xi[p]);
            v[1] = s2s(xi[p + 1024]);
            v[2] = s2s(xi[p + 2048]);
        }
        Xs[e] = v;
    }
    __syncthreads();

    const int wv = threadIdx.x >> 6, lane = threadIdx.x & 63;
    const int lp = lane & 15, lq = lane >> 4;

    short8 wf[3];
    #pragma unroll
    for (int q = 0; q < 3; ++q)
        wf[q] = *reinterpret_cast<const short8*>(wte + ((size_t)(q * 16 + lp)) * 32 + lq * 8);
    float bv[4];
    #pragma unroll
    for (int r = 0; r < 4; ++r) bv[r] = bias[lq * 4 + r];

    bf16* yi = yg + (size_t)img * 1024 * 16;
    for (int mt = wv * 16; mt < wv * 16 + 16; ++mt) {
        int m = mt * 16 + lp;
        int ho = m >> 5, wo = m & 31;
        f32x4 acc = {0.f, 0.f, 0.f, 0.f};
        #pragma unroll
        for (int q = 0; q < 3; ++q) {
            int t = 4 * q + lq;
            if (t > 8) t = 8;
            int dh = t / 3 - 1, dw = t % 3 - 1;
            int pos = (ho + dh + 1) * 34 + (wo + dw + 1);
            acc = __builtin_amdgcn_mfma_f32_16x16x32_bf16(wf[q], Xs[pos], acc, 0, 0, 0);
        }
        __align__(8) bf16 ov[4];
        #pragma unroll
        for (int r = 0; r < 4; ++r) ov[r] = f2b(fmaxf(acc[r] + bv[r], 0.f));
        *reinterpret_cast<uint2*>(yi + (size_t)m * 16 + lq * 4) = *reinterpret_cast<uint2*>(ov);
    }
}

// ============ enc2 MFMA: h1b -> h2b, stride 2, parity planes, 2 taps/MFMA ============
__global__ __launch_bounds__(256)
void enc2_mfma(const bf16* __restrict__ xg, const bf16* __restrict__ wte,
               const float* __restrict__ bias, bf16* __restrict__ yg)
{
    __shared__ short8 Xs[4 * 289 * 2];
    const int img = blockIdx.x;
    const bf16* xi = xg + (size_t)img * 32 * 32 * 16;
    for (int e = threadIdx.x; e < 4 * 289 * 2; e += 256) {
        int c8 = e & 1, q = e >> 1;
        int pl = q / 289, pos = q - pl * 289;
        int pr = pos / 17, pc = pos - pr * 17;
        int pa = pl >> 1, pb = pl & 1;
        int ihr = 2 * (pr - 1) + pa, iwc = 2 * (pc - 1) + pb;
        short8 v = s8zero();
        if ((unsigned)ihr < 32u && (unsigned)iwc < 32u)
            v = *reinterpret_cast<const short8*>(xi + ((size_t)(ihr * 32 + iwc)) * 16 + c8 * 8);
        Xs[(pl * 289 + pos) * 2 + (c8 ^ (pos & 1))] = v;
    }
    __syncthreads();

    const int wv = threadIdx.x >> 6, lane = threadIdx.x & 63;
    const int lp = lane & 15, lq = lane >> 4;
    const int nt = wv & 1, mh = wv >> 1;

    short8 wf[5];
    #pragma unroll
    for (int p = 0; p < 5; ++p)
        wf[p] = *reinterpret_cast<const short8*>(wte + ((size_t)(p * 32 + nt * 16 + lp)) * 32 + lq * 8);
    float bv[4];
    #pragma unroll
    for (int r = 0; r < 4; ++r) bv[r] = bias[nt * 16 + lq * 4 + r];

    bf16* yi = yg + (size_t)img * 16 * 16 * 32;
    for (int mt = mh * 8; mt < mh * 8 + 8; ++mt) {
        int m = mt * 16 + lp;
        int ho = m >> 4, wo = m & 15;
        f32x4 acc = {0.f, 0.f, 0.f, 0.f};
        #pragma unroll
        for (int p = 0; p < 5; ++p) {
            const int tA = 2 * p, tB = (p < 4) ? 2 * p + 1 : 8;
            const int khA = tA / 3, kwA = tA % 3;
            const int paA = (khA == 1) ? 0 : 1, dhA = (khA == 0) ? -1 : 0;
            const int pbA = (kwA == 1) ? 0 : 1, dwA = (kwA == 0) ? -1 : 0;
            const int khB = tB / 3, kwB = tB % 3;
            const int paB = (khB == 1) ? 0 : 1, dhB = (khB == 0) ? -1 : 0;
            const int pbB = (kwB == 1) ? 0 : 1, dwB = (kwB == 0) ? -1 : 0;
            int posA = (ho + dhA + 1) * 17 + (wo + dwA + 1);
            int posB = (ho + dhB + 1) * 17 + (wo + dwB + 1);
            int idxA = ((paA * 2 + pbA) * 289 + posA) * 2 + ((lq & 1) ^ (posA & 1));
            int idxB = ((paB * 2 + pbB) * 289 + posB) * 2 + ((lq & 1) ^ (posB & 1));
            short8 b = Xs[(lq < 2) ? idxA : idxB];
            acc = __builtin_amdgcn_mfma_f32_16x16x32_bf16(wf[p], b, acc, 0, 0, 0);
        }
        __align__(8) bf16 ov[4];
        #pragma unroll
        for (int r = 0; r < 4; ++r) ov[r] = f2b(fmaxf(acc[r] + bv[r], 0.f));
        *reinterpret_cast<uint2*>(yi + ((size_t)(ho * 16 + wo)) * 32 + nt * 16 + lq * 4)
            = *reinterpret_cast<uint2*>(ov);
    }
}

// ============ enc3 MFMA: h2b -> h3b, stride 2 ============
__global__ __launch_bounds__(256)
void enc3_mfma(const bf16* __restrict__ xg, const bf16* __restrict__ wte,
               const float* __restrict__ bias, bf16* __restrict__ yg)
{
    __shared__ short8 Xs[4 * 81 * 4];
    const int img = blockIdx.x;
    const bf16* xi = xg + (size_t)img * 16 * 16 * 32;
    for (int e = threadIdx.x; e < 4 * 81 * 4; e += 256) {
        int c8 = e & 3, q = e >> 2;
        int pl = q / 81, pos = q - pl * 81;
        int pr = pos / 9, pc = pos - pr * 9;
        int pa = pl >> 1, pb = pl & 1;
        int ihr = 2 * (pr - 1) + pa, iwc = 2 * (pc - 1) + pb;
        short8 v = s8zero();
        if ((unsigned)ihr < 16u && (unsigned)iwc < 16u)
            v = *reinterpret_cast<const short8*>(xi + ((size_t)(ihr * 16 + iwc)) * 32 + c8 * 8);
        Xs[(pl * 81 + pos) * 4 + (c8 ^ (pos & 3))] = v;
    }
    __syncthreads();

    const int wv = threadIdx.x >> 6, lane = threadIdx.x & 63;
    const int lp = lane & 15, lq = lane >> 4;
    const int nt = wv;

    short8 wf[9];
    #pragma unroll
    for (int t = 0; t < 9; ++t)
        wf[t] = *reinterpret_cast<const short8*>(wte + ((size_t)(t * 64 + nt * 16 + lp)) * 32 + lq * 8);
    float bv[4];
    #pragma unroll
    for (int r = 0; r < 4; ++r) bv[r] = bias[nt * 16 + lq * 4 + r];

    bf16* yi = yg + (size_t)img * 8 * 8 * 64;
    for (int mt = 0; mt < 4; ++mt) {
        int m = mt * 16 + lp;
        int ho = m >> 3, wo = m & 7;
        f32x4 acc = {0.f, 0.f, 0.f, 0.f};
        #pragma unroll
        for (int t = 0; t < 9; ++t) {
            const int kh = t / 3, kw2 = t % 3;
            const int pa = (kh == 1) ? 0 : 1, dh = (kh == 0) ? -1 : 0;
            const int pb = (kw2 == 1) ? 0 : 1, dw = (kw2 == 0) ? -1 : 0;
            int pos = (ho + dh + 1) * 9 + (wo + dw + 1);
            int idx = ((pa * 2 + pb) * 81 + pos) * 4 + (lq ^ (pos & 3));
            acc = __builtin_amdgcn_mfma_f32_16x16x32_bf16(wf[t], Xs[idx], acc, 0, 0, 0);
        }
        __align__(8) bf16 ov[4];
        #pragma unroll
        for (int r = 0; r < 4; ++r) ov[r] = f2b(fmaxf(acc[r] + bv[r], 0.f));
        *reinterpret_cast<uint2*>(yi + ((size_t)(ho * 8 + wo)) * 64 + nt * 16 + lq * 4)
            = *reinterpret_cast<uint2*>(ov);
    }
}

// ============ emb = sigmoid(h3b @ kwt^T + kb); n-tile via blockIdx.y ============
__global__ __launch_bounds__(256)
void emb_mfma(const bf16* __restrict__ h3b, const bf16* __restrict__ kwt,
              const float* __restrict__ kb, float* __restrict__ emb)
{
    __shared__ f32x4 Ls[3][64];
    const int imgbase = blockIdx.x * 16;
    const int nt = blockIdx.y;
    const int w = threadIdx.x >> 6, lane = threadIdx.x & 63;
    const int lp = lane & 15, lq = lane >> 4;
    const int k0 = w * 1024;

    f32x4 acc = {0.f, 0.f, 0.f, 0.f};
    const bf16* bp = h3b + (size_t)(imgbase + lp) * 4096 + k0 + lq * 8;
    const bf16* ap = kwt + (size_t)(nt * 16 + lp) * 4096 + k0 + lq * 8;
    for (int ks = 0; ks < 32; ++ks) {
        short8 bfrag = *reinterpret_cast<const short8*>(bp + ks * 32);
        short8 afrag = *reinterpret_cast<const short8*>(ap + ks * 32);
        acc = __builtin_amdgcn_mfma_f32_16x16x32_bf16(afrag, bfrag, acc, 0, 0, 0);
    }
    if (w > 0) Ls[w - 1][lane] = acc;
    __syncthreads();
    if (w == 0) {
        #pragma unroll
        for (int ww = 0; ww < 3; ++ww) acc += Ls[ww][lane];
        const int e0 = nt * 16 + lq * 4;
        #pragma unroll
        for (int r = 0; r < 4; ++r) {
            int e = e0 + r;
            if (e < 110) {
                float v = acc[r] + kb[e];
                emb[(size_t)(imgbase + lp) * 110 + e] = 1.f / (1.f + expf(-v));
            }
        }
    }
}

// ============ MFMA transpose-conv stride 2 (decoder) ============
template<int COUT, int HIN, int WIN, int HSPLIT>
__global__ __launch_bounds__(256)
void convt2_mfma(const bf16* __restrict__ xg, const bf16* __restrict__ wtb,
                 const float* __restrict__ bias, bf16* __restrict__ yg)
{
    constexpr int CIN = 64, C8 = 8;
    constexpr int WP  = WIN + 1;
    constexpr int HS  = HIN / HSPLIT;
    constexpr int HPS = HS + 1;
    constexpr int NPOS = HPS * WP;
    constexpr int HOUT = HIN * 2, WOUT = WIN * 2;
    constexpr int NT = COUT / 16;
    constexpr int MT = (HS * WIN) / 16;
    __shared__ short8 Xs[NPOS * C8];

    const int img = blockIdx.x;
    const int s   = blockIdx.y;
    const int hqb = s * HS;
    const bf16* xi = xg + (size_t)img * HIN * WIN * CIN;

    for (int e = threadIdx.x; e < NPOS * C8; e += 256) {
        int c8 = e & 7, pos = e >> 3;
        int hl = pos / WP, wi = pos % WP;
        int hi = hqb + hl;
        short8 v = s8zero();
        if (hi < HIN && wi < WIN)
            v = *reinterpret_cast<const short8*>(xi + ((size_t)(hi * WIN + wi)) * CIN + c8 * 8);
        Xs[pos * C8 + (c8 ^ (pos & 7))] = v;
    }
    __syncthreads();

    const int wv = threadIdx.x >> 6, lane = threadIdx.x & 63;
    const int lp = lane & 15, lq = lane >> 4;
    const int nt    = (NT == 4) ? wv : (wv & 1);
    const int mt0   = (NT == 4) ? 0  : (wv >> 1) * (MT / 2);
    const int mtend = (NT == 4) ? MT : mt0 + (MT / 2);

    short8 wf[9][2];
    #pragma unroll
    for (int t = 0; t < 9; ++t) {
        const bf16* wp = wtb + ((size_t)t * COUT + nt * 16 + lp) * CIN + lq * 8;
        wf[t][0] = *reinterpret_cast<const short8*>(wp);
        wf[t][1] = *reinterpret_cast<const short8*>(wp + 32);
    }
    float bv[4];
    #pragma unroll
    for (int r = 0; r < 4; ++r) bv[r] = bias[nt * 16 + lq * 4 + r];

    bf16* yi = yg + (size_t)img * HOUT * WOUT * COUT;
    for (int mt = mt0; mt < mtend; ++mt) {
        int m = mt * 16 + lp;
        int hql = m / WIN, wq = m % WIN;
        f32x4 zero = {0.f, 0.f, 0.f, 0.f};
        f32x4 acc[4] = {zero, zero, zero, zero};
        #pragma unroll
        for (int kh = 0; kh < 3; ++kh) {
            #pragma unroll
            for (int kw = 0; kw < 3; ++kw) {
                const int pa = (kh + 1) & 1, pb = (kw + 1) & 1;
                const int oh = (pa + 1 - kh) >> 1, ow = (pb + 1 - kw) >> 1;
                const int cls = pa * 2 + pb;
                const int t = kh * 3 + kw;
                int pos = (hql + oh) * WP + (wq + ow);
                int sw = pos & 7;
                short8 b0 = Xs[pos * C8 + (lq ^ sw)];
                acc[cls] = __builtin_amdgcn_mfma_f32_16x16x32_bf16(wf[t][0], b0, acc[cls], 0, 0, 0);
                short8 b1 = Xs[pos * C8 + ((4 + lq) ^ sw)];
                acc[cls] = __builtin_amdgcn_mfma_f32_16x16x32_bf16(wf[t][1], b1, acc[cls], 0, 0, 0);
            }
        }
        int hq = hqb + hql;
        #pragma unroll
        for (int cls = 0; cls < 4; ++cls) {
            int pa = cls >> 1, pb = cls & 1;
            int ho = hq * 2 + pa, wo = wq * 2 + pb;
            __align__(8) bf16 ov[4];
            #pragma unroll
            for (int r = 0; r < 4; ++r) ov[r] = f2b(fmaxf(acc[cls][r] + bv[r], 0.f));
            *reinterpret_cast<uint2*>(yi + ((size_t)(ho * WOUT + wo)) * COUT + nt * 16 + lq * 4)
                = *reinterpret_cast<uint2*>(ov);
        }
    }
}

// ============ MFMA transpose-conv stride 1 (32->16) + fused 1x1 (16->3) ============
__global__ __launch_bounds__(256)
void convt1_mfma_fused(const bf16* __restrict__ xg, const bf16* __restrict__ wtb,
                       const float* __restrict__ bias,
                       const float* __restrict__ w4, const float* __restrict__ b4,
                       float* __restrict__ dec)
{
    constexpr int CIN = 32, C8 = 4;
    constexpr int H = 32, W = 32, HR = 18, WR = 34, NPOS = HR * WR;
    __shared__ short8 Xs[NPOS * C8];

    const int img  = blockIdx.x >> 1;
    const int half = blockIdx.x & 1;
    const int hbase = half * 16;
    const bf16* xi = xg + (size_t)img * H * W * CIN;

    for (int e = threadIdx.x; e < NPOS * C8; e += 256) {
        int c8 = e & 3, pos = e >> 2;
        int hr = pos / WR, wr = pos % WR;
        int hi = hbase - 1 + hr, wi = wr - 1;
        short8 v = s8zero();
        if ((unsigned)hi < (unsigned)H && (unsigned)wi < (unsigned)W)
            v = *reinterpret_cast<const short8*>(xi + ((size_t)(hi * W + wi)) * CIN + c8 * 8);
        Xs[pos * C8 + (c8 ^ (pos & 3))] = v;
    }
    __syncthreads();

    const int wv = threadIdx.x >> 6, lane = threadIdx.x & 63;
    const int lp = lane & 15, lq = lane >> 4;

    short8 wf[9];
    #pragma unroll
    for (int t = 0; t < 9; ++t)
        wf[t] = *reinterpret_cast<const short8*>(wtb + ((size_t)t * 16 + lp) * CIN + lq * 8);
    float bv[4];
    #pragma unroll
    for (int r = 0; r < 4; ++r) bv[r] = bias[lq * 4 + r];
    float w4r[3][4];
    #pragma unroll
    for (int j = 0; j < 3; ++j)
        #pragma unroll
        for (int r = 0; r < 4; ++r) w4r[j][r] = w4[j * 16 + lq * 4 + r];
    float b4r[3] = {b4[0], b4[1], b4[2]};

    for (int mt = wv; mt < 32; mt += 4) {
        int m = mt * 16 + lp;
        int hol = m >> 5, wo = m & 31;
        f32x4 acc = {0.f, 0.f, 0.f, 0.f};
        #pragma unroll
        for (int t = 0; t < 9; ++t) {
            int kh = t / 3, kw = t % 3;
            int pos = (hol + 2 - kh) * WR + (wo + 2 - kw);
            short8 b0 = Xs[pos * C8 + (lq ^ (pos & 3))];
            acc = __builtin_amdgcn_mfma_f32_16x16x32_bf16(wf[t], b0, acc, 0, 0, 0);
        }
        float s0 = 0.f, s1 = 0.f, s2 = 0.f;
        #pragma unroll
        for (int r = 0; r < 4; ++r) {
            float v = fmaxf(acc[r] + bv[r], 0.f);
            s0 += v * w4r[0][r]; s1 += v * w4r[1][r]; s2 += v * w4r[2][r];
        }
        s0 += __shfl_xor(s0, 16); s0 += __shfl_xor(s0, 32);
        s1 += __shfl_xor(s1, 16); s1 += __shfl_xor(s1, 32);
        s2 += __shfl_xor(s2, 16); s2 += __shfl_xor(s2, 32);
        if (lq == 0) {
            int ho = hbase + hol;
            size_t base = (size_t)img * 3072 + ho * 32 + wo;
            dec[base]        = s0 + b4r[0];
            dec[base + 1024] = s1 + b4r[1];
            dec[base + 2048] = s2 + b4r[2];
        }
    }
}

// ============ KDE: 64 blocks -> fdb bf16 [64][1280] (padded) ============
__global__ __launch_bounds__(256)
void kde_kernel(const float* __restrict__ emb, bf16* __restrict__ fdb)
{
    __shared__ float es[3520];
    const int b = blockIdx.x, tid = threadIdx.x;
    for (int i = tid; i < 3520; i += 256) es[i] = emb[(size_t)b * 3520 + i];
    __syncthreads();
    if (tid < 110) {
        float dens[11];
        #pragma unroll
        for (int j = 0; j < 11; ++j) dens[j] = 0.f;
        for (int n = 0; n < 32; ++n) {
            float e = es[n * 110 + tid];
            #pragma unroll
            for (int j = 0; j < 11; ++j) {
                float d = 0.1f * j - e;
                dens[j] += __expf(-50.f * d * d);
            }
        }
        float s = 0.f;
        #pragma unroll
        for (int j = 0; j < 11; ++j) s += dens[j];
        float inv = 1.f / s;
        #pragma unroll
        for (int j = 0; j < 11; ++j)
            fdb[(size_t)b * 1280 + tid * 11 + j] = f2b(dens[j] * inv);
    } else if (tid >= 128 && tid < 198) {
        fdb[(size_t)b * 1280 + 1210 + (tid - 128)] = f2b(0.f);
    }
}

// ============ dense MFMA layer: out = relu(in[64][K]bf16 @ w^T[N][K]bf16 + b) -> bf16 ====
template<int K, int N, int RELU>
__global__ __launch_bounds__(256)
void dense_mfma(const bf16* __restrict__ inb, const bf16* __restrict__ wtb,
                const float* __restrict__ bias, bf16* __restrict__ outb)
{
    __shared__ f32x4 Ls[3][64];
    constexpr int KW = K / 4;                 // per-wave K
    const int mt = blockIdx.x, nt = blockIdx.y;
    const int w = threadIdx.x >> 6, lane = threadIdx.x & 63;
    const int lp = lane & 15, lq = lane >> 4;
    const int k0 = w * KW;

    f32x4 acc = {0.f, 0.f, 0.f, 0.f};
    const bf16* bp = inb + (size_t)(mt * 16 + lp) * K + k0 + lq * 8;
    const bf16* ap = wtb + (size_t)(nt * 16 + lp) * K + k0 + lq * 8;
    for (int ks = 0; ks < KW / 32; ++ks) {
        short8 bfrag = *reinterpret_cast<const short8*>(bp + ks * 32);
        short8 afrag = *reinterpret_cast<const short8*>(ap + ks * 32);
        acc = __builtin_amdgcn_mfma_f32_16x16x32_bf16(afrag, bfrag, acc, 0, 0, 0);
    }
    if (w > 0) Ls[w - 1][lane] = acc;
    __syncthreads();
    if (w == 0) {
        #pragma unroll
        for (int ww = 0; ww < 3; ++ww) acc += Ls[ww][lane];
        const int b = mt * 16 + lp;
        const int o0 = nt * 16 + lq * 4;
        __align__(8) bf16 ov[4];
        #pragma unroll
        for (int r = 0; r < 4; ++r) {
            float v = acc[r] + bias[o0 + r];
            if (RELU) v = fmaxf(v, 0.f);
            ov[r] = f2b(v);
        }
        *reinterpret_cast<uint2*>(outb + (size_t)b * N + o0) = *reinterpret_cast<uint2*>(ov);
    }
}

// ============ f3: 256 -> 4, one block ============
__global__ __launch_bounds__(256)
void f3_kernel(const bf16* __restrict__ m2b, const float* __restrict__ f3w,
               const float* __restrict__ f3b, float* __restrict__ logits)
{
    __shared__ float m2s[64 * 256];
    const int tid = threadIdx.x;
    for (int i = tid; i < 16384; i += 256) m2s[i] = __bfloat162float(m2b[i]);
    __syncthreads();
    int b = tid >> 2, o = tid & 3;
    float a = f3b[o];
    const float* wr = f3w + o * 256;
    for (int k = 0; k < 256; ++k) a += m2s[b * 256 + k] * wr[k];
    logits[b * 4 + o] = a;
}

extern "C" void kernel_launch(void* const* d_in, const int* in_sizes, int n_in,
                              void* d_out, int out_size, void* d_ws, size_t ws_size,
                              hipStream_t stream)
{
    const float* x    = (const float*)d_in[0];
    const float* ew1  = (const float*)d_in[1];
    const float* eb1  = (const float*)d_in[2];
    const float* ew2  = (const float*)d_in[3];
    const float* eb2  = (const float*)d_in[4];
    const float* ew3  = (const float*)d_in[5];
    const float* eb3  = (const float*)d_in[6];
    const float* kw   = (const float*)d_in[7];
    const float* kb   = (const float*)d_in[8];
    const float* dw1  = (const float*)d_in[9];
    const float* db1  = (const float*)d_in[10];
    const float* dw2  = (const float*)d_in[11];
    const float* db2  = (const float*)d_in[12];
    const float* dw3  = (const float*)d_in[13];
    const float* db3  = (const float*)d_in[14];
    const float* dw4  = (const float*)d_in[15];
    const float* db4  = (const float*)d_in[16];
    const float* f1w  = (const float*)d_in[17];
    const float* f1b  = (const float*)d_in[18];
    const float* f2w  = (const float*)d_in[19];
    const float* f2b_ = (const float*)d_in[20];
    const float* f3w  = (const float*)d_in[21];
    const float* f3b  = (const float*)d_in[22];

    // ---------- workspace ----------
    char* ws = (char*)d_ws;
    float* emb  = (float*)(ws + 0);          //   901,120
    bf16*  fdb  = (bf16*) (ws + 901120);     //   163,840 (64*1280)
    bf16*  m1b  = (bf16*) (ws + 1064960);    //    65,536 (64*512)
    bf16*  m2b  = (bf16*) (ws + 1130496);    //    32,768 (64*256)
    bf16*  wte1 = (bf16*) (ws + 1163264);    //     3,072
    bf16*  wte2 = (bf16*) (ws + 1166336);    //    10,240
    bf16*  wte3 = (bf16*) (ws + 1176576);    //    36,864
    bf16*  wtb4 = (bf16*) (ws + 1213440);    //    73,728
    bf16*  wtb5 = (bf16*) (ws + 1287168);    //    36,864
    bf16*  wtb6 = (bf16*) (ws + 1324032);    //     9,216
    bf16*  kwt  = (bf16*) (ws + 1333248);    //   917,504
    bf16*  wtf1 = (bf16*) (ws + 2250752);    // 1,310,720 (512*1280)
    bf16*  wtf2 = (bf16*) (ws + 3561472);    //   262,144 (256*512)
    const size_t FIXED = 3823616;

    // per image (bf16 NHWC): h1b 32K (d1b overlays) | h2b 16K | h3b 8K | d2b 64K
    const size_t PER_IMG = 122880;
    int CHUNK = 1024;
    while (CHUNK > 16 && FIXED + (size_t)CHUNK * PER_IMG > ws_size) CHUNK >>= 1;
    const int NCHUNK = 2048 / CHUNK;

    char* p   = ws + FIXED;
    bf16* h1b = (bf16*)(p);
    bf16* h2b = (bf16*)(p + (size_t)CHUNK * 32768);
    bf16* h3b = (bf16*)(p + (size_t)CHUNK * 49152);
    bf16* d2b = (bf16*)(p + (size_t)CHUNK * 57344);
    bf16* d1b = h1b;                          // overlay: h1b dead after enc2

    float* logits = (float*)d_out;            // 64*4
    float* dec    = (float*)d_out + 256;      // 2048*3*32*32 NCHW

    // ---- fused weight prep (1 launch) ----
    prep_weights<<<(1330176 + 255)/256, 256, 0, stream>>>(
        ew1, ew2, ew3, dw1, dw2, dw3, kw, f1w, f2w,
        wte1, wte2, wte3, wtb4, wtb5, wtb6, kwt, wtf1, wtf2);

    for (int c = 0; c < NCHUNK; ++c) {
        const float* xc   = x   + (size_t)c * CHUNK * 3 * 1024;
        float*       decc = dec + (size_t)c * CHUNK * 3 * 1024;
        float*       embc = emb + (size_t)c * CHUNK * 110;

        // encoder (all MFMA)
        enc1_mfma<<<CHUNK, 256, 0, stream>>>(xc, wte1, eb1, h1b);
        enc2_mfma<<<CHUNK, 256, 0, stream>>>(h1b, wte2, eb2, h2b);
        enc3_mfma<<<CHUNK, 256, 0, stream>>>(h2b, wte3, eb3, h3b);

        // embedding (n-split grid)
        emb_mfma<<<dim3(CHUNK/16, 7), 256, 0, stream>>>(h3b, kwt, kb, embc);

        // decoder
        convt2_mfma<64, 8, 8, 1>  <<<dim3(CHUNK,1), 256, 0, stream>>>(h3b, wtb4, db1, d1b);
        convt2_mfma<32, 16, 16, 2><<<dim3(CHUNK,2), 256, 0, stream>>>(d1b, wtb5, db2, d2b);
        convt1_mfma_fused         <<<dim3(CHUNK*2,1), 256, 0, stream>>>(d2b, wtb6, db3, dw4, db4, decc);
    }

    // classifier: KDE -> f1 (MFMA) -> f2 (MFMA) -> f3
    kde_kernel<<<64, 256, 0, stream>>>(emb, fdb);
    dense_mfma<1280, 512, 1><<<dim3(4, 32), 256, 0, stream>>>(fdb, wtf1, f1b, m1b);
    dense_mfma<512, 256, 1> <<<dim3(4, 16), 256, 0, stream>>>(m1b, wtf2, f2b_, m2b);
    f3_kernel<<<1, 256, 0, stream>>>(m2b, f3w, f3b, logits);
}

// Round 15
// 213.526 us; speedup vs baseline: 39.0160x; 1.4424x over previous
//
#include <hip/hip_runtime.h>
#include <hip/hip_bf16.h>
#include <stdint.h>

typedef __hip_bfloat16 bf16;
typedef __attribute__((ext_vector_type(8))) short short8;
typedef __attribute__((ext_vector_type(4))) float f32x4;

__device__ __forceinline__ bf16 f2b(float v){ return __float2bfloat16(v); }
__device__ __forceinline__ short s2s(float v){ bf16 b = __float2bfloat16(v); return *reinterpret_cast<short*>(&b); }
__device__ __forceinline__ short8 s8zero()
{
    short8 z;
    for (int i = 0; i < 8; ++i) z[i] = 0;
    return z;
}

// ============ ONE fused weight-prep kernel (9 transforms, segment if-chain) ============
__global__ void prep_weights(const float* __restrict__ ew1, const float* __restrict__ ew2,
                             const float* __restrict__ ew3, const float* __restrict__ dw1,
                             const float* __restrict__ dw2, const float* __restrict__ dw3,
                             const float* __restrict__ kw,  const float* __restrict__ f1w,
                             const float* __restrict__ f2w,
                             bf16* __restrict__ wte1, bf16* __restrict__ wte2,
                             bf16* __restrict__ wte3, bf16* __restrict__ wtb4,
                             bf16* __restrict__ wtb5, bf16* __restrict__ wtb6,
                             bf16* __restrict__ kwt,  bf16* __restrict__ wtf1,
                             bf16* __restrict__ wtf2)
{
    int idx = blockIdx.x * blockDim.x + threadIdx.x;
    if (idx < 1536) {
        int q = idx >> 9, r = idx & 511;
        int co = r >> 5, k = r & 31;
        int j = k >> 3, ci = k & 7;
        int t = 4 * q + j;
        float v = (ci < 3 && t < 9) ? ew1[((size_t)co * 3 + ci) * 9 + t] : 0.f;
        wte1[idx] = f2b(v);
        return;
    }
    idx -= 1536;
    if (idx < 5120) {
        int p = idx >> 10, r = idx & 1023;
        int co = r >> 5, k = r & 31;
        int t = 2 * p + (k >> 4);
        int ch = k & 15;
        float v = (t <= 8) ? ew2[((size_t)co * 16 + ch) * 9 + t] : 0.f;
        wte2[idx] = f2b(v);
        return;
    }
    idx -= 5120;
    if (idx < 18432) {
        int co = idx / 288;
        int r  = idx - co * 288;
        int ci = r / 9, t = r - ci * 9;
        wte3[((size_t)t * 64 + co) * 32 + ci] = f2b(ew3[idx]);
        return;
    }
    idx -= 18432;
    if (idx < 36864) {
        int ci = idx / 576;
        int r  = idx - ci * 576;
        int co = r / 9, t = r - co * 9;
        wtb4[((size_t)t * 64 + co) * 64 + ci] = f2b(dw1[idx]);
        return;
    }
    idx -= 36864;
    if (idx < 18432) {
        int ci = idx / 288;
        int r  = idx - ci * 288;
        int co = r / 9, t = r - co * 9;
        wtb5[((size_t)t * 32 + co) * 64 + ci] = f2b(dw2[idx]);
        return;
    }
    idx -= 18432;
    if (idx < 4608) {
        int ci = idx / 144;
        int r  = idx - ci * 144;
        int co = r / 9, t = r - co * 9;
        wtb6[((size_t)t * 16 + co) * 32 + ci] = f2b(dw3[idx]);
        return;
    }
    idx -= 4608;
    if (idx < 458752) {
        int e = idx >> 12, kk = idx & 4095;
        int pos = kk >> 6, ci = kk & 63;
        float v = (e < 110) ? kw[(size_t)e * 4096 + ci * 64 + pos] : 0.f;
        kwt[idx] = f2b(v);
        return;
    }
    idx -= 458752;
    if (idx < 655360) {
        int n = idx / 1280, k = idx - n * 1280;
        float v = (k < 1210) ? f1w[(size_t)n * 1210 + k] : 0.f;
        wtf1[idx] = f2b(v);
        return;
    }
    idx -= 655360;
    if (idx < 131072) {
        wtf2[idx] = f2b(f2w[idx]);
        return;
    }
}

// ============ FUSED encoder: x fp32 -> (LDS h1 -> LDS h2) -> h3b bf16 NHWC ============
__global__ __launch_bounds__(256)
void enc123_fused(const float* __restrict__ xg,
                  const bf16* __restrict__ wte1, const float* __restrict__ eb1,
                  const bf16* __restrict__ wte2, const float* __restrict__ eb2,
                  const bf16* __restrict__ wte3, const float* __restrict__ eb3,
                  bf16* __restrict__ h3g)
{
    __shared__ char smem[57728];
    short8* H1  = (short8*)smem;             // 2312 short8 (4 planes x 289 pos x 2 c8)
    short8* Xs1 = (short8*)(smem + 36992);   // 1156 short8 (34x34)
    short8* H2  = (short8*)(smem + 36992);   // 1296 short8 (4 x 81 x 4) — overlays Xs1

    const int img = blockIdx.x;
    const int tid = threadIdx.x;
    const float* xi = xg + (size_t)img * 3072;

    // phase 0: stage x (bf16-cast) + zero H1 borders
    for (int e = tid; e < 1156; e += 256) {
        int hr = e / 34, wc = e % 34;
        int hi = hr - 1, wi = wc - 1;
        short8 v = s8zero();
        if ((unsigned)hi < 32u && (unsigned)wi < 32u) {
            int p = hi * 32 + wi;
            v[0] = s2s(xi[p]);
            v[1] = s2s(xi[p + 1024]);
            v[2] = s2s(xi[p + 2048]);
        }
        Xs1[e] = v;
    }
    for (int e = tid; e < 264; e += 256) {
        int c8 = e & 1, q = e >> 1;
        int pl = q / 33, j = q % 33;
        int pos = (j < 17) ? j : (j - 16) * 17;
        H1[(pl * 289 + pos) * 2 + c8] = s8zero();
    }
    __syncthreads();

    const int wv = tid >> 6, lane = tid & 63;
    const int lp = lane & 15, lq = lane >> 4;

    // ---- enc1: write into H1 (enc2 parity-plane layout) ----
    {
        short8 wf[3];
        #pragma unroll
        for (int q = 0; q < 3; ++q)
            wf[q] = *reinterpret_cast<const short8*>(wte1 + (size_t)(q * 16 + lp) * 32 + lq * 8);
        float bv[4];
        #pragma unroll
        for (int r = 0; r < 4; ++r) bv[r] = eb1[lq * 4 + r];

        for (int mt = wv * 16; mt < wv * 16 + 16; ++mt) {
            int m = mt * 16 + lp;
            int ho = m >> 5, wo = m & 31;
            f32x4 acc = {0.f, 0.f, 0.f, 0.f};
            #pragma unroll
            for (int q = 0; q < 3; ++q) {
                int t = 4 * q + lq;
                if (t > 8) t = 8;
                int pos = (ho + t / 3) * 34 + (wo + t % 3);
                acc = __builtin_amdgcn_mfma_f32_16x16x32_bf16(wf[q], Xs1[pos], acc, 0, 0, 0);
            }
            int pl  = (ho & 1) * 2 + (wo & 1);
            int pos = ((ho >> 1) + 1) * 17 + ((wo >> 1) + 1);
            int slot = (pl * 289 + pos) * 2 + ((lq >> 1) ^ (pos & 1));
            __align__(8) bf16 ov[4];
            #pragma unroll
            for (int r = 0; r < 4; ++r) ov[r] = f2b(fmaxf(acc[r] + bv[r], 0.f));
            *reinterpret_cast<uint2*>(reinterpret_cast<char*>(&H1[slot]) + (lq & 1) * 8)
                = *reinterpret_cast<uint2*>(ov);
        }
    }
    __syncthreads();

    // ---- enc2: read H1, write into H2 (enc3 layout); zero H2 borders first ----
    for (int e = tid; e < 272; e += 256) {
        int c8 = e & 3, q = e >> 2;
        int pl = q / 17, j = q % 17;
        int pos = (j < 9) ? j : (j - 8) * 9;
        H2[(pl * 81 + pos) * 4 + c8] = s8zero();
    }
    {
        const int nt = wv & 1, mh = wv >> 1;
        short8 wf[5];
        #pragma unroll
        for (int p = 0; p < 5; ++p)
            wf[p] = *reinterpret_cast<const short8*>(wte2 + ((size_t)(p * 32 + nt * 16 + lp)) * 32 + lq * 8);
        float bv[4];
        #pragma unroll
        for (int r = 0; r < 4; ++r) bv[r] = eb2[nt * 16 + lq * 4 + r];

        for (int mt = mh * 8; mt < mh * 8 + 8; ++mt) {
            int m = mt * 16 + lp;
            int ho = m >> 4, wo = m & 15;
            f32x4 acc = {0.f, 0.f, 0.f, 0.f};
            #pragma unroll
            for (int p = 0; p < 5; ++p) {
                const int tA = 2 * p, tB = (p < 4) ? 2 * p + 1 : 8;
                const int khA = tA / 3, kwA = tA % 3;
                const int paA = (khA == 1) ? 0 : 1, dhA = (khA == 0) ? -1 : 0;
                const int pbA = (kwA == 1) ? 0 : 1, dwA = (kwA == 0) ? -1 : 0;
                const int khB = tB / 3, kwB = tB % 3;
                const int paB = (khB == 1) ? 0 : 1, dhB = (khB == 0) ? -1 : 0;
                const int pbB = (kwB == 1) ? 0 : 1, dwB = (kwB == 0) ? -1 : 0;
                int posA = (ho + dhA + 1) * 17 + (wo + dwA + 1);
                int posB = (ho + dhB + 1) * 17 + (wo + dwB + 1);
                int idxA = ((paA * 2 + pbA) * 289 + posA) * 2 + ((lq & 1) ^ (posA & 1));
                int idxB = ((paB * 2 + pbB) * 289 + posB) * 2 + ((lq & 1) ^ (posB & 1));
                short8 b = H1[(lq < 2) ? idxA : idxB];
                acc = __builtin_amdgcn_mfma_f32_16x16x32_bf16(wf[p], b, acc, 0, 0, 0);
            }
            int pl  = (ho & 1) * 2 + (wo & 1);
            int pos = ((ho >> 1) + 1) * 9 + ((wo >> 1) + 1);
            int c8w = nt * 2 + (lq >> 1);
            int slot = (pl * 81 + pos) * 4 + (c8w ^ (pos & 3));
            __align__(8) bf16 ov[4];
            #pragma unroll
            for (int r = 0; r < 4; ++r) ov[r] = f2b(fmaxf(acc[r] + bv[r], 0.f));
            *reinterpret_cast<uint2*>(reinterpret_cast<char*>(&H2[slot]) + (lq & 1) * 8)
                = *reinterpret_cast<uint2*>(ov);
        }
    }
    __syncthreads();

    // ---- enc3: read H2, write h3b ----
    {
        const int nt = wv;
        short8 wf[9];
        #pragma unroll
        for (int t = 0; t < 9; ++t)
            wf[t] = *reinterpret_cast<const short8*>(wte3 + ((size_t)(t * 64 + nt * 16 + lp)) * 32 + lq * 8);
        float bv[4];
        #pragma unroll
        for (int r = 0; r < 4; ++r) bv[r] = eb3[nt * 16 + lq * 4 + r];

        bf16* yi = h3g + (size_t)img * 4096;
        for (int mt = 0; mt < 4; ++mt) {
            int m = mt * 16 + lp;
            int ho = m >> 3, wo = m & 7;
            f32x4 acc = {0.f, 0.f, 0.f, 0.f};
            #pragma unroll
            for (int t = 0; t < 9; ++t) {
                const int kh = t / 3, kw2 = t % 3;
                const int pa = (kh == 1) ? 0 : 1, dh = (kh == 0) ? -1 : 0;
                const int pb = (kw2 == 1) ? 0 : 1, dw = (kw2 == 0) ? -1 : 0;
                int pos = (ho + dh + 1) * 9 + (wo + dw + 1);
                int idx = ((pa * 2 + pb) * 81 + pos) * 4 + (lq ^ (pos & 3));
                acc = __builtin_amdgcn_mfma_f32_16x16x32_bf16(wf[t], H2[idx], acc, 0, 0, 0);
            }
            __align__(8) bf16 ov[4];
            #pragma unroll
            for (int r = 0; r < 4; ++r) ov[r] = f2b(fmaxf(acc[r] + bv[r], 0.f));
            *reinterpret_cast<uint2*>(yi + ((size_t)(ho * 8 + wo)) * 64 + nt * 16 + lq * 4)
                = *reinterpret_cast<uint2*>(ov);
        }
    }
}

// ============ FUSED dec1+dec2: h3b -> (LDS d1) -> d2p parity-plane layout ============
// d2p per image: [cls 4][nt 2][256 pos][16 ch] bf16 (32768 elem)
__global__ __launch_bounds__(256)
void dec12_fused(const bf16* __restrict__ h3g,
                 const bf16* __restrict__ wtb4, const float* __restrict__ db1,
                 const bf16* __restrict__ wtb5, const float* __restrict__ db2,
                 bf16* __restrict__ d2p)
{
    __shared__ short8 H3s[648];     // 9x9 padded x 8 c8
    __shared__ short8 D1s[2312];    // 17x17 padded x 8 c8
    const int img = blockIdx.x;
    const int tid = threadIdx.x;
    const bf16* xi = h3g + (size_t)img * 4096;

    for (int e = tid; e < 648; e += 256) {
        int c8 = e & 7, pos = e >> 3;
        int hl = pos / 9, wi = pos % 9;
        short8 v = s8zero();
        if (hl < 8 && wi < 8)
            v = *reinterpret_cast<const short8*>(xi + ((size_t)(hl * 8 + wi)) * 64 + c8 * 8);
        H3s[pos * 8 + (c8 ^ (pos & 7))] = v;
    }
    for (int e = tid; e < 264; e += 256) {
        int c8 = e & 7, q = e >> 3;
        int pos = (q < 17) ? (16 * 17 + q) : ((q - 17) * 17 + 16);
        D1s[pos * 8 + c8] = s8zero();
    }
    __syncthreads();

    const int wv = tid >> 6, lane = tid & 63;
    const int lp = lane & 15, lq = lane >> 4;

    // ---- dec1: 8x8x64 -> 16x16x64 into D1s ----
    {
        const int nt = wv;
        short8 wf[9][2];
        #pragma unroll
        for (int t = 0; t < 9; ++t) {
            const bf16* wp = wtb4 + ((size_t)t * 64 + nt * 16 + lp) * 64 + lq * 8;
            wf[t][0] = *reinterpret_cast<const short8*>(wp);
            wf[t][1] = *reinterpret_cast<const short8*>(wp + 32);
        }
        float bv[4];
        #pragma unroll
        for (int r = 0; r < 4; ++r) bv[r] = db1[nt * 16 + lq * 4 + r];

        const int c8w = nt * 2 + (lq >> 1);
        for (int mt = 0; mt < 4; ++mt) {
            int m = mt * 16 + lp;
            int hq = m >> 3, wq = m & 7;
            f32x4 zero = {0.f, 0.f, 0.f, 0.f};
            f32x4 acc[4] = {zero, zero, zero, zero};
            #pragma unroll
            for (int kh = 0; kh < 3; ++kh) {
                #pragma unroll
                for (int kw = 0; kw < 3; ++kw) {
                    const int pa = (kh + 1) & 1, pb = (kw + 1) & 1;
                    const int oh = (pa + 1 - kh) >> 1, ow = (pb + 1 - kw) >> 1;
                    const int cls = pa * 2 + pb;
                    const int t = kh * 3 + kw;
                    int pos = (hq + oh) * 9 + (wq + ow);
                    int sw = pos & 7;
                    acc[cls] = __builtin_amdgcn_mfma_f32_16x16x32_bf16(wf[t][0], H3s[pos * 8 + (lq ^ sw)], acc[cls], 0, 0, 0);
                    acc[cls] = __builtin_amdgcn_mfma_f32_16x16x32_bf16(wf[t][1], H3s[pos * 8 + ((4 + lq) ^ sw)], acc[cls], 0, 0, 0);
                }
            }
            #pragma unroll
            for (int cls = 0; cls < 4; ++cls) {
                int pa = cls >> 1, pb = cls & 1;
                int ho = hq * 2 + pa, wo = wq * 2 + pb;
                int pos = ho * 17 + wo;
                int slot = pos * 8 + (c8w ^ (pos & 7));
                __align__(8) bf16 ov[4];
                #pragma unroll
                for (int r = 0; r < 4; ++r) ov[r] = f2b(fmaxf(acc[cls][r] + bv[r], 0.f));
                *reinterpret_cast<uint2*>(reinterpret_cast<char*>(&D1s[slot]) + (lq & 1) * 8)
                    = *reinterpret_cast<uint2*>(ov);
            }
        }
    }
    __syncthreads();

    // ---- dec2: 16x16x64 -> 32x32x32, parity-plane coalesced write ----
    {
        const int nt = wv & 1;
        const int mt0 = (wv >> 1) * 8;
        short8 wf[9][2];
        #pragma unroll
        for (int t = 0; t < 9; ++t) {
            const bf16* wp = wtb5 + ((size_t)t * 32 + nt * 16 + lp) * 64 + lq * 8;
            wf[t][0] = *reinterpret_cast<const short8*>(wp);
            wf[t][1] = *reinterpret_cast<const short8*>(wp + 32);
        }
        float bv[4];
        #pragma unroll
        for (int r = 0; r < 4; ++r) bv[r] = db2[nt * 16 + lq * 4 + r];

        bf16* yo = d2p + (size_t)img * 32768;
        for (int mt = mt0; mt < mt0 + 8; ++mt) {
            const int hq = mt, wq = lp;
            f32x4 zero = {0.f, 0.f, 0.f, 0.f};
            f32x4 acc[4] = {zero, zero, zero, zero};
            #pragma unroll
            for (int kh = 0; kh < 3; ++kh) {
                #pragma unroll
                for (int kw = 0; kw < 3; ++kw) {
                    const int pa = (kh + 1) & 1, pb = (kw + 1) & 1;
                    const int oh = (pa + 1 - kh) >> 1, ow = (pb + 1 - kw) >> 1;
                    const int cls = pa * 2 + pb;
                    const int t = kh * 3 + kw;
                    int pos = (hq + oh) * 17 + (wq + ow);
                    int sw = pos & 7;
                    acc[cls] = __builtin_amdgcn_mfma_f32_16x16x32_bf16(wf[t][0], D1s[pos * 8 + (lq ^ sw)], acc[cls], 0, 0, 0);
                    acc[cls] = __builtin_amdgcn_mfma_f32_16x16x32_bf16(wf[t][1], D1s[pos * 8 + ((4 + lq) ^ sw)], acc[cls], 0, 0, 0);
                }
            }
            #pragma unroll
            for (int cls = 0; cls < 4; ++cls) {
                __align__(8) bf16 ov[4];
                #pragma unroll
                for (int r = 0; r < 4; ++r) ov[r] = f2b(fmaxf(acc[cls][r] + bv[r], 0.f));
                size_t off = (size_t)cls * 8192 + (size_t)nt * 4096 + (hq * 16 + wq) * 16 + lq * 4;
                *reinterpret_cast<uint2*>(yo + off) = *reinterpret_cast<uint2*>(ov);
            }
        }
    }
}

// ============ emb = sigmoid(h3b @ kwt^T + kb); n-tile via blockIdx.y ============
__global__ __launch_bounds__(256)
void emb_mfma(const bf16* __restrict__ h3b, const bf16* __restrict__ kwt,
              const float* __restrict__ kb, float* __restrict__ emb)
{
    __shared__ f32x4 Ls[3][64];
    const int imgbase = blockIdx.x * 16;
    const int nt = blockIdx.y;
    const int w = threadIdx.x >> 6, lane = threadIdx.x & 63;
    const int lp = lane & 15, lq = lane >> 4;
    const int k0 = w * 1024;

    f32x4 acc = {0.f, 0.f, 0.f, 0.f};
    const bf16* bp = h3b + (size_t)(imgbase + lp) * 4096 + k0 + lq * 8;
    const bf16* ap = kwt + (size_t)(nt * 16 + lp) * 4096 + k0 + lq * 8;
    for (int ks = 0; ks < 32; ++ks) {
        short8 bfrag = *reinterpret_cast<const short8*>(bp + ks * 32);
        short8 afrag = *reinterpret_cast<const short8*>(ap + ks * 32);
        acc = __builtin_amdgcn_mfma_f32_16x16x32_bf16(afrag, bfrag, acc, 0, 0, 0);
    }
    if (w > 0) Ls[w - 1][lane] = acc;
    __syncthreads();
    if (w == 0) {
        #pragma unroll
        for (int ww = 0; ww < 3; ++ww) acc += Ls[ww][lane];
        const int e0 = nt * 16 + lq * 4;
        #pragma unroll
        for (int r = 0; r < 4; ++r) {
            int e = e0 + r;
            if (e < 110) {
                float v = acc[r] + kb[e];
                emb[(size_t)(imgbase + lp) * 110 + e] = 1.f / (1.f + expf(-v));
            }
        }
    }
}

// ============ dec3: d2p (parity layout) -> conv_t1 -> fused 1x1 -> dec fp32 NCHW ============
__global__ __launch_bounds__(256)
void convt1_mfma_fused(const bf16* __restrict__ d2p, const bf16* __restrict__ wtb,
                       const float* __restrict__ bias,
                       const float* __restrict__ w4, const float* __restrict__ b4,
                       float* __restrict__ dec)
{
    constexpr int C8 = 4;
    constexpr int HR = 18, WR = 34, NPOS = HR * WR;
    __shared__ short8 Xs[NPOS * C8];

    const int img  = blockIdx.x >> 1;
    const int half = blockIdx.x & 1;
    const int hbase = half * 16;
    const bf16* xi = d2p + (size_t)img * 32768;

    for (int e = threadIdx.x; e < NPOS * C8; e += 256) {
        int c8 = e & 3, pos = e >> 2;
        int hr = pos / WR, wr = pos % WR;
        int hi = hbase - 1 + hr, wi = wr - 1;
        short8 v = s8zero();
        if ((unsigned)hi < 32u && (unsigned)wi < 32u) {
            int cls = ((hi & 1) << 1) | (wi & 1);
            size_t src = (size_t)cls * 8192 + (size_t)(c8 >> 1) * 4096
                       + (((hi >> 1) << 4) + (wi >> 1)) * 16 + (c8 & 1) * 8;
            v = *reinterpret_cast<const short8*>(xi + src);
        }
        Xs[pos * C8 + (c8 ^ (pos & 3))] = v;
    }
    __syncthreads();

    const int wv = threadIdx.x >> 6, lane = threadIdx.x & 63;
    const int lp = lane & 15, lq = lane >> 4;

    short8 wf[9];
    #pragma unroll
    for (int t = 0; t < 9; ++t)
        wf[t] = *reinterpret_cast<const short8*>(wtb + ((size_t)t * 16 + lp) * 32 + lq * 8);
    float bv[4];
    #pragma unroll
    for (int r = 0; r < 4; ++r) bv[r] = bias[lq * 4 + r];
    float w4r[3][4];
    #pragma unroll
    for (int j = 0; j < 3; ++j)
        #pragma unroll
        for (int r = 0; r < 4; ++r) w4r[j][r] = w4[j * 16 + lq * 4 + r];
    float b4r[3] = {b4[0], b4[1], b4[2]};

    for (int mt = wv; mt < 32; mt += 4) {
        int m = mt * 16 + lp;
        int hol = m >> 5, wo = m & 31;
        f32x4 acc = {0.f, 0.f, 0.f, 0.f};
        #pragma unroll
        for (int t = 0; t < 9; ++t) {
            int kh = t / 3, kw = t % 3;
            int pos = (hol + 2 - kh) * WR + (wo + 2 - kw);
            short8 b0 = Xs[pos * C8 + (lq ^ (pos & 3))];
            acc = __builtin_amdgcn_mfma_f32_16x16x32_bf16(wf[t], b0, acc, 0, 0, 0);
        }
        float s0 = 0.f, s1 = 0.f, s2 = 0.f;
        #pragma unroll
        for (int r = 0; r < 4; ++r) {
            float v = fmaxf(acc[r] + bv[r], 0.f);
            s0 += v * w4r[0][r]; s1 += v * w4r[1][r]; s2 += v * w4r[2][r];
        }
        s0 += __shfl_xor(s0, 16); s0 += __shfl_xor(s0, 32);
        s1 += __shfl_xor(s1, 16); s1 += __shfl_xor(s1, 32);
        s2 += __shfl_xor(s2, 16); s2 += __shfl_xor(s2, 32);
        if (lq == 0) {
            int ho = hbase + hol;
            size_t base = (size_t)img * 3072 + ho * 32 + wo;
            dec[base]        = s0 + b4r[0];
            dec[base + 1024] = s1 + b4r[1];
            dec[base + 2048] = s2 + b4r[2];
        }
    }
}

// ============ KDE: 64 blocks -> fdb bf16 [64][1280] (padded) ============
__global__ __launch_bounds__(256)
void kde_kernel(const float* __restrict__ emb, bf16* __restrict__ fdb)
{
    __shared__ float es[3520];
    const int b = blockIdx.x, tid = threadIdx.x;
    for (int i = tid; i < 3520; i += 256) es[i] = emb[(size_t)b * 3520 + i];
    __syncthreads();
    if (tid < 110) {
        float dens[11];
        #pragma unroll
        for (int j = 0; j < 11; ++j) dens[j] = 0.f;
        for (int n = 0; n < 32; ++n) {
            float e = es[n * 110 + tid];
            #pragma unroll
            for (int j = 0; j < 11; ++j) {
                float d = 0.1f * j - e;
                dens[j] += __expf(-50.f * d * d);
            }
        }
        float s = 0.f;
        #pragma unroll
        for (int j = 0; j < 11; ++j) s += dens[j];
        float inv = 1.f / s;
        #pragma unroll
        for (int j = 0; j < 11; ++j)
            fdb[(size_t)b * 1280 + tid * 11 + j] = f2b(dens[j] * inv);
    } else if (tid >= 128 && tid < 198) {
        fdb[(size_t)b * 1280 + 1210 + (tid - 128)] = f2b(0.f);
    }
}

// ============ dense MFMA layer ============
template<int K, int N, int RELU>
__global__ __launch_bounds__(256)
void dense_mfma(const bf16* __restrict__ inb, const bf16* __restrict__ wtb,
                const float* __restrict__ bias, bf16* __restrict__ outb)
{
    __shared__ f32x4 Ls[3][64];
    constexpr int KW = K / 4;
    const int mt = blockIdx.x, nt = blockIdx.y;
    const int w = threadIdx.x >> 6, lane = threadIdx.x & 63;
    const int lp = lane & 15, lq = lane >> 4;
    const int k0 = w * KW;

    f32x4 acc = {0.f, 0.f, 0.f, 0.f};
    const bf16* bp = inb + (size_t)(mt * 16 + lp) * K + k0 + lq * 8;
    const bf16* ap = wtb + (size_t)(nt * 16 + lp) * K + k0 + lq * 8;
    for (int ks = 0; ks < KW / 32; ++ks) {
        short8 bfrag = *reinterpret_cast<const short8*>(bp + ks * 32);
        short8 afrag = *reinterpret_cast<const short8*>(ap + ks * 32);
        acc = __builtin_amdgcn_mfma_f32_16x16x32_bf16(afrag, bfrag, acc, 0, 0, 0);
    }
    if (w > 0) Ls[w - 1][lane] = acc;
    __syncthreads();
    if (w == 0) {
        #pragma unroll
        for (int ww = 0; ww < 3; ++ww) acc += Ls[ww][lane];
        const int b = mt * 16 + lp;
        const int o0 = nt * 16 + lq * 4;
        __align__(8) bf16 ov[4];
        #pragma unroll
        for (int r = 0; r < 4; ++r) {
            float v = acc[r] + bias[o0 + r];
            if (RELU) v = fmaxf(v, 0.f);
            ov[r] = f2b(v);
        }
        *reinterpret_cast<uint2*>(outb + (size_t)b * N + o0) = *reinterpret_cast<uint2*>(ov);
    }
}

// ============ f3: 256 -> 4, one block ============
__global__ __launch_bounds__(256)
void f3_kernel(const bf16* __restrict__ m2b, const float* __restrict__ f3w,
               const float* __restrict__ f3b, float* __restrict__ logits)
{
    __shared__ float m2s[64 * 256];
    const int tid = threadIdx.x;
    for (int i = tid; i < 16384; i += 256) m2s[i] = __bfloat162float(m2b[i]);
    __syncthreads();
    int b = tid >> 2, o = tid & 3;
    float a = f3b[o];
    const float* wr = f3w + o * 256;
    for (int k = 0; k < 256; ++k) a += m2s[b * 256 + k] * wr[k];
    logits[b * 4 + o] = a;
}

extern "C" void kernel_launch(void* const* d_in, const int* in_sizes, int n_in,
                              void* d_out, int out_size, void* d_ws, size_t ws_size,
                              hipStream_t stream)
{
    const float* x    = (const float*)d_in[0];
    const float* ew1  = (const float*)d_in[1];
    const float* eb1  = (const float*)d_in[2];
    const float* ew2  = (const float*)d_in[3];
    const float* eb2  = (const float*)d_in[4];
    const float* ew3  = (const float*)d_in[5];
    const float* eb3  = (const float*)d_in[6];
    const float* kw   = (const float*)d_in[7];
    const float* kb   = (const float*)d_in[8];
    const float* dw1  = (const float*)d_in[9];
    const float* db1  = (const float*)d_in[10];
    const float* dw2  = (const float*)d_in[11];
    const float* db2  = (const float*)d_in[12];
    const float* dw3  = (const float*)d_in[13];
    const float* db3  = (const float*)d_in[14];
    const float* dw4  = (const float*)d_in[15];
    const float* db4  = (const float*)d_in[16];
    const float* f1w  = (const float*)d_in[17];
    const float* f1b  = (const float*)d_in[18];
    const float* f2w  = (const float*)d_in[19];
    const float* f2b_ = (const float*)d_in[20];
    const float* f3w  = (const float*)d_in[21];
    const float* f3b  = (const float*)d_in[22];

    // ---------- workspace ----------
    char* ws = (char*)d_ws;
    float* emb  = (float*)(ws + 0);          //   901,120
    bf16*  fdb  = (bf16*) (ws + 901120);     //   163,840
    bf16*  m1b  = (bf16*) (ws + 1064960);    //    65,536
    bf16*  m2b  = (bf16*) (ws + 1130496);    //    32,768
    bf16*  wte1 = (bf16*) (ws + 1163264);    //     3,072
    bf16*  wte2 = (bf16*) (ws + 1166336);    //    10,240
    bf16*  wte3 = (bf16*) (ws + 1176576);    //    36,864
    bf16*  wtb4 = (bf16*) (ws + 1213440);    //    73,728
    bf16*  wtb5 = (bf16*) (ws + 1287168);    //    36,864
    bf16*  wtb6 = (bf16*) (ws + 1324032);    //     9,216
    bf16*  kwt  = (bf16*) (ws + 1333248);    //   917,504
    bf16*  wtf1 = (bf16*) (ws + 2250752);    // 1,310,720
    bf16*  wtf2 = (bf16*) (ws + 3561472);    //   262,144
    const size_t FIXED = 3823616;

    // per image: h3b 8 KB + d2p 64 KB (h1b/h2b/d1b eliminated by fusion)
    const size_t PER_IMG = 73728;
    int CHUNK = 2048;
    while (CHUNK > 16 && FIXED + (size_t)CHUNK * PER_IMG > ws_size) CHUNK >>= 1;
    const int NCHUNK = 2048 / CHUNK;

    char* p   = ws + FIXED;
    bf16* h3b = (bf16*)(p);
    bf16* d2p = (bf16*)(p + (size_t)CHUNK * 8192);

    float* logits = (float*)d_out;            // 64*4
    float* dec    = (float*)d_out + 256;      // 2048*3*32*32 NCHW

    // ---- fused weight prep (1 launch) ----
    prep_weights<<<(1330176 + 255)/256, 256, 0, stream>>>(
        ew1, ew2, ew3, dw1, dw2, dw3, kw, f1w, f2w,
        wte1, wte2, wte3, wtb4, wtb5, wtb6, kwt, wtf1, wtf2);

    for (int c = 0; c < NCHUNK; ++c) {
        const float* xc   = x   + (size_t)c * CHUNK * 3 * 1024;
        float*       decc = dec + (size_t)c * CHUNK * 3 * 1024;
        float*       embc = emb + (size_t)c * CHUNK * 110;

        enc123_fused<<<CHUNK, 256, 0, stream>>>(xc, wte1, eb1, wte2, eb2, wte3, eb3, h3b);
        emb_mfma<<<dim3(CHUNK/16, 7), 256, 0, stream>>>(h3b, kwt, kb, embc);
        dec12_fused<<<CHUNK, 256, 0, stream>>>(h3b, wtb4, db1, wtb5, db2, d2p);
        convt1_mfma_fused<<<CHUNK*2, 256, 0, stream>>>(d2p, wtb6, db3, dw4, db4, decc);
    }

    // classifier: KDE -> f1 (MFMA) -> f2 (MFMA) -> f3
    kde_kernel<<<64, 256, 0, stream>>>(emb, fdb);
    dense_mfma<1280, 512, 1><<<dim3(4, 32), 256, 0, stream>>>(fdb, wtf1, f1b, m1b);
    dense_mfma<512, 256, 1> <<<dim3(4, 16), 256, 0, stream>>>(m1b, wtf2, f2b_, m2b);
    f3_kernel<<<1, 256, 0, stream>>>(m2b, f3w, f3b, logits);
}